// Round 1
// baseline (896.477 us; speedup 1.0000x reference)
//
#include <hip/hip_runtime.h>
#include <cmath>

// Problem constants: M=87, CLS=65, K=128, DL=DC=128, DO=2048, BD=256, B=256, HW=49

// ---------------- workspace layout (float offsets) ----------------
constexpr size_t OFF_W12T  = 0;                               // 2048x128 (W12 transposed [c][o])
constexpr size_t OFF_B12   = OFF_W12T  + 2048*128;            // 128
constexpr size_t OFF_WAPT  = OFF_B12   + 128;                 // 128x216  ([c][r], r:0..127=Wps,128..214=Wa,215=0)
constexpr size_t OFF_B215  = OFF_WAPT  + 128*216;             // 216
constexpr size_t OFF_WG2T  = OFF_B215  + 216;                 // 128x128  ([d][o])
constexpr size_t OFF_WSPT  = OFF_WG2T  + 128*128;             // 128x128  ([c][o])
constexpr size_t OFF_ENP   = OFF_WSPT  + 128*128;             // 87x88 padded edge_norm
constexpr size_t OFF_WPR   = OFF_ENP   + 87*88 + 8;           // 87x87 (+pad)
constexpr size_t OFF_WOX21 = OFF_WPR   + 7572;                // 2048x128 ([c][d])
constexpr size_t OFF_BTMP  = OFF_WOX21 + 2048*128;            // 2048
constexpr size_t OFF_WC    = OFF_BTMP  + 2048;                // 256x128
constexpr size_t OFF_BC    = OFF_WC    + 256*128;             // 256
constexpr size_t OFF_XP    = OFF_BC    + 256;                 // 256x2048
constexpr size_t OFF_XL    = OFF_XP    + 256*2048;            // 256x128x49
constexpr size_t OFF_VY    = OFF_XL    + (size_t)256*128*49;  // 256x87
constexpr size_t OFF_NT    = OFF_VY    + 256*87;              // 2x128x88 node-term (b-parity)
constexpr size_t OFF_M3M   = OFF_NT    + 2*128*88;            // 256x128
constexpr size_t OFF_BUFA  = OFF_M3M   + 256*128;             // 256x128x88 (m1, then m2)
constexpr size_t OFF_BUFB  = OFF_BUFA  + (size_t)256*128*88;  // 256x128x88 (g)
constexpr size_t WS_FLOATS = OFF_BUFB  + (size_t)256*128*88;  // ~34.4 MB

__device__ __forceinline__ void fma44(float (&acc)[4][4], const float4 a, const float4 b) {
  float av[4] = {a.x, a.y, a.z, a.w};
  float bv[4] = {b.x, b.y, b.z, b.w};
  #pragma unroll
  for (int i = 0; i < 4; ++i)
    #pragma unroll
    for (int j = 0; j < 4; ++j)
      acc[i][j] += av[i] * bv[j];
}

// ---------------- setup1: weight precompute / transposes / init ----------------
__global__ __launch_bounds__(256) void setup1(
    const float* __restrict__ bb,  const float* __restrict__ Wo1, const float* __restrict__ bo1,
    const float* __restrict__ Wo2, const float* __restrict__ bo2, const float* __restrict__ Wa,
    const float* __restrict__ ba,  const float* __restrict__ Wps, const float* __restrict__ bps,
    const float* __restrict__ Wg,  const float* __restrict__ Wsp, const float* __restrict__ Wox1,
    const float* __restrict__ box1,const float* __restrict__ Wox2,const float* __restrict__ box2,
    const float* __restrict__ edge, float* __restrict__ ws, float* __restrict__ featp)
{
  int blk = blockIdx.x, tid = threadIdx.x;
  if (blk < 1024) {                       // W12t[c*128+o] = sum_h Wo2[o,h]*Wo1[h,c]
    int idx = blk*256 + tid;
    int c = idx >> 7, o = idx & 127;
    float s = 0.f;
    for (int h = 0; h < 512; ++h) s += Wo2[o*512+h] * Wo1[h*2048+c];
    ws[OFF_W12T + idx] = s;
  } else if (blk < 2048) {                // Wox21[c*128+d] = sum_h Wox2[c,h]*Wox1[h,d]
    int idx = (blk-1024)*256 + tid;
    int c = idx >> 7, d = idx & 127;
    float s = 0.f;
    for (int h = 0; h < 512; ++h) s += Wox2[c*512+h] * Wox1[h*128+d];
    ws[OFF_WOX21 + idx] = s;
  } else if (blk < 2056) {                // btmp = Wox2@box1 + box2
    int c = (blk-2048)*256 + tid;
    float s = 0.f;
    for (int h = 0; h < 512; ++h) s += Wox2[c*512+h] * box1[h];
    ws[OFF_BTMP + c] = s + box2[c];
  } else if (blk < 2164) {                // Wapt[c*216+r]
    int idx = (blk-2056)*256 + tid;       // < 27648
    int c = idx / 216, r = idx % 216;
    float v;
    if (r < 128)      v = Wps[r*128 + c];
    else if (r < 215) v = Wa[(r-128)*128 + c];
    else              v = 0.f;
    ws[OFF_WAPT + idx] = v;
  } else if (blk == 2164) {               // b215
    if (tid < 216) {
      float v = (tid < 128) ? bps[tid] : (tid < 215 ? ba[tid-128] : 0.f);
      ws[OFF_B215 + tid] = v;
    }
  } else if (blk == 2165) {               // b12 = Wo2@bo1 + bo2
    if (tid < 128) {
      float s = 0.f;
      for (int h = 0; h < 512; ++h) s += Wo2[tid*512+h] * bo1[h];
      ws[OFF_B12 + tid] = s + bo2[tid];
    }
  } else if (blk < 2230) {                // Wg2t[d*128+o] = Wg[o, 128+d]
    int idx = (blk-2166)*256 + tid;
    int d = idx >> 7, o = idx & 127;
    ws[OFF_WG2T + idx] = Wg[o*256 + 128 + d];
  } else if (blk < 2294) {                // Wspt[c*128+o] = Wsp[o,c]
    int idx = (blk-2230)*256 + tid;
    int c = idx >> 7, o = idx & 127;
    ws[OFF_WSPT + idx] = Wsp[o*128 + c];
  } else if (blk < 2324) {                // edge_norm padded to width 88
    int idx = (blk-2294)*256 + tid;
    if (idx < 87*88) {
      int m = idx / 88, n = idx % 88;
      float v = 0.f;
      if (n < 87) {
        float sm = 0.f, sn = 0.f;
        for (int k = 0; k < 87; ++k) { sm += edge[k*87+m]; sn += edge[k*87+n]; }
        v = edge[m*87+n] / sqrtf(sm*sn);
      }
      ws[OFF_ENP + idx] = v;
    }
  } else if (blk < 2354) {                // Wpr[i*87+j] = 0.85*edge[i,j]/rowsum(j)
    int idx = (blk-2324)*256 + tid;
    if (idx < 87*87) {
      int j = idx % 87;
      float rs = 0.f;
      for (int k = 0; k < 87; ++k) rs += edge[j*87+k];
      ws[OFF_WPR + idx] = 0.85f * edge[idx] / rs;
    }
  } else {                                // features_p init = bb[j]  (256 blocks)
    int idx = (blk-2354)*256 + tid;       // < 65536
    featp[idx] = bb[idx & 255];
  }
}

// ---------------- setup2: Wc = Wb@Wox21, bc = Wb@btmp + bb ----------------
__global__ __launch_bounds__(256) void setup2(const float* __restrict__ Wb,
                                              const float* __restrict__ bb,
                                              float* __restrict__ ws)
{
  int blk = blockIdx.x, tid = threadIdx.x;
  if (blk < 128) {
    int idx = blk*256 + tid;
    int j = idx >> 7, d = idx & 127;
    const float* wox21 = ws + OFF_WOX21;
    float s = 0.f;
    for (int c = 0; c < 2048; ++c) s += Wb[(size_t)j*2048+c] * wox21[c*128+d];
    ws[OFF_WC + idx] = s;
  } else {
    int j = tid;
    float s = 0.f;
    for (int c = 0; c < 2048; ++c) s += Wb[(size_t)j*2048+c] * ws[OFF_BTMP+c];
    ws[OFF_BC + j] = s + bb[j];
  }
}

// ---------------- kmain: x_l = W12@x + b12  (fused x_p = mean(x)) ----------------
__global__ __launch_bounds__(512) void kmain(const float* __restrict__ x,
                                             const float* __restrict__ w12t,
                                             const float* __restrict__ b12,
                                             float* __restrict__ xl,
                                             float* __restrict__ xp)
{
  __shared__ alignas(16) float Xs[64*68];
  __shared__ alignas(16) float Wst[64*132];
  int b = blockIdx.x, tid = threadIdx.x;
  int og = tid >> 4, pg = tid & 15;
  int ob = og*4, pb = pg*4;
  float acc[4][4] = {};
  for (int kc = 0; kc < 2048; kc += 64) {
    for (int i = tid; i < 64*64; i += 512) {
      int c = i >> 6, p = i & 63;
      Xs[c*68+p] = (p < 49) ? x[((size_t)b*2048 + kc + c)*49 + p] : 0.f;
    }
    for (int i = tid; i < 64*128; i += 512) {
      int c = i >> 7, o = i & 127;
      Wst[c*132+o] = w12t[(size_t)(kc+c)*128 + o];
    }
    __syncthreads();
    if (tid < 64) {                       // fused x_p
      float s = 0.f;
      for (int p = 0; p < 49; ++p) s += Xs[tid*68+p];
      xp[(size_t)b*2048 + kc + tid] = s * (1.f/49.f);
    }
    for (int c = 0; c < 64; ++c) {
      float4 w4 = *(const float4*)&Wst[c*132 + ob];
      float4 x4 = *(const float4*)&Xs[c*68 + pb];
      fma44(acc, w4, x4);
    }
    __syncthreads();
  }
  #pragma unroll
  for (int i = 0; i < 4; ++i) {
    float bias = b12[ob+i];
    #pragma unroll
    for (int j = 0; j < 4; ++j) {
      int p = pb + j;
      if (p < 49) xl[((size_t)b*128 + ob + i)*49 + p] = acc[i][j] + bias;
    }
  }
}

// ---------------- gemm64: C(MxN) = A(MxK) @ B(NxK)^T [+bias], tile 64x64 ----------------
template<int ATOMIC>
__global__ __launch_bounds__(256) void gemm64(const float* __restrict__ A, int lda,
                                              const float* __restrict__ Bm, int ldb,
                                              float* __restrict__ C, int ldc,
                                              int Mh, int Nh, int Kz,
                                              const float* __restrict__ bias)
{
  __shared__ alignas(16) float As[16*68];
  __shared__ alignas(16) float Bs[16*68];
  int i0 = blockIdx.x*64, j0 = blockIdx.y*64;
  int kc0 = blockIdx.z*Kz;
  int ti = threadIdx.x >> 4, tj = threadIdx.x & 15;
  float acc[4][4] = {};
  for (int kc = kc0; kc < kc0 + Kz; kc += 16) {
    for (int i = threadIdx.x; i < 1024; i += 256) {
      int r = i >> 4, k = i & 15;
      As[k*68+r] = (i0 + r < Mh) ? A[(size_t)(i0+r)*lda + kc + k] : 0.f;
      Bs[k*68+r] = (j0 + r < Nh) ? Bm[(size_t)(j0+r)*ldb + kc + k] : 0.f;
    }
    __syncthreads();
    #pragma unroll
    for (int k = 0; k < 16; ++k) {
      float4 a4 = *(const float4*)&As[k*68 + ti*4];
      float4 b4 = *(const float4*)&Bs[k*68 + tj*4];
      fma44(acc, a4, b4);
    }
    __syncthreads();
  }
  #pragma unroll
  for (int i = 0; i < 4; ++i) {
    int r = i0 + ti*4 + i;
    if (r < Mh) {
      #pragma unroll
      for (int j = 0; j < 4; ++j) {
        int cc = j0 + tj*4 + j;
        if (cc < Nh) {
          float v = acc[i][j];
          if (bias) v += bias[cc];
          if (ATOMIC) atomicAdd(&C[(size_t)r*ldc + cc], v);
          else        C[(size_t)r*ldc + cc] = v;
        }
      }
    }
  }
}

// ---------------- kpr: softmax(pre_output) -> v_init -> 100 PageRank iters -> v_y ----------------
__global__ __launch_bounds__(128) void kpr(const float* __restrict__ preout,
                                           const float* __restrict__ wpr,
                                           float* __restrict__ vy)
{
  __shared__ alignas(16) float po[68];
  __shared__ alignas(16) float vs[88];
  __shared__ float red[2];
  int b = blockIdx.x, tid = threadIdx.x;
  if (tid < 65) po[tid] = preout[b*65 + tid];
  __syncthreads();
  if (tid == 0) {
    float mx = po[0];
    for (int j = 1; j < 65; ++j) mx = fmaxf(mx, po[j]);
    float sm = 0.f;
    for (int j = 0; j < 65; ++j) sm += expf(po[j]-mx);
    red[0] = mx; red[1] = 1.f/sm;
  }
  __syncthreads();
  float vinit = 0.f;
  if (tid >= 22 && tid < 87) vinit = expf(po[tid-22]-red[0]) * red[1];
  float s_i = vinit * 87.f;
  float wrow[87];
  if (tid < 87) {
    float add = s_i * (0.15f/87.0f);       // rank-1 fold of the zx term
    #pragma unroll
    for (int j = 0; j < 87; ++j) wrow[j] = wpr[tid*87 + j] + add;
    vs[tid] = s_i;
  }
  __syncthreads();
  for (int it = 0; it < 100; ++it) {
    float nv = 0.f;
    if (tid < 87) {
      #pragma unroll
      for (int j4 = 0; j4 < 21; ++j4) {
        float4 v4 = *(const float4*)&vs[j4*4];
        nv += wrow[j4*4+0]*v4.x + wrow[j4*4+1]*v4.y + wrow[j4*4+2]*v4.z + wrow[j4*4+3]*v4.w;
      }
      nv += wrow[84]*vs[84] + wrow[85]*vs[85] + wrow[86]*vs[86];
    }
    __syncthreads();
    if (tid < 87) vs[tid] = nv;
    __syncthreads();
  }
  if (tid == 0) {
    float ss = 0.f;
    for (int j = 0; j < 87; ++j) ss += vs[j]*vs[j];
    red[0] = 1.f / fmaxf(sqrtf(ss), 1e-12f);
  }
  __syncthreads();
  if (tid < 87) vy[b*87 + tid] = vinit + vs[tid]*red[0];
}

// ---------------- knode: NT[par][o][m] = sum_k Wg[o,k]*node_p[k,m]*v_y[par*128+k, m] ----------------
// (the reference's reshape makes node depend on b only via b%2)
__global__ __launch_bounds__(256) void knode(const float* __restrict__ Wg,
                                             const float* __restrict__ node_p,
                                             const float* __restrict__ vy,
                                             float* __restrict__ nt)
{
  int idx = blockIdx.x*256 + threadIdx.x;  // < 22528
  int par = idx / 11264;
  int r = idx % 11264;
  int o = r / 88, m = r % 88;
  float v = 0.f;
  if (m < 87) {
    float s = 0.f;
    for (int k = 0; k < 128; ++k)
      s += Wg[o*256+k] * node_p[k*87+m] * vy[(par*128+k)*87+m];
    v = s;
  }
  nt[idx] = v;
}

// ---------------- kgraph1: a/ps projections + m1 = relu(ps @ a^T) ----------------
__global__ __launch_bounds__(256) void kgraph1(const float* __restrict__ xl,
                                               const float* __restrict__ wapt,
                                               const float* __restrict__ b215,
                                               float* __restrict__ m1)
{
  __shared__ alignas(16) float Xs[64*68];
  __shared__ alignas(16) float At[49*220];   // [p][r]: r<128 ps, 128..214 a, 215 zero
  int b = blockIdx.x, tid = threadIdx.x;
  int rg = tid >> 2, pg = tid & 3;
  float acc[4][16] = {};
  for (int kc = 0; kc < 128; kc += 64) {
    for (int i = tid; i < 64*64; i += 256) {
      int c = i >> 6, p = i & 63;
      Xs[c*68+p] = (p < 49) ? xl[((size_t)b*128 + kc + c)*49 + p] : 0.f;
    }
    __syncthreads();
    if (rg < 54) {
      for (int c = 0; c < 64; ++c) {
        float4 w4 = *(const float4*)&wapt[(kc+c)*216 + rg*4];
        float wv[4] = {w4.x, w4.y, w4.z, w4.w};
        #pragma unroll
        for (int q = 0; q < 4; ++q) {
          float4 x4 = *(const float4*)&Xs[c*68 + pg*16 + q*4];
          float xv[4] = {x4.x, x4.y, x4.z, x4.w};
          #pragma unroll
          for (int i = 0; i < 4; ++i)
            #pragma unroll
            for (int t = 0; t < 4; ++t)
              acc[i][q*4+t] += wv[i]*xv[t];
        }
      }
    }
    __syncthreads();
  }
  if (rg < 54) {
    #pragma unroll
    for (int i = 0; i < 4; ++i) {
      int r = rg*4 + i;
      float bias = b215[r];
      #pragma unroll
      for (int j = 0; j < 16; ++j) {
        int p = pg*16 + j;
        if (p < 49) At[p*220 + r] = acc[i][j] + bias;
      }
    }
  }
  __syncthreads();
  // phase B: m1[d][m] = relu(sum_p ps[d][p]*a[m][p])
  int dg = tid >> 3, mg = tid & 7;
  for (int pass = 0; pass < 3; ++pass) {
    int mb = pass*32 + mg*4;
    if (mb < 88) {
      float a2[4][4] = {};
      for (int p = 0; p < 49; ++p) {
        float4 psv = *(const float4*)&At[p*220 + dg*4];
        float4 av  = *(const float4*)&At[p*220 + 128 + mb];
        fma44(a2, psv, av);
      }
      #pragma unroll
      for (int i = 0; i < 4; ++i)
        #pragma unroll
        for (int j = 0; j < 4; ++j) {
          int m = mb + j;
          if (m < 88) m1[((size_t)b*128 + dg*4 + i)*88 + m] = fmaxf(a2[i][j], 0.f);
        }
    }
  }
}

// ---------------- kg: g = Wg2@m1 + NT[b%2] + bg ----------------
__global__ __launch_bounds__(256) void kg(const float* __restrict__ m1,
                                          const float* __restrict__ wg2t,
                                          const float* __restrict__ nt,
                                          const float* __restrict__ bg,
                                          float* __restrict__ g)
{
  __shared__ alignas(16) float S[128*88];
  int b = blockIdx.x, tid = threadIdx.x;
  { int d = tid >> 1, h = tid & 1;
    for (int j = 0; j < 44; ++j) S[d*88 + h*44 + j] = m1[((size_t)b*128 + d)*88 + h*44 + j]; }
  __syncthreads();
  int og = tid >> 3, mg = tid & 7;
  const float* ntb = nt + (size_t)(b & 1)*11264;
  for (int pass = 0; pass < 3; ++pass) {
    int mb = pass*32 + mg*4;
    if (mb < 88) {
      float acc[4][4] = {};
      for (int d = 0; d < 128; ++d) {
        float4 w4 = *(const float4*)&wg2t[d*128 + og*4];
        float4 m4 = *(const float4*)&S[d*88 + mb];
        fma44(acc, w4, m4);
      }
      #pragma unroll
      for (int i = 0; i < 4; ++i) {
        int o = og*4 + i;
        float bo = bg[o];
        #pragma unroll
        for (int j = 0; j < 4; ++j) {
          int m = mb + j;
          if (m < 88) g[((size_t)b*128 + o)*88 + m] = acc[i][j] + ntb[o*88+m] + bo;
        }
      }
    }
  }
}

// ---------------- km2: m2 = relu(g @ edge_norm) ----------------
__global__ __launch_bounds__(256) void km2(const float* __restrict__ g,
                                           const float* __restrict__ enp,
                                           float* __restrict__ m2)
{
  __shared__ alignas(16) float Gt[88*132];
  int b = blockIdx.x, tid = threadIdx.x;
  for (int i = tid; i < 128*88; i += 256) {
    int d = i / 88, m = i % 88;
    Gt[m*132 + d] = g[(size_t)b*128*88 + i];
  }
  __syncthreads();
  int cg = tid >> 3, ng = tid & 7;
  for (int pass = 0; pass < 3; ++pass) {
    int nb = pass*32 + ng*4;
    if (nb < 88) {
      float acc[4][4] = {};
      for (int m = 0; m < 87; ++m) {
        float4 g4 = *(const float4*)&Gt[m*132 + cg*4];
        float4 e4 = *(const float4*)&enp[m*88 + nb];
        fma44(acc, g4, e4);
      }
      #pragma unroll
      for (int i = 0; i < 4; ++i)
        #pragma unroll
        for (int j = 0; j < 4; ++j) {
          int n = nb + j;
          if (n < 88) m2[((size_t)b*128 + cg*4 + i)*88 + n] = fmaxf(acc[i][j], 0.f);
        }
    }
  }
}

// ---------------- ksp: sp = Wsp@m2+bsp; att = softmax(t_node); m3mean = relu(sp@att) ----------------
// (s_att is pixel-independent: the t_pix term cancels in the softmax over nodes)
__global__ __launch_bounds__(256) void ksp(const float* __restrict__ m2,
                                           const float* __restrict__ wspt,
                                           const float* __restrict__ bsp,
                                           const float* __restrict__ Ws,
                                           float* __restrict__ m3m)
{
  __shared__ alignas(16) float S[128*88];
  __shared__ float wsm[96];
  __shared__ float m3acc[128];
  __shared__ float tnb[88];
  __shared__ float redx[1];
  int b = blockIdx.x, tid = threadIdx.x;
  { int d = tid >> 1, h = tid & 1;
    for (int j = 0; j < 44; ++j) S[d*88 + h*44 + j] = m2[((size_t)b*128 + d)*88 + h*44 + j]; }
  if (tid < 96) wsm[tid] = 0.f;
  if (tid < 128) m3acc[tid] = 0.f;
  __syncthreads();
  if (tid < 87) {
    float s = 0.f;
    for (int c = 0; c < 128; ++c) s += Ws[c] * S[c*88 + tid];
    tnb[tid] = s;
  }
  __syncthreads();
  if (tid == 0) {
    float mx = tnb[0];
    for (int j = 1; j < 87; ++j) mx = fmaxf(mx, tnb[j]);
    redx[0] = mx;
  }
  __syncthreads();
  if (tid < 87) wsm[tid] = expf(tnb[tid] - redx[0]);
  __syncthreads();
  if (tid == 0) {
    float sm = 0.f;
    for (int j = 0; j < 87; ++j) sm += wsm[j];
    redx[0] = 1.f/sm;
  }
  __syncthreads();
  if (tid < 87) wsm[tid] *= redx[0];
  __syncthreads();
  int og = tid >> 3, mg = tid & 7;
  for (int pass = 0; pass < 3; ++pass) {
    int mb = pass*32 + mg*4;
    if (mb < 88) {
      float acc[4][4] = {};
      for (int d = 0; d < 128; ++d) {
        float4 w4 = *(const float4*)&wspt[d*128 + og*4];
        float4 m4 = *(const float4*)&S[d*88 + mb];
        fma44(acc, w4, m4);
      }
      #pragma unroll
      for (int i = 0; i < 4; ++i) {
        int o = og*4 + i;
        float bo = bsp[o];
        float part = 0.f;
        #pragma unroll
        for (int j = 0; j < 4; ++j) part += (acc[i][j] + bo) * wsm[mb+j];
        atomicAdd(&m3acc[o], part);
      }
    }
  }
  __syncthreads();
  if (tid < 128) m3m[b*128 + tid] = fmaxf(m3acc[tid], 0.f);
}

// ---------------- kfin: features, outputs2, softmax ----------------
__global__ __launch_bounds__(256) void kfin(const float* __restrict__ m3m,
                                            const float* __restrict__ wc,
                                            const float* __restrict__ bc,
                                            const float* __restrict__ featp,
                                            const float* __restrict__ Wfc2,
                                            float* __restrict__ feat,
                                            float* __restrict__ out2,
                                            float* __restrict__ soft)
{
  __shared__ alignas(16) float m3s[128];
  __shared__ float fs[256];
  __shared__ float o2s[68];
  __shared__ float r2[2];
  int b = blockIdx.x, tid = threadIdx.x;
  if (tid < 128) m3s[tid] = m3m[b*128 + tid];
  __syncthreads();
  {
    float s = 0.f;
    #pragma unroll 4
    for (int d4 = 0; d4 < 32; ++d4) {
      float4 w4 = *(const float4*)&wc[tid*128 + d4*4];
      float4 m4 = *(const float4*)&m3s[d4*4];
      s += w4.x*m4.x + w4.y*m4.y + w4.z*m4.z + w4.w*m4.w;
    }
    float f = featp[b*256 + tid] + bc[tid] + s;
    fs[tid] = f;
    feat[b*256 + tid] = f;
  }
  __syncthreads();
  if (tid < 65) {
    float s = 0.f;
    for (int j = 0; j < 256; ++j) s += Wfc2[tid*256 + j] * fs[j];
    out2[b*65 + tid] = s;
    o2s[tid] = s;
  }
  __syncthreads();
  if (tid == 0) {
    float mx = o2s[0];
    for (int j = 1; j < 65; ++j) mx = fmaxf(mx, o2s[j]);
    float sm = 0.f;
    for (int j = 0; j < 65; ++j) sm += expf(o2s[j]-mx);
    r2[0] = mx; r2[1] = 1.f/sm;
  }
  __syncthreads();
  if (tid < 65) soft[b*65 + tid] = expf(o2s[tid]-r2[0]) * r2[1];
}

// ---------------- launch ----------------
extern "C" void kernel_launch(void* const* d_in, const int* in_sizes, int n_in,
                              void* d_out, int out_size, void* d_ws, size_t ws_size,
                              hipStream_t stream)
{
  (void)in_sizes; (void)n_in; (void)out_size; (void)ws_size;
  const float* x      = (const float*)d_in[0];
  const float* Wb     = (const float*)d_in[1];
  const float* bb     = (const float*)d_in[2];
  const float* Wfc    = (const float*)d_in[3];
  const float* Wfc2   = (const float*)d_in[4];
  const float* Wo1    = (const float*)d_in[5];
  const float* bo1    = (const float*)d_in[6];
  const float* Wo2    = (const float*)d_in[7];
  const float* bo2    = (const float*)d_in[8];
  const float* Wa     = (const float*)d_in[9];
  const float* ba     = (const float*)d_in[10];
  const float* Wps    = (const float*)d_in[11];
  const float* bps    = (const float*)d_in[12];
  const float* node_p = (const float*)d_in[13];
  const float* Wg     = (const float*)d_in[14];
  const float* bg     = (const float*)d_in[15];
  const float* Wsp    = (const float*)d_in[16];
  const float* bsp    = (const float*)d_in[17];
  const float* Ws     = (const float*)d_in[18];
  const float* Wox1   = (const float*)d_in[20];
  const float* box1   = (const float*)d_in[21];
  const float* Wox2   = (const float*)d_in[22];
  const float* box2   = (const float*)d_in[23];
  const float* edge   = (const float*)d_in[24];
  // d_in[19] (bs) cancels in the node-softmax; d_in[18][128:] (Ws2) likewise.

  float* ws   = (float*)d_ws;
  float* out  = (float*)d_out;
  float* feat  = out;            // (256,256)
  float* out2  = out + 65536;    // (256,65)
  float* soft  = out + 82176;    // (256,65)
  float* preo  = out + 98816;    // (256,65)
  float* featp = out + 115456;   // (256,256)

  setup1<<<2610, 256, 0, stream>>>(bb, Wo1, bo1, Wo2, bo2, Wa, ba, Wps, bps,
                                   Wg, Wsp, Wox1, box1, Wox2, box2, edge, ws, featp);
  setup2<<<129, 256, 0, stream>>>(Wb, bb, ws);
  kmain<<<256, 512, 0, stream>>>(x, ws+OFF_W12T, ws+OFF_B12, ws+OFF_XL, ws+OFF_XP);
  // features_p += x_p @ Wb^T   (split-K atomic; featp pre-initialized to bb)
  gemm64<1><<<dim3(4,4,16), 256, 0, stream>>>(ws+OFF_XP, 2048, Wb, 2048, featp, 256,
                                              256, 256, 128, nullptr);
  // pre_output = features_p @ Wfc^T
  gemm64<0><<<dim3(4,2,1), 256, 0, stream>>>(featp, 256, Wfc, 256, preo, 65,
                                             256, 65, 256, nullptr);
  kpr<<<256, 128, 0, stream>>>(preo, ws+OFF_WPR, ws+OFF_VY);
  knode<<<88, 256, 0, stream>>>(Wg, node_p, ws+OFF_VY, ws+OFF_NT);
  kgraph1<<<256, 256, 0, stream>>>(ws+OFF_XL, ws+OFF_WAPT, ws+OFF_B215, ws+OFF_BUFA);
  kg<<<256, 256, 0, stream>>>(ws+OFF_BUFA, ws+OFF_WG2T, ws+OFF_NT, bg, ws+OFF_BUFB);
  km2<<<256, 256, 0, stream>>>(ws+OFF_BUFB, ws+OFF_ENP, ws+OFF_BUFA);
  ksp<<<256, 256, 0, stream>>>(ws+OFF_BUFA, ws+OFF_WSPT, bsp, Ws, ws+OFF_M3M);
  kfin<<<256, 256, 0, stream>>>(ws+OFF_M3M, ws+OFF_WC, ws+OFF_BC, featp, Wfc2,
                                feat, out2, soft);
}

// Round 2
// 876.461 us; speedup vs baseline: 1.0228x; 1.0228x over previous
//
#include <hip/hip_runtime.h>
#include <cmath>

// M=87, CLS=65, K=128, DL=DC=128, DO=2048, BD=256, B=256, HW=49

typedef __attribute__((ext_vector_type(8))) short short8;
typedef __attribute__((ext_vector_type(4))) float f32x4;

// ---------------- workspace layout (float offsets) ----------------
constexpr size_t OFF_W12BF = 0;                                // 2048*128 bf16 (= 131072 floats), [o][c]
constexpr size_t OFF_B12   = OFF_W12BF + 131072;               // 128
constexpr size_t OFF_WAPT  = OFF_B12   + 128;                  // 128x216 [c][r]
constexpr size_t OFF_B215  = OFF_WAPT  + 128*216;              // 216
constexpr size_t OFF_WG2T  = OFF_B215  + 216;                  // 128x128 [d][o]
constexpr size_t OFF_WSPT  = OFF_WG2T  + 128*128;              // 128x128 [c][o]
constexpr size_t OFF_ENP   = OFF_WSPT  + 128*128;              // 87x88
constexpr size_t OFF_WPR   = OFF_ENP   + 87*88 + 8;            // 87x87
constexpr size_t OFF_WOX21 = OFF_WPR   + 7576;                 // 2048x128 [c][d] fp32
constexpr size_t OFF_BTMP  = OFF_WOX21 + 2048*128;             // 2048
constexpr size_t OFF_WC    = OFF_BTMP  + 2048;                 // 256x128
constexpr size_t OFF_BC    = OFF_WC    + 256*128;              // 256
constexpr size_t OFF_XP    = OFF_BC    + 256;                  // 256x2048
constexpr size_t OFF_XL    = OFF_XP    + 256*2048;             // 256x128x49
constexpr size_t OFF_VY    = OFF_XL    + (size_t)256*128*49;   // 256x87
constexpr size_t OFF_NT    = OFF_VY    + 256*87 + 8;           // 2x128x88
constexpr size_t OFF_M3M   = OFF_NT    + 2*128*88;             // 256x128
constexpr size_t OFF_BUFA  = OFF_M3M   + 256*128;              // 256x128x88
constexpr size_t OFF_BUFB  = OFF_BUFA  + (size_t)256*128*88;   // 256x128x88

__device__ __forceinline__ unsigned short f2bf(float f) {
  unsigned u = __builtin_bit_cast(unsigned, f);
  u += 0x7fffu + ((u >> 16) & 1u);
  return (unsigned short)(u >> 16);
}

__device__ __forceinline__ void fma44(float (&acc)[4][4], const float4 a, const float4 b) {
  float av[4] = {a.x, a.y, a.z, a.w};
  float bv[4] = {b.x, b.y, b.z, b.w};
  #pragma unroll
  for (int i = 0; i < 4; ++i)
    #pragma unroll
    for (int j = 0; j < 4; ++j)
      acc[i][j] += av[i] * bv[j];
}

// ---------------- ksetup: small transposes / inits / zero Wc ----------------
__global__ __launch_bounds__(256) void ksetup(
    const float* __restrict__ bb,  const float* __restrict__ Wa,  const float* __restrict__ ba,
    const float* __restrict__ Wps, const float* __restrict__ bps, const float* __restrict__ Wg,
    const float* __restrict__ Wsp, const float* __restrict__ edge,
    float* __restrict__ ws, float* __restrict__ featp)
{
  int blk = blockIdx.x, tid = threadIdx.x;
  if (blk < 108) {                         // Wapt[c*216+r]
    int idx = blk*256 + tid;               // < 27648
    int c = idx / 216, r = idx % 216;
    float v;
    if (r < 128)      v = Wps[r*128 + c];
    else if (r < 215) v = Wa[(r-128)*128 + c];
    else              v = 0.f;
    ws[OFF_WAPT + idx] = v;
  } else if (blk == 108) {                 // b215
    if (tid < 216) {
      float v = (tid < 128) ? bps[tid] : (tid < 215 ? ba[tid-128] : 0.f);
      ws[OFF_B215 + tid] = v;
    }
  } else if (blk < 173) {                  // Wg2t[d*128+o] = Wg[o, 128+d]
    int idx = (blk-109)*256 + tid;
    int d = idx >> 7, o = idx & 127;
    ws[OFF_WG2T + idx] = Wg[o*256 + 128 + d];
  } else if (blk < 237) {                  // Wspt[c*128+o] = Wsp[o,c]
    int idx = (blk-173)*256 + tid;
    int c = idx >> 7, o = idx & 127;
    ws[OFF_WSPT + idx] = Wsp[o*128 + c];
  } else if (blk < 267) {                  // edge_norm padded to width 88
    int idx = (blk-237)*256 + tid;
    if (idx < 87*88) {
      int m = idx / 88, n = idx % 88;
      float v = 0.f;
      if (n < 87) {
        float sm = 0.f, sn = 0.f;
        for (int k = 0; k < 87; ++k) { sm += edge[k*87+m]; sn += edge[k*87+n]; }
        v = edge[m*87+n] / sqrtf(sm*sn);
      }
      ws[OFF_ENP + idx] = v;
    }
  } else if (blk < 297) {                  // Wpr
    int idx = (blk-267)*256 + tid;
    if (idx < 87*87) {
      int j = idx % 87;
      float rs = 0.f;
      for (int k = 0; k < 87; ++k) rs += edge[j*87+k];
      ws[OFF_WPR + idx] = 0.85f * edge[idx] / rs;
    }
  } else if (blk < 553) {                  // featp init = bb
    int idx = (blk-297)*256 + tid;
    featp[idx] = bb[idx & 255];
  } else {                                 // zero Wc (128 blocks)
    int idx = (blk-553)*256 + tid;
    ws[OFF_WC + idx] = 0.f;
  }
}

// ---------------- kwpair: W12(bf16) and Wox21(fp32), 64x64 fp32 tiles ----------------
__global__ __launch_bounds__(256) void kwpair(const float* __restrict__ Wo2, const float* __restrict__ Wo1,
                                              const float* __restrict__ Wox2, const float* __restrict__ Wox1,
                                              float* __restrict__ ws)
{
  __shared__ alignas(16) float As[16*68];
  __shared__ alignas(16) float Bs[16*68];
  int blk = blockIdx.x, tid = threadIdx.x;
  const float *A, *Bm; int lda, ldb, i0, j0, isW12;
  if (blk < 64) {  // W12[o][c] = Wo2@Wo1 : M=128,N=2048,K=512
    isW12 = 1; A = Wo2; Bm = Wo1; lda = 512; ldb = 2048;
    i0 = (blk & 1)*64; j0 = (blk >> 1)*64;
  } else {         // Wox21[c][d] = Wox2@Wox1 : M=2048,N=128,K=512
    isW12 = 0; A = Wox2; Bm = Wox1; lda = 512; ldb = 128;
    int b2 = blk - 64; i0 = (b2 >> 1)*64; j0 = (b2 & 1)*64;
  }
  int ti = tid >> 4, tj = tid & 15;
  float acc[4][4] = {};
  for (int kc = 0; kc < 512; kc += 16) {
    for (int i = tid; i < 1024; i += 256) {
      int r = i >> 4, k = i & 15;
      As[k*68 + r] = A[(size_t)(i0+r)*lda + kc + k];
    }
    for (int i = tid; i < 1024; i += 256) {
      int k = i >> 6, c = i & 63;
      Bs[k*68 + c] = Bm[(size_t)(kc+k)*ldb + j0 + c];
    }
    __syncthreads();
    #pragma unroll
    for (int k = 0; k < 16; ++k) {
      float4 a4 = *(const float4*)&As[k*68 + ti*4];
      float4 b4 = *(const float4*)&Bs[k*68 + tj*4];
      fma44(acc, a4, b4);
    }
    __syncthreads();
  }
  if (isW12) {
    unsigned short* C = (unsigned short*)(ws + OFF_W12BF);
    #pragma unroll
    for (int i = 0; i < 4; ++i)
      #pragma unroll
      for (int j = 0; j < 4; ++j)
        C[(size_t)(i0+ti*4+i)*2048 + j0+tj*4+j] = f2bf(acc[i][j]);
  } else {
    float* C = ws + OFF_WOX21;
    #pragma unroll
    for (int i = 0; i < 4; ++i)
      #pragma unroll
      for (int j = 0; j < 4; ++j)
        C[(size_t)(i0+ti*4+i)*128 + j0+tj*4+j] = acc[i][j];
  }
}

// ---------------- kvec: btmp = Wox2@box1+box2 ; b12 = Wo2@bo1+bo2 ----------------
__global__ __launch_bounds__(256) void kvec(const float* __restrict__ Wox2, const float* __restrict__ box1,
                                            const float* __restrict__ box2, const float* __restrict__ Wo2,
                                            const float* __restrict__ bo1,  const float* __restrict__ bo2,
                                            float* __restrict__ ws)
{
  int blk = blockIdx.x, tid = threadIdx.x;
  int w = tid >> 6, l = tid & 63;
  if (blk < 512) {
    int o = blk*4 + w;
    float s = 0.f;
    for (int h = l; h < 512; h += 64) s += Wox2[(size_t)o*512 + h] * box1[h];
    for (int off = 32; off; off >>= 1) s += __shfl_down(s, off, 64);
    if (l == 0) ws[OFF_BTMP + o] = s + box2[o];
  } else {
    int o = (blk - 512)*4 + w;
    float s = 0.f;
    for (int h = l; h < 512; h += 64) s += Wo2[(size_t)o*512 + h] * bo1[h];
    for (int off = 32; off; off >>= 1) s += __shfl_down(s, off, 64);
    if (l == 0) ws[OFF_B12 + o] = s + bo2[o];
  }
}

// ---------------- kwcg: Wc += Wb @ Wox21 (split-K atomic) ----------------
__global__ __launch_bounds__(256) void kwcg(const float* __restrict__ Wb, float* __restrict__ ws)
{
  __shared__ alignas(16) float As[16*68];
  __shared__ alignas(16) float Bs[16*68];
  int i0 = blockIdx.x*64, j0 = blockIdx.y*64, kc0 = blockIdx.z*256;
  const float* Bm = ws + OFF_WOX21;
  int tid = threadIdx.x, ti = tid >> 4, tj = tid & 15;
  float acc[4][4] = {};
  for (int kc = kc0; kc < kc0+256; kc += 16) {
    for (int i = tid; i < 1024; i += 256) {
      int r = i >> 4, k = i & 15;
      As[k*68 + r] = Wb[(size_t)(i0+r)*2048 + kc + k];
    }
    for (int i = tid; i < 1024; i += 256) {
      int k = i >> 6, c = i & 63;
      Bs[k*68 + c] = Bm[(size_t)(kc+k)*128 + j0 + c];
    }
    __syncthreads();
    #pragma unroll
    for (int k = 0; k < 16; ++k) {
      float4 a4 = *(const float4*)&As[k*68 + ti*4];
      float4 b4 = *(const float4*)&Bs[k*68 + tj*4];
      fma44(acc, a4, b4);
    }
    __syncthreads();
  }
  #pragma unroll
  for (int i = 0; i < 4; ++i)
    #pragma unroll
    for (int j = 0; j < 4; ++j)
      atomicAdd(&ws[OFF_WC + (size_t)(i0+ti*4+i)*128 + j0+tj*4+j], acc[i][j]);
}

// ---------------- kbc: bc = Wb@btmp + bb ----------------
__global__ __launch_bounds__(256) void kbc(const float* __restrict__ Wb, const float* __restrict__ bb,
                                           float* __restrict__ ws)
{
  int j = blockIdx.x*4 + (threadIdx.x >> 6), l = threadIdx.x & 63;
  float s = 0.f;
  for (int c = l; c < 2048; c += 64) s += Wb[(size_t)j*2048 + c] * ws[OFF_BTMP + c];
  for (int off = 32; off; off >>= 1) s += __shfl_down(s, off, 64);
  if (l == 0) ws[OFF_BC + j] = s + bb[j];
}

// ---------------- kmain2: xl = W12@x + b12 (bf16 MFMA), fused xp = mean(x) ----------------
// Per batch: D[o=128][p=64pad] = A(W12 [o][c] bf16) x B(x[b] [c][p] -> LDS [p][c] bf16)
__global__ __launch_bounds__(256) void kmain2(const float* __restrict__ x,
                                              const short* __restrict__ w12bf,
                                              const float* __restrict__ b12,
                                              float* __restrict__ xl,
                                              float* __restrict__ xp)
{
  __shared__ alignas(16) short At[128*64];   // [o][k] 16KB
  __shared__ alignas(16) short Bt[64*64];    // [p][k] 8KB (rows 49..63 garbage -> discarded cols)
  __shared__ float xps[64];
  int b = blockIdx.x, tid = threadIdx.x;
  int w = tid >> 6, l = tid & 63;
  int quad = l >> 4, lane16 = l & 15;
  f32x4 acc[2][4];
  #pragma unroll
  for (int i = 0; i < 2; ++i)
    #pragma unroll
    for (int j = 0; j < 4; ++j) acc[i][j] = (f32x4)(0.f);
  if (tid < 64) xps[tid] = 0.f;
  __syncthreads();
  const float* xb = x + (size_t)b*2048*49;
  for (int kc = 0; kc < 2048; kc += 64) {
    // stage A (W12 bf16 tile, 128x64): 1024 chunks of 8 shorts
    #pragma unroll
    for (int r = 0; r < 4; ++r) {
      int chunk = r*256 + tid;
      int row = chunk >> 3, c16 = chunk & 7;
      short8 v = *(const short8*)(w12bf + (size_t)row*2048 + kc + c16*8);
      *(short8*)(At + chunk*8) = v;
    }
    // stage B: x chunk [64c][49p] contiguous -> Bt[p][c] bf16, + xp partial sums
    for (int i4 = tid; i4 < 784; i4 += 256) {
      float4 v = *(const float4*)(xb + (size_t)kc*49 + i4*4);
      float vv[4] = {v.x, v.y, v.z, v.w};
      int e0 = i4*4;
      #pragma unroll
      for (int j = 0; j < 4; ++j) {
        int e = e0 + j, c = e/49, p = e - c*49;
        Bt[p*64 + c] = (short)f2bf(vv[j]);
        atomicAdd(&xps[c], vv[j]);
      }
    }
    __syncthreads();
    // compute: wave w covers rows [w*32, w*32+32)
    #pragma unroll
    for (int ks = 0; ks < 2; ++ks) {
      short8 a0 = *(const short8*)(At + (w*32 +      lane16)*64 + ks*32 + quad*8);
      short8 a1 = *(const short8*)(At + (w*32 + 16 + lane16)*64 + ks*32 + quad*8);
      #pragma unroll
      for (int ni = 0; ni < 4; ++ni) {
        short8 bfr = *(const short8*)(Bt + (ni*16 + lane16)*64 + ks*32 + quad*8);
        acc[0][ni] = __builtin_amdgcn_mfma_f32_16x16x32_bf16(a0, bfr, acc[0][ni], 0, 0, 0);
        acc[1][ni] = __builtin_amdgcn_mfma_f32_16x16x32_bf16(a1, bfr, acc[1][ni], 0, 0, 0);
      }
    }
    if (tid < 64) {                        // xp for this k-chunk; re-zero for next
      xp[(size_t)b*2048 + kc + tid] = xps[tid] * (1.f/49.f);
      xps[tid] = 0.f;
    }
    __syncthreads();
  }
  // epilogue: D row = quad*4+reg, col = lane16
  #pragma unroll
  for (int mi = 0; mi < 2; ++mi) {
    #pragma unroll
    for (int r = 0; r < 4; ++r) {
      int o = w*32 + mi*16 + quad*4 + r;
      float bias = b12[o];
      #pragma unroll
      for (int ni = 0; ni < 4; ++ni) {
        int p = ni*16 + lane16;
        if (p < 49)
          xl[((size_t)b*128 + o)*49 + p] = acc[mi][ni][r] + bias;
      }
    }
  }
}

// ---------------- gemm64: C(MxN) = A(MxK) @ B(NxK)^T [+bias], tile 64x64 ----------------
template<int ATOMIC>
__global__ __launch_bounds__(256) void gemm64(const float* __restrict__ A, int lda,
                                              const float* __restrict__ Bm, int ldb,
                                              float* __restrict__ C, int ldc,
                                              int Mh, int Nh, int Kz,
                                              const float* __restrict__ bias)
{
  __shared__ alignas(16) float As[16*68];
  __shared__ alignas(16) float Bs[16*68];
  int i0 = blockIdx.x*64, j0 = blockIdx.y*64;
  int kc0 = blockIdx.z*Kz;
  int ti = threadIdx.x >> 4, tj = threadIdx.x & 15;
  float acc[4][4] = {};
  for (int kc = kc0; kc < kc0 + Kz; kc += 16) {
    for (int i = threadIdx.x; i < 1024; i += 256) {
      int r = i >> 4, k = i & 15;
      As[k*68+r] = (i0 + r < Mh) ? A[(size_t)(i0+r)*lda + kc + k] : 0.f;
      Bs[k*68+r] = (j0 + r < Nh) ? Bm[(size_t)(j0+r)*ldb + kc + k] : 0.f;
    }
    __syncthreads();
    #pragma unroll
    for (int k = 0; k < 16; ++k) {
      float4 a4 = *(const float4*)&As[k*68 + ti*4];
      float4 b4 = *(const float4*)&Bs[k*68 + tj*4];
      fma44(acc, a4, b4);
    }
    __syncthreads();
  }
  #pragma unroll
  for (int i = 0; i < 4; ++i) {
    int r = i0 + ti*4 + i;
    if (r < Mh) {
      #pragma unroll
      for (int j = 0; j < 4; ++j) {
        int cc = j0 + tj*4 + j;
        if (cc < Nh) {
          float v = acc[i][j];
          if (bias) v += bias[cc];
          if (ATOMIC) atomicAdd(&C[(size_t)r*ldc + cc], v);
          else        C[(size_t)r*ldc + cc] = v;
        }
      }
    }
  }
}

// ---------------- kpr: softmax(pre_output) -> v_init -> 100 PageRank iters -> v_y ----------------
__global__ __launch_bounds__(128) void kpr(const float* __restrict__ preout,
                                           const float* __restrict__ wpr,
                                           float* __restrict__ vy)
{
  __shared__ alignas(16) float po[68];
  __shared__ alignas(16) float vs[88];
  __shared__ float red[2];
  int b = blockIdx.x, tid = threadIdx.x;
  if (tid < 65) po[tid] = preout[b*65 + tid];
  __syncthreads();
  if (tid == 0) {
    float mx = po[0];
    for (int j = 1; j < 65; ++j) mx = fmaxf(mx, po[j]);
    float sm = 0.f;
    for (int j = 0; j < 65; ++j) sm += expf(po[j]-mx);
    red[0] = mx; red[1] = 1.f/sm;
  }
  __syncthreads();
  float vinit = 0.f;
  if (tid >= 22 && tid < 87) vinit = expf(po[tid-22]-red[0]) * red[1];
  float s_i = vinit * 87.f;
  float wrow[87];
  if (tid < 87) {
    float add = s_i * (0.15f/87.0f);
    #pragma unroll
    for (int j = 0; j < 87; ++j) wrow[j] = wpr[tid*87 + j] + add;
    vs[tid] = s_i;
  }
  __syncthreads();
  for (int it = 0; it < 100; ++it) {
    float nv = 0.f;
    if (tid < 87) {
      #pragma unroll
      for (int j4 = 0; j4 < 21; ++j4) {
        float4 v4 = *(const float4*)&vs[j4*4];
        nv += wrow[j4*4+0]*v4.x + wrow[j4*4+1]*v4.y + wrow[j4*4+2]*v4.z + wrow[j4*4+3]*v4.w;
      }
      nv += wrow[84]*vs[84] + wrow[85]*vs[85] + wrow[86]*vs[86];
    }
    __syncthreads();
    if (tid < 87) vs[tid] = nv;
    __syncthreads();
  }
  if (tid == 0) {
    float ss = 0.f;
    for (int j = 0; j < 87; ++j) ss += vs[j]*vs[j];
    red[0] = 1.f / fmaxf(sqrtf(ss), 1e-12f);
  }
  __syncthreads();
  if (tid < 87) vy[b*87 + tid] = vinit + vs[tid]*red[0];
}

// ---------------- knode ----------------
__global__ __launch_bounds__(256) void knode(const float* __restrict__ Wg,
                                             const float* __restrict__ node_p,
                                             const float* __restrict__ vy,
                                             float* __restrict__ nt)
{
  int idx = blockIdx.x*256 + threadIdx.x;  // < 22528
  int par = idx / 11264;
  int r = idx % 11264;
  int o = r / 88, m = r % 88;
  float v = 0.f;
  if (m < 87) {
    float s = 0.f;
    for (int k = 0; k < 128; ++k)
      s += Wg[o*256+k] * node_p[k*87+m] * vy[(par*128+k)*87+m];
    v = s;
  }
  nt[idx] = v;
}

// ---------------- kgraph1 ----------------
__global__ __launch_bounds__(256) void kgraph1(const float* __restrict__ xl,
                                               const float* __restrict__ wapt,
                                               const float* __restrict__ b215,
                                               float* __restrict__ m1)
{
  __shared__ alignas(16) float Xs[64*68];
  __shared__ alignas(16) float At[49*220];
  int b = blockIdx.x, tid = threadIdx.x;
  int rg = tid >> 2, pg = tid & 3;
  float acc[4][16] = {};
  for (int kc = 0; kc < 128; kc += 64) {
    for (int i = tid; i < 64*64; i += 256) {
      int c = i >> 6, p = i & 63;
      Xs[c*68+p] = (p < 49) ? xl[((size_t)b*128 + kc + c)*49 + p] : 0.f;
    }
    __syncthreads();
    if (rg < 54) {
      for (int c = 0; c < 64; ++c) {
        float4 w4 = *(const float4*)&wapt[(kc+c)*216 + rg*4];
        float wv[4] = {w4.x, w4.y, w4.z, w4.w};
        #pragma unroll
        for (int q = 0; q < 4; ++q) {
          float4 x4 = *(const float4*)&Xs[c*68 + pg*16 + q*4];
          float xv[4] = {x4.x, x4.y, x4.z, x4.w};
          #pragma unroll
          for (int i = 0; i < 4; ++i)
            #pragma unroll
            for (int t = 0; t < 4; ++t)
              acc[i][q*4+t] += wv[i]*xv[t];
        }
      }
    }
    __syncthreads();
  }
  if (rg < 54) {
    #pragma unroll
    for (int i = 0; i < 4; ++i) {
      int r = rg*4 + i;
      float bias = b215[r];
      #pragma unroll
      for (int j = 0; j < 16; ++j) {
        int p = pg*16 + j;
        if (p < 49) At[p*220 + r] = acc[i][j] + bias;
      }
    }
  }
  __syncthreads();
  int dg = tid >> 3, mg = tid & 7;
  for (int pass = 0; pass < 3; ++pass) {
    int mb = pass*32 + mg*4;
    if (mb < 88) {
      float a2[4][4] = {};
      for (int p = 0; p < 49; ++p) {
        float4 psv = *(const float4*)&At[p*220 + dg*4];
        float4 av  = *(const float4*)&At[p*220 + 128 + mb];
        fma44(a2, psv, av);
      }
      #pragma unroll
      for (int i = 0; i < 4; ++i)
        #pragma unroll
        for (int j = 0; j < 4; ++j) {
          int m = mb + j;
          if (m < 88) m1[((size_t)b*128 + dg*4 + i)*88 + m] = fmaxf(a2[i][j], 0.f);
        }
    }
  }
}

// ---------------- kg ----------------
__global__ __launch_bounds__(256) void kg(const float* __restrict__ m1,
                                          const float* __restrict__ wg2t,
                                          const float* __restrict__ nt,
                                          const float* __restrict__ bg,
                                          float* __restrict__ g)
{
  __shared__ alignas(16) float S[128*88];
  int b = blockIdx.x, tid = threadIdx.x;
  { int d = tid >> 1, h = tid & 1;
    for (int j = 0; j < 44; ++j) S[d*88 + h*44 + j] = m1[((size_t)b*128 + d)*88 + h*44 + j]; }
  __syncthreads();
  int og = tid >> 3, mg = tid & 7;
  const float* ntb = nt + (size_t)(b & 1)*11264;
  for (int pass = 0; pass < 3; ++pass) {
    int mb = pass*32 + mg*4;
    if (mb < 88) {
      float acc[4][4] = {};
      for (int d = 0; d < 128; ++d) {
        float4 w4 = *(const float4*)&wg2t[d*128 + og*4];
        float4 m4 = *(const float4*)&S[d*88 + mb];
        fma44(acc, w4, m4);
      }
      #pragma unroll
      for (int i = 0; i < 4; ++i) {
        int o = og*4 + i;
        float bo = bg[o];
        #pragma unroll
        for (int j = 0; j < 4; ++j) {
          int m = mb + j;
          if (m < 88) g[((size_t)b*128 + o)*88 + m] = acc[i][j] + ntb[o*88+m] + bo;
        }
      }
    }
  }
}

// ---------------- km2 ----------------
__global__ __launch_bounds__(256) void km2(const float* __restrict__ g,
                                           const float* __restrict__ enp,
                                           float* __restrict__ m2)
{
  __shared__ alignas(16) float Gt[88*132];
  int b = blockIdx.x, tid = threadIdx.x;
  for (int i = tid; i < 128*88; i += 256) {
    int d = i / 88, m = i % 88;
    Gt[m*132 + d] = g[(size_t)b*128*88 + i];
  }
  __syncthreads();
  int cg = tid >> 3, ng = tid & 7;
  for (int pass = 0; pass < 3; ++pass) {
    int nb = pass*32 + ng*4;
    if (nb < 88) {
      float acc[4][4] = {};
      for (int m = 0; m < 87; ++m) {
        float4 g4 = *(const float4*)&Gt[m*132 + cg*4];
        float4 e4 = *(const float4*)&enp[m*88 + nb];
        fma44(acc, g4, e4);
      }
      #pragma unroll
      for (int i = 0; i < 4; ++i)
        #pragma unroll
        for (int j = 0; j < 4; ++j) {
          int n = nb + j;
          if (n < 88) m2[((size_t)b*128 + cg*4 + i)*88 + n] = fmaxf(acc[i][j], 0.f);
        }
    }
  }
}

// ---------------- ksp ----------------
__global__ __launch_bounds__(256) void ksp(const float* __restrict__ m2,
                                           const float* __restrict__ wspt,
                                           const float* __restrict__ bsp,
                                           const float* __restrict__ Ws,
                                           float* __restrict__ m3m)
{
  __shared__ alignas(16) float S[128*88];
  __shared__ float wsm[96];
  __shared__ float m3acc[128];
  __shared__ float tnb[88];
  __shared__ float redx[1];
  int b = blockIdx.x, tid = threadIdx.x;
  { int d = tid >> 1, h = tid & 1;
    for (int j = 0; j < 44; ++j) S[d*88 + h*44 + j] = m2[((size_t)b*128 + d)*88 + h*44 + j]; }
  if (tid < 96) wsm[tid] = 0.f;
  if (tid < 128) m3acc[tid] = 0.f;
  __syncthreads();
  if (tid < 87) {
    float s = 0.f;
    for (int c = 0; c < 128; ++c) s += Ws[c] * S[c*88 + tid];
    tnb[tid] = s;
  }
  __syncthreads();
  if (tid == 0) {
    float mx = tnb[0];
    for (int j = 1; j < 87; ++j) mx = fmaxf(mx, tnb[j]);
    redx[0] = mx;
  }
  __syncthreads();
  if (tid < 87) wsm[tid] = expf(tnb[tid] - redx[0]);
  __syncthreads();
  if (tid == 0) {
    float sm = 0.f;
    for (int j = 0; j < 87; ++j) sm += wsm[j];
    redx[0] = 1.f/sm;
  }
  __syncthreads();
  if (tid < 87) wsm[tid] *= redx[0];
  __syncthreads();
  int og = tid >> 3, mg = tid & 7;
  for (int pass = 0; pass < 3; ++pass) {
    int mb = pass*32 + mg*4;
    if (mb < 88) {
      float acc[4][4] = {};
      for (int d = 0; d < 128; ++d) {
        float4 w4 = *(const float4*)&wspt[d*128 + og*4];
        float4 m4 = *(const float4*)&S[d*88 + mb];
        fma44(acc, w4, m4);
      }
      #pragma unroll
      for (int i = 0; i < 4; ++i) {
        int o = og*4 + i;
        float bo = bsp[o];
        float part = 0.f;
        #pragma unroll
        for (int j = 0; j < 4; ++j) part += (acc[i][j] + bo) * wsm[mb+j];
        atomicAdd(&m3acc[o], part);
      }
    }
  }
  __syncthreads();
  if (tid < 128) m3m[b*128 + tid] = fmaxf(m3acc[tid], 0.f);
}

// ---------------- kfin ----------------
__global__ __launch_bounds__(256) void kfin(const float* __restrict__ m3m,
                                            const float* __restrict__ wc,
                                            const float* __restrict__ bc,
                                            const float* __restrict__ featp,
                                            const float* __restrict__ Wfc2,
                                            float* __restrict__ feat,
                                            float* __restrict__ out2,
                                            float* __restrict__ soft)
{
  __shared__ alignas(16) float m3s[128];
  __shared__ float fs[256];
  __shared__ float o2s[68];
  __shared__ float r2[2];
  int b = blockIdx.x, tid = threadIdx.x;
  if (tid < 128) m3s[tid] = m3m[b*128 + tid];
  __syncthreads();
  {
    float s = 0.f;
    #pragma unroll 4
    for (int d4 = 0; d4 < 32; ++d4) {
      float4 w4 = *(const float4*)&wc[tid*128 + d4*4];
      float4 m4 = *(const float4*)&m3s[d4*4];
      s += w4.x*m4.x + w4.y*m4.y + w4.z*m4.z + w4.w*m4.w;
    }
    float f = featp[b*256 + tid] + bc[tid] + s;
    fs[tid] = f;
    feat[b*256 + tid] = f;
  }
  __syncthreads();
  if (tid < 65) {
    float s = 0.f;
    for (int j = 0; j < 256; ++j) s += Wfc2[tid*256 + j] * fs[j];
    out2[b*65 + tid] = s;
    o2s[tid] = s;
  }
  __syncthreads();
  if (tid == 0) {
    float mx = o2s[0];
    for (int j = 1; j < 65; ++j) mx = fmaxf(mx, o2s[j]);
    float sm = 0.f;
    for (int j = 0; j < 65; ++j) sm += expf(o2s[j]-mx);
    r2[0] = mx; r2[1] = 1.f/sm;
  }
  __syncthreads();
  if (tid < 65) soft[b*65 + tid] = expf(o2s[tid]-r2[0]) * r2[1];
}

// ---------------- launch ----------------
extern "C" void kernel_launch(void* const* d_in, const int* in_sizes, int n_in,
                              void* d_out, int out_size, void* d_ws, size_t ws_size,
                              hipStream_t stream)
{
  (void)in_sizes; (void)n_in; (void)out_size; (void)ws_size;
  const float* x      = (const float*)d_in[0];
  const float* Wb     = (const float*)d_in[1];
  const float* bb     = (const float*)d_in[2];
  const float* Wfc    = (const float*)d_in[3];
  const float* Wfc2   = (const float*)d_in[4];
  const float* Wo1    = (const float*)d_in[5];
  const float* bo1    = (const float*)d_in[6];
  const float* Wo2    = (const float*)d_in[7];
  const float* bo2    = (const float*)d_in[8];
  const float* Wa     = (const float*)d_in[9];
  const float* ba     = (const float*)d_in[10];
  const float* Wps    = (const float*)d_in[11];
  const float* bps    = (const float*)d_in[12];
  const float* node_p = (const float*)d_in[13];
  const float* Wg     = (const float*)d_in[14];
  const float* bg     = (const float*)d_in[15];
  const float* Wsp    = (const float*)d_in[16];
  const float* bsp    = (const float*)d_in[17];
  const float* Ws     = (const float*)d_in[18];
  const float* Wox1   = (const float*)d_in[20];
  const float* box1   = (const float*)d_in[21];
  const float* Wox2   = (const float*)d_in[22];
  const float* box2   = (const float*)d_in[23];
  const float* edge   = (const float*)d_in[24];

  float* ws   = (float*)d_ws;
  float* out  = (float*)d_out;
  float* feat  = out;            // (256,256)
  float* out2  = out + 65536;    // (256,65)
  float* soft  = out + 82176;    // (256,65)
  float* preo  = out + 98816;    // (256,65)
  float* featp = out + 115456;   // (256,256)

  ksetup<<<681, 256, 0, stream>>>(bb, Wa, ba, Wps, bps, Wg, Wsp, edge, ws, featp);
  kwpair<<<128, 256, 0, stream>>>(Wo2, Wo1, Wox2, Wox1, ws);
  kvec<<<544, 256, 0, stream>>>(Wox2, box1, box2, Wo2, bo1, bo2, ws);
  kwcg<<<dim3(4,2,8), 256, 0, stream>>>(Wb, ws);
  kbc<<<64, 256, 0, stream>>>(Wb, bb, ws);
  kmain2<<<256, 256, 0, stream>>>(x, (const short*)(ws + OFF_W12BF), ws + OFF_B12,
                                  ws + OFF_XL, ws + OFF_XP);
  gemm64<1><<<dim3(4,4,16), 256, 0, stream>>>(ws+OFF_XP, 2048, Wb, 2048, featp, 256,
                                              256, 256, 128, nullptr);
  gemm64<0><<<dim3(4,2,1), 256, 0, stream>>>(featp, 256, Wfc, 256, preo, 65,
                                             256, 65, 256, nullptr);
  kpr<<<256, 128, 0, stream>>>(preo, ws+OFF_WPR, ws+OFF_VY);
  knode<<<88, 256, 0, stream>>>(Wg, node_p, ws+OFF_VY, ws+OFF_NT);
  kgraph1<<<256, 256, 0, stream>>>(ws+OFF_XL, ws+OFF_WAPT, ws+OFF_B215, ws+OFF_BUFA);
  kg<<<256, 256, 0, stream>>>(ws+OFF_BUFA, ws+OFF_WG2T, ws+OFF_NT, bg, ws+OFF_BUFB);
  km2<<<256, 256, 0, stream>>>(ws+OFF_BUFB, ws+OFF_ENP, ws+OFF_BUFA);
  ksp<<<256, 256, 0, stream>>>(ws+OFF_BUFA, ws+OFF_WSPT, bsp, Ws, ws+OFF_M3M);
  kfin<<<256, 256, 0, stream>>>(ws+OFF_M3M, ws+OFF_WC, ws+OFF_BC, featp, Wfc2,
                                feat, out2, soft);
}

// Round 3
// 689.314 us; speedup vs baseline: 1.3005x; 1.2715x over previous
//
#include <hip/hip_runtime.h>
#include <cmath>

// M=87, CLS=65, K=128, DL=DC=128, DO=2048, BD=256, B=256, HW=49

typedef __attribute__((ext_vector_type(8))) short short8;
typedef __attribute__((ext_vector_type(4))) float f32x4;

// ---------------- workspace layout (float offsets) ----------------
constexpr size_t OFF_W12BF = 0;                                // 2048*128 bf16 [o][c] (131072 floats of space)
constexpr size_t OFF_B12   = OFF_W12BF + 131072;               // 128
constexpr size_t OFF_WAPT  = OFF_B12   + 128;                  // 128x216 [c][r]
constexpr size_t OFF_B215  = OFF_WAPT  + 128*216;              // 216
constexpr size_t OFF_WG2T  = OFF_B215  + 216;                  // 128x128 [d][o]
constexpr size_t OFF_WSPT  = OFF_WG2T  + 128*128;              // 128x128 [c][o]
constexpr size_t OFF_ENP   = OFF_WSPT  + 128*128;              // 87x88 (+8 pad)
constexpr size_t OFF_WPR   = OFF_ENP   + 87*88 + 8;            // 87x87
constexpr size_t OFF_WOX21 = OFF_WPR   + 7576;                 // 2048x128 [c][d] fp32
constexpr size_t OFF_BTMP  = OFF_WOX21 + 2048*128;             // 2048
constexpr size_t OFF_WC    = OFF_BTMP  + 2048;                 // 256x128
constexpr size_t OFF_BC    = OFF_WC    + 256*128;              // 256
constexpr size_t OFF_XP    = OFF_BC    + 256;                  // 256x2048
constexpr size_t OFF_XL    = OFF_XP    + 256*2048;             // 256x128x49
constexpr size_t OFF_VY    = OFF_XL    + (size_t)256*128*49;   // 256x87
constexpr size_t OFF_NT    = OFF_VY    + 256*87 + 8;           // 2x128x88
constexpr size_t OFF_M3M   = OFF_NT    + 2*128*88;             // 256x128

__device__ __forceinline__ unsigned short f2bf(float f) {
  unsigned u = __builtin_bit_cast(unsigned, f);
  u += 0x7fffu + ((u >> 16) & 1u);
  return (unsigned short)(u >> 16);
}

__device__ __forceinline__ float bf2f(unsigned short s) {
  return __builtin_bit_cast(float, ((unsigned)s) << 16);
}

__device__ __forceinline__ void fma44(float (&acc)[4][4], const float4 a, const float4 b) {
  float av[4] = {a.x, a.y, a.z, a.w};
  float bv[4] = {b.x, b.y, b.z, b.w};
  #pragma unroll
  for (int i = 0; i < 4; ++i)
    #pragma unroll
    for (int j = 0; j < 4; ++j)
      acc[i][j] += av[i] * bv[j];
}

// ---------------- ksetup: small transposes / inits / zero Wc ----------------
__global__ __launch_bounds__(256) void ksetup(
    const float* __restrict__ bb,  const float* __restrict__ Wa,  const float* __restrict__ ba,
    const float* __restrict__ Wps, const float* __restrict__ bps, const float* __restrict__ Wg,
    const float* __restrict__ Wsp, const float* __restrict__ edge,
    float* __restrict__ ws, float* __restrict__ featp)
{
  int blk = blockIdx.x, tid = threadIdx.x;
  if (blk < 108) {                         // Wapt[c*216+r]
    int idx = blk*256 + tid;
    int c = idx / 216, r = idx % 216;
    float v;
    if (r < 128)      v = Wps[r*128 + c];
    else if (r < 215) v = Wa[(r-128)*128 + c];
    else              v = 0.f;
    ws[OFF_WAPT + idx] = v;
  } else if (blk == 108) {                 // b215
    if (tid < 216) {
      float v = (tid < 128) ? bps[tid] : (tid < 215 ? ba[tid-128] : 0.f);
      ws[OFF_B215 + tid] = v;
    }
  } else if (blk < 173) {                  // Wg2t[d*128+o] = Wg[o, 128+d]
    int idx = (blk-109)*256 + tid;
    int d = idx >> 7, o = idx & 127;
    ws[OFF_WG2T + idx] = Wg[o*256 + 128 + d];
  } else if (blk < 237) {                  // Wspt[c*128+o] = Wsp[o,c]
    int idx = (blk-173)*256 + tid;
    int c = idx >> 7, o = idx & 127;
    ws[OFF_WSPT + idx] = Wsp[o*128 + c];
  } else if (blk < 267) {                  // edge_norm padded to width 88
    int idx = (blk-237)*256 + tid;
    if (idx < 87*88) {
      int m = idx / 88, n = idx % 88;
      float v = 0.f;
      if (n < 87) {
        float sm = 0.f, sn = 0.f;
        for (int k = 0; k < 87; ++k) { sm += edge[k*87+m]; sn += edge[k*87+n]; }
        v = edge[m*87+n] / sqrtf(sm*sn);
      }
      ws[OFF_ENP + idx] = v;
    }
  } else if (blk < 297) {                  // Wpr
    int idx = (blk-267)*256 + tid;
    if (idx < 87*87) {
      int j = idx % 87;
      float rs = 0.f;
      for (int k = 0; k < 87; ++k) rs += edge[j*87+k];
      ws[OFF_WPR + idx] = 0.85f * edge[idx] / rs;
    }
  } else if (blk < 553) {                  // featp init = bb
    int idx = (blk-297)*256 + tid;
    featp[idx] = bb[idx & 255];
  } else {                                 // zero Wc (128 blocks)
    int idx = (blk-553)*256 + tid;
    ws[OFF_WC + idx] = 0.f;
  }
}

// ---------------- kwpair: W12(bf16) and Wox21(fp32), 64x64 fp32 tiles ----------------
__global__ __launch_bounds__(256) void kwpair(const float* __restrict__ Wo2, const float* __restrict__ Wo1,
                                              const float* __restrict__ Wox2, const float* __restrict__ Wox1,
                                              float* __restrict__ ws)
{
  __shared__ alignas(16) float As[16*68];
  __shared__ alignas(16) float Bs[16*68];
  int blk = blockIdx.x, tid = threadIdx.x;
  const float *A, *Bm; int lda, ldb, i0, j0, isW12;
  if (blk < 64) {  // W12[o][c] = Wo2@Wo1 : M=128,N=2048,K=512
    isW12 = 1; A = Wo2; Bm = Wo1; lda = 512; ldb = 2048;
    i0 = (blk & 1)*64; j0 = (blk >> 1)*64;
  } else {         // Wox21[c][d] = Wox2@Wox1 : M=2048,N=128,K=512
    isW12 = 0; A = Wox2; Bm = Wox1; lda = 512; ldb = 128;
    int b2 = blk - 64; i0 = (b2 >> 1)*64; j0 = (b2 & 1)*64;
  }
  int ti = tid >> 4, tj = tid & 15;
  float acc[4][4] = {};
  for (int kc = 0; kc < 512; kc += 16) {
    for (int i = tid; i < 1024; i += 256) {
      int r = i >> 4, k = i & 15;
      As[k*68 + r] = A[(size_t)(i0+r)*lda + kc + k];
    }
    for (int i = tid; i < 1024; i += 256) {
      int k = i >> 6, c = i & 63;
      Bs[k*68 + c] = Bm[(size_t)(kc+k)*ldb + j0 + c];
    }
    __syncthreads();
    #pragma unroll
    for (int k = 0; k < 16; ++k) {
      float4 a4 = *(const float4*)&As[k*68 + ti*4];
      float4 b4 = *(const float4*)&Bs[k*68 + tj*4];
      fma44(acc, a4, b4);
    }
    __syncthreads();
  }
  if (isW12) {
    unsigned short* C = (unsigned short*)(ws + OFF_W12BF);
    #pragma unroll
    for (int i = 0; i < 4; ++i)
      #pragma unroll
      for (int j = 0; j < 4; ++j)
        C[(size_t)(i0+ti*4+i)*2048 + j0+tj*4+j] = f2bf(acc[i][j]);
  } else {
    float* C = ws + OFF_WOX21;
    #pragma unroll
    for (int i = 0; i < 4; ++i)
      #pragma unroll
      for (int j = 0; j < 4; ++j)
        C[(size_t)(i0+ti*4+i)*128 + j0+tj*4+j] = acc[i][j];
  }
}

// ---------------- kvec: btmp = Wox2@box1+box2 ; b12 = Wo2@bo1+bo2 ----------------
__global__ __launch_bounds__(256) void kvec(const float* __restrict__ Wox2, const float* __restrict__ box1,
                                            const float* __restrict__ box2, const float* __restrict__ Wo2,
                                            const float* __restrict__ bo1,  const float* __restrict__ bo2,
                                            float* __restrict__ ws)
{
  int blk = blockIdx.x, tid = threadIdx.x;
  int w = tid >> 6, l = tid & 63;
  if (blk < 512) {
    int o = blk*4 + w;
    float s = 0.f;
    for (int h = l; h < 512; h += 64) s += Wox2[(size_t)o*512 + h] * box1[h];
    for (int off = 32; off; off >>= 1) s += __shfl_down(s, off, 64);
    if (l == 0) ws[OFF_BTMP + o] = s + box2[o];
  } else {
    int o = (blk - 512)*4 + w;
    float s = 0.f;
    for (int h = l; h < 512; h += 64) s += Wo2[(size_t)o*512 + h] * bo1[h];
    for (int off = 32; off; off >>= 1) s += __shfl_down(s, off, 64);
    if (l == 0) ws[OFF_B12 + o] = s + bo2[o];
  }
}

// ---------------- kwcg: Wc += Wb @ Wox21 (split-K atomic) ----------------
__global__ __launch_bounds__(256) void kwcg(const float* __restrict__ Wb, float* __restrict__ ws)
{
  __shared__ alignas(16) float As[16*68];
  __shared__ alignas(16) float Bs[16*68];
  int i0 = blockIdx.x*64, j0 = blockIdx.y*64, kc0 = blockIdx.z*256;
  const float* Bm = ws + OFF_WOX21;
  int tid = threadIdx.x, ti = tid >> 4, tj = tid & 15;
  float acc[4][4] = {};
  for (int kc = kc0; kc < kc0+256; kc += 16) {
    for (int i = tid; i < 1024; i += 256) {
      int r = i >> 4, k = i & 15;
      As[k*68 + r] = Wb[(size_t)(i0+r)*2048 + kc + k];
    }
    for (int i = tid; i < 1024; i += 256) {
      int k = i >> 6, c = i & 63;
      Bs[k*68 + c] = Bm[(size_t)(kc+k)*128 + j0 + c];
    }
    __syncthreads();
    #pragma unroll
    for (int k = 0; k < 16; ++k) {
      float4 a4 = *(const float4*)&As[k*68 + ti*4];
      float4 b4 = *(const float4*)&Bs[k*68 + tj*4];
      fma44(acc, a4, b4);
    }
    __syncthreads();
  }
  #pragma unroll
  for (int i = 0; i < 4; ++i)
    #pragma unroll
    for (int j = 0; j < 4; ++j)
      atomicAdd(&ws[OFF_WC + (size_t)(i0+ti*4+i)*128 + j0+tj*4+j], acc[i][j]);
}

// ---------------- kbc: bc = Wb@btmp + bb ----------------
__global__ __launch_bounds__(256) void kbc(const float* __restrict__ Wb, const float* __restrict__ bb,
                                           float* __restrict__ ws)
{
  int j = blockIdx.x*4 + (threadIdx.x >> 6), l = threadIdx.x & 63;
  float s = 0.f;
  for (int c = l; c < 2048; c += 64) s += Wb[(size_t)j*2048 + c] * ws[OFF_BTMP + c];
  for (int off = 32; off; off >>= 1) s += __shfl_down(s, off, 64);
  if (l == 0) ws[OFF_BC + j] = s + bb[j];
}

// ---------------- kmain3: xl = W12@x + b12 (bf16 MFMA), transpose-on-gather ----------------
// Per batch b: D[o=128][p] = A(W12 [o][c]) x B(x[b] -> LDS Bt[p][c] bf16).
// Gather: task (p, c-oct): 8 stride-49 dword loads (lanes cover contiguous row
// segments -> coalesced), pack bf16 in regs, one aligned b128 LDS write.
// Register double-buffer: next chunk's loads issued before this chunk's MFMAs.
__global__ __launch_bounds__(256) void kmain3(const float* __restrict__ x,
                                              const short* __restrict__ w12bf,
                                              const float* __restrict__ b12,
                                              float* __restrict__ xl,
                                              float* __restrict__ xp)
{
  __shared__ alignas(16) short Bt[2][52*72];   // [p][c64] bf16, stride 72 shorts (144B)
  int b = blockIdx.x, tid = threadIdx.x;
  int w = tid >> 6, l = tid & 63;
  int quad = l >> 4, lane16 = l & 15;
  const float* xb = x + (size_t)b*2048*49;

  int p0 = tid % 49, oct0 = tid / 49;        // task tid
  int t1 = tid + 256;
  int p1 = t1 % 49, oct1 = t1 / 49;          // task tid+256 (tid<136)
  bool has1 = (tid < 136);

  float g0[8], g1[8];
  #pragma unroll
  for (int j = 0; j < 8; ++j) g0[j] = xb[(size_t)(oct0*8+j)*49 + p0];
  if (has1) {
    #pragma unroll
    for (int j = 0; j < 8; ++j) g1[j] = xb[(size_t)(oct1*8+j)*49 + p1];
  }

  f32x4 acc[2][4];
  #pragma unroll
  for (int i = 0; i < 2; ++i)
    #pragma unroll
    for (int j = 0; j < 4; ++j) acc[i][j] = (f32x4)(0.f);

  for (int kci = 0; kci < 32; ++kci) {
    int kc = kci*64;
    short* bt = Bt[kci & 1];
    {
      short8 v;
      #pragma unroll
      for (int j = 0; j < 8; ++j) v[j] = (short)f2bf(g0[j]);
      *(short8*)(bt + p0*72 + oct0*8) = v;
    }
    if (has1) {
      short8 v;
      #pragma unroll
      for (int j = 0; j < 8; ++j) v[j] = (short)f2bf(g1[j]);
      *(short8*)(bt + p1*72 + oct1*8) = v;
    }
    __syncthreads();
    // prefetch next chunk into regs (overlaps this chunk's MFMAs)
    if (kci < 31) {
      const float* xc = xb + (size_t)(kc+64)*49;
      #pragma unroll
      for (int j = 0; j < 8; ++j) g0[j] = xc[(size_t)(oct0*8+j)*49 + p0];
      if (has1) {
        #pragma unroll
        for (int j = 0; j < 8; ++j) g1[j] = xc[(size_t)(oct1*8+j)*49 + p1];
      }
    }
    // A fragments straight from global (L2-resident, identical across blocks)
    const short* wr = w12bf + (size_t)(w*32 + lane16)*2048 + kc + quad*8;
    short8 a00 = *(const short8*)(wr);
    short8 a01 = *(const short8*)(wr + 32);
    short8 a10 = *(const short8*)(wr + 16*2048);
    short8 a11 = *(const short8*)(wr + 16*2048 + 32);
    #pragma unroll
    for (int ni = 0; ni < 4; ++ni) {
      const short* br = bt + (ni*16 + lane16)*72 + quad*8;
      short8 b0 = *(const short8*)(br);
      short8 b1 = *(const short8*)(br + 32);
      acc[0][ni] = __builtin_amdgcn_mfma_f32_16x16x32_bf16(a00, b0, acc[0][ni], 0, 0, 0);
      acc[1][ni] = __builtin_amdgcn_mfma_f32_16x16x32_bf16(a10, b0, acc[1][ni], 0, 0, 0);
      acc[0][ni] = __builtin_amdgcn_mfma_f32_16x16x32_bf16(a01, b1, acc[0][ni], 0, 0, 0);
      acc[1][ni] = __builtin_amdgcn_mfma_f32_16x16x32_bf16(a11, b1, acc[1][ni], 0, 0, 0);
    }
    // fused xp (bf16 partials; stride-144B b16 reads, 2 lanes/bank = free)
    if (tid < 64) {
      float s = 0.f;
      for (int p = 0; p < 49; ++p)
        s += bf2f((unsigned short)bt[p*72 + tid]);
      xp[(size_t)b*2048 + kc + tid] = s * (1.f/49.f);
    }
    // no second barrier: next iter writes the other buffer; parity + the single
    // barrier per iter orders all reuse of this buffer.
  }
  // epilogue: D row = quad*4+reg, col = lane16
  #pragma unroll
  for (int mi = 0; mi < 2; ++mi) {
    #pragma unroll
    for (int r = 0; r < 4; ++r) {
      int o = w*32 + mi*16 + quad*4 + r;
      float bias = b12[o];
      #pragma unroll
      for (int ni = 0; ni < 4; ++ni) {
        int p = ni*16 + lane16;
        if (p < 49)
          xl[((size_t)b*128 + o)*49 + p] = acc[mi][ni][r] + bias;
      }
    }
  }
}

// ---------------- gemm64: C(MxN) = A(MxK) @ B(NxK)^T [+bias], tile 64x64 ----------------
template<int ATOMIC>
__global__ __launch_bounds__(256) void gemm64(const float* __restrict__ A, int lda,
                                              const float* __restrict__ Bm, int ldb,
                                              float* __restrict__ C, int ldc,
                                              int Mh, int Nh, int Kz,
                                              const float* __restrict__ bias)
{
  __shared__ alignas(16) float As[16*68];
  __shared__ alignas(16) float Bs[16*68];
  int i0 = blockIdx.x*64, j0 = blockIdx.y*64;
  int kc0 = blockIdx.z*Kz;
  int ti = threadIdx.x >> 4, tj = threadIdx.x & 15;
  float acc[4][4] = {};
  for (int kc = kc0; kc < kc0 + Kz; kc += 16) {
    for (int i = threadIdx.x; i < 1024; i += 256) {
      int r = i >> 4, k = i & 15;
      As[k*68+r] = (i0 + r < Mh) ? A[(size_t)(i0+r)*lda + kc + k] : 0.f;
      Bs[k*68+r] = (j0 + r < Nh) ? Bm[(size_t)(j0+r)*ldb + kc + k] : 0.f;
    }
    __syncthreads();
    #pragma unroll
    for (int k = 0; k < 16; ++k) {
      float4 a4 = *(const float4*)&As[k*68 + ti*4];
      float4 b4 = *(const float4*)&Bs[k*68 + tj*4];
      fma44(acc, a4, b4);
    }
    __syncthreads();
  }
  #pragma unroll
  for (int i = 0; i < 4; ++i) {
    int r = i0 + ti*4 + i;
    if (r < Mh) {
      #pragma unroll
      for (int j = 0; j < 4; ++j) {
        int cc = j0 + tj*4 + j;
        if (cc < Nh) {
          float v = acc[i][j];
          if (bias) v += bias[cc];
          if (ATOMIC) atomicAdd(&C[(size_t)r*ldc + cc], v);
          else        C[(size_t)r*ldc + cc] = v;
        }
      }
    }
  }
}

// ---------------- kpr: softmax(pre_output) -> v_init -> 100 PageRank iters -> v_y ----------------
__global__ __launch_bounds__(128) void kpr(const float* __restrict__ preout,
                                           const float* __restrict__ wpr,
                                           float* __restrict__ vy)
{
  __shared__ alignas(16) float po[68];
  __shared__ alignas(16) float vs[88];
  __shared__ float red[2];
  int b = blockIdx.x, tid = threadIdx.x;
  if (tid < 65) po[tid] = preout[b*65 + tid];
  __syncthreads();
  if (tid == 0) {
    float mx = po[0];
    for (int j = 1; j < 65; ++j) mx = fmaxf(mx, po[j]);
    float sm = 0.f;
    for (int j = 0; j < 65; ++j) sm += expf(po[j]-mx);
    red[0] = mx; red[1] = 1.f/sm;
  }
  __syncthreads();
  float vinit = 0.f;
  if (tid >= 22 && tid < 87) vinit = expf(po[tid-22]-red[0]) * red[1];
  float s_i = vinit * 87.f;
  float wrow[87];
  if (tid < 87) {
    float add = s_i * (0.15f/87.0f);
    #pragma unroll
    for (int j = 0; j < 87; ++j) wrow[j] = wpr[tid*87 + j] + add;
    vs[tid] = s_i;
  }
  __syncthreads();
  for (int it = 0; it < 100; ++it) {
    float nv = 0.f;
    if (tid < 87) {
      #pragma unroll
      for (int j4 = 0; j4 < 21; ++j4) {
        float4 v4 = *(const float4*)&vs[j4*4];
        nv += wrow[j4*4+0]*v4.x + wrow[j4*4+1]*v4.y + wrow[j4*4+2]*v4.z + wrow[j4*4+3]*v4.w;
      }
      nv += wrow[84]*vs[84] + wrow[85]*vs[85] + wrow[86]*vs[86];
    }
    __syncthreads();
    if (tid < 87) vs[tid] = nv;
    __syncthreads();
  }
  if (tid == 0) {
    float ss = 0.f;
    for (int j = 0; j < 87; ++j) ss += vs[j]*vs[j];
    red[0] = 1.f / fmaxf(sqrtf(ss), 1e-12f);
  }
  __syncthreads();
  if (tid < 87) vy[b*87 + tid] = vinit + vs[tid]*red[0];
}

// ---------------- knode ----------------
__global__ __launch_bounds__(256) void knode(const float* __restrict__ Wg,
                                             const float* __restrict__ node_p,
                                             const float* __restrict__ vy,
                                             float* __restrict__ nt)
{
  int idx = blockIdx.x*256 + threadIdx.x;  // < 22528
  int par = idx / 11264;
  int r = idx % 11264;
  int o = r / 88, m = r % 88;
  float v = 0.f;
  if (m < 87) {
    float s = 0.f;
    for (int k = 0; k < 128; ++k)
      s += Wg[o*256+k] * node_p[k*87+m] * vy[(par*128+k)*87+m];
    v = s;
  }
  nt[idx] = v;
}

// ---------------- kgraph_all: fused kgraph1 + kg + km2 + ksp ----------------
// dynamic LDS layout (floats):
//   At  [0 .. 10780)        49x220 projections (phase 1)     / GT 88x132 (phase 3)
//   Xs  [10780 .. 15132)    64x68 xl staging (phase 1)
//   M1  [15132 .. 26396)    128x88 (phase 1 out)             / M2 (phase 3 out)
//   G   [26396 .. 37660)    128x88 (phase 2 out)
//   wsm [37660..37756) m3acc[..37884) tnb[..37972) redx[..37976)
__global__ __launch_bounds__(256) void kgraph_all(const float* __restrict__ xl,
    const float* __restrict__ wapt, const float* __restrict__ b215,
    const float* __restrict__ wg2t, const float* __restrict__ nt, const float* __restrict__ bg,
    const float* __restrict__ enp,
    const float* __restrict__ wspt, const float* __restrict__ bsp, const float* __restrict__ Ws,
    float* __restrict__ m3m)
{
  extern __shared__ float sm[];
  float* At = sm;
  float* Xs = sm + 10780;
  float* M1 = sm + 15132;
  float* G  = sm + 26396;
  float* GT = sm;
  float* M2 = sm + 15132;
  float* wsm   = sm + 37660;
  float* m3acc = sm + 37756;
  float* tnb   = sm + 37884;
  float* redx  = sm + 37972;
  int b = blockIdx.x, tid = threadIdx.x;

  // ---------- phase 1a: At[p][r] = (Wps;Wa) proj of xl + bias ----------
  {
    int rg = tid >> 2, pg = tid & 3;
    float acc[4][16] = {};
    for (int kc = 0; kc < 128; kc += 64) {
      for (int i = tid; i < 64*64; i += 256) {
        int c = i >> 6, p = i & 63;
        Xs[c*68+p] = (p < 49) ? xl[((size_t)b*128 + kc + c)*49 + p] : 0.f;
      }
      __syncthreads();
      if (rg < 54) {
        for (int c = 0; c < 64; ++c) {
          float4 w4 = *(const float4*)&wapt[(kc+c)*216 + rg*4];
          float wv[4] = {w4.x, w4.y, w4.z, w4.w};
          #pragma unroll
          for (int q = 0; q < 4; ++q) {
            float4 x4 = *(const float4*)&Xs[c*68 + pg*16 + q*4];
            float xv[4] = {x4.x, x4.y, x4.z, x4.w};
            #pragma unroll
            for (int i = 0; i < 4; ++i)
              #pragma unroll
              for (int t = 0; t < 4; ++t)
                acc[i][q*4+t] += wv[i]*xv[t];
          }
        }
      }
      __syncthreads();
    }
    if (rg < 54) {
      #pragma unroll
      for (int i = 0; i < 4; ++i) {
        int r = rg*4 + i;
        float bias = b215[r];
        #pragma unroll
        for (int j = 0; j < 16; ++j) {
          int p = pg*16 + j;
          if (p < 49) At[p*220 + r] = acc[i][j] + bias;
        }
      }
    }
  }
  __syncthreads();
  // ---------- phase 1b: M1[d][m] = relu(sum_p ps[d][p]*a[m][p]) ----------
  {
    int dg = tid >> 3, mg = tid & 7;
    for (int pass = 0; pass < 3; ++pass) {
      int mb = pass*32 + mg*4;
      if (mb < 88) {
        float a2[4][4] = {};
        for (int p = 0; p < 49; ++p) {
          float4 psv = *(const float4*)&At[p*220 + dg*4];
          float4 av  = *(const float4*)&At[p*220 + 128 + mb];
          fma44(a2, psv, av);
        }
        #pragma unroll
        for (int i = 0; i < 4; ++i)
          #pragma unroll
          for (int j = 0; j < 4; ++j) {
            int m = mb + j;
            if (m < 88) M1[(dg*4 + i)*88 + m] = fmaxf(a2[i][j], 0.f);
          }
      }
    }
  }
  __syncthreads();
  // ---------- phase 2: G = Wg2@M1 + nt[b&1] + bg (merged 3 passes) ----------
  {
    int og = tid >> 3, mg = tid & 7;
    float acc[4][12] = {};
    for (int d = 0; d < 128; ++d) {
      float4 w4 = *(const float4*)&wg2t[d*128 + og*4];
      float wv[4] = {w4.x, w4.y, w4.z, w4.w};
      #pragma unroll
      for (int pass = 0; pass < 3; ++pass) {
        float4 m4 = *(const float4*)&M1[d*88 + pass*32 + mg*4];
        float mv[4] = {m4.x, m4.y, m4.z, m4.w};
        #pragma unroll
        for (int i = 0; i < 4; ++i)
          #pragma unroll
          for (int j = 0; j < 4; ++j)
            acc[i][pass*4+j] += wv[i]*mv[j];
      }
    }
    const float* ntb = nt + (size_t)(b & 1)*11264;
    #pragma unroll
    for (int i = 0; i < 4; ++i) {
      int o = og*4 + i;
      float bo = bg[o];
      #pragma unroll
      for (int pass = 0; pass < 3; ++pass)
        #pragma unroll
        for (int j = 0; j < 4; ++j) {
          int m = pass*32 + mg*4 + j;
          if (m < 88) G[o*88 + m] = acc[i][pass*4+j] + ntb[o*88+m] + bo;
        }
    }
  }
  __syncthreads();
  // ---------- phase 3a: GT[m][d] = G[d][m] ----------
  for (int i = tid; i < 128*88; i += 256) {
    int d = i / 88, m = i % 88;
    GT[m*132 + d] = G[i];
  }
  __syncthreads();
  // ---------- phase 3b: M2 = relu(GT x edge_norm) (merged passes) + phase-4 inits ----------
  {
    int cg = tid >> 3, ng = tid & 7;
    float acc[4][12] = {};
    for (int m = 0; m < 87; ++m) {
      float4 g4 = *(const float4*)&GT[m*132 + cg*4];
      float gv[4] = {g4.x, g4.y, g4.z, g4.w};
      #pragma unroll
      for (int pass = 0; pass < 3; ++pass) {
        float4 e4 = *(const float4*)&enp[m*88 + pass*32 + ng*4];
        float ev[4] = {e4.x, e4.y, e4.z, e4.w};
        #pragma unroll
        for (int i = 0; i < 4; ++i)
          #pragma unroll
          for (int j = 0; j < 4; ++j)
            acc[i][pass*4+j] += gv[i]*ev[j];
      }
    }
    #pragma unroll
    for (int i = 0; i < 4; ++i)
      #pragma unroll
      for (int pass = 0; pass < 3; ++pass)
        #pragma unroll
        for (int j = 0; j < 4; ++j) {
          int n = pass*32 + ng*4 + j;
          if (n < 88) M2[(cg*4 + i)*88 + n] = fmaxf(acc[i][pass*4+j], 0.f);
        }
    if (tid < 96) wsm[tid] = 0.f;
    if (tid < 128) m3acc[tid] = 0.f;
  }
  __syncthreads();
  // ---------- phase 4: node softmax + m3mean ----------
  if (tid < 87) {
    float s = 0.f;
    for (int c = 0; c < 128; ++c) s += Ws[c] * M2[c*88 + tid];
    tnb[tid] = s;
  }
  __syncthreads();
  if (tid == 0) {
    float mx = tnb[0];
    for (int j = 1; j < 87; ++j) mx = fmaxf(mx, tnb[j]);
    redx[0] = mx;
  }
  __syncthreads();
  if (tid < 87) wsm[tid] = expf(tnb[tid] - redx[0]);
  __syncthreads();
  if (tid == 0) {
    float smv = 0.f;
    for (int j = 0; j < 87; ++j) smv += wsm[j];
    redx[0] = 1.f/smv;
  }
  __syncthreads();
  if (tid < 87) wsm[tid] *= redx[0];
  __syncthreads();
  {
    int og = tid >> 3, mg = tid & 7;
    float acc[4][12] = {};
    for (int d = 0; d < 128; ++d) {
      float4 w4 = *(const float4*)&wspt[d*128 + og*4];
      float wv[4] = {w4.x, w4.y, w4.z, w4.w};
      #pragma unroll
      for (int pass = 0; pass < 3; ++pass) {
        float4 m4 = *(const float4*)&M2[d*88 + pass*32 + mg*4];
        float mv[4] = {m4.x, m4.y, m4.z, m4.w};
        #pragma unroll
        for (int i = 0; i < 4; ++i)
          #pragma unroll
          for (int j = 0; j < 4; ++j)
            acc[i][pass*4+j] += wv[i]*mv[j];
      }
    }
    #pragma unroll
    for (int i = 0; i < 4; ++i) {
      int o = og*4 + i;
      float bo = bsp[o];
      #pragma unroll
      for (int pass = 0; pass < 3; ++pass) {
        int mb = pass*32 + mg*4;
        float part = 0.f;
        #pragma unroll
        for (int j = 0; j < 4; ++j)
          part += (acc[i][pass*4+j] + bo) * wsm[mb+j];   // wsm[m>=88]=0
        atomicAdd(&m3acc[o], part);
      }
    }
  }
  __syncthreads();
  if (tid < 128) m3m[b*128 + tid] = fmaxf(m3acc[tid], 0.f);
}

// ---------------- kfin ----------------
__global__ __launch_bounds__(256) void kfin(const float* __restrict__ m3m,
                                            const float* __restrict__ wc,
                                            const float* __restrict__ bc,
                                            const float* __restrict__ featp,
                                            const float* __restrict__ Wfc2,
                                            float* __restrict__ feat,
                                            float* __restrict__ out2,
                                            float* __restrict__ soft)
{
  __shared__ alignas(16) float m3s[128];
  __shared__ float fs[256];
  __shared__ float o2s[68];
  __shared__ float r2[2];
  int b = blockIdx.x, tid = threadIdx.x;
  if (tid < 128) m3s[tid] = m3m[b*128 + tid];
  __syncthreads();
  {
    float s = 0.f;
    #pragma unroll 4
    for (int d4 = 0; d4 < 32; ++d4) {
      float4 w4 = *(const float4*)&wc[tid*128 + d4*4];
      float4 m4 = *(const float4*)&m3s[d4*4];
      s += w4.x*m4.x + w4.y*m4.y + w4.z*m4.z + w4.w*m4.w;
    }
    float f = featp[b*256 + tid] + bc[tid] + s;
    fs[tid] = f;
    feat[b*256 + tid] = f;
  }
  __syncthreads();
  if (tid < 65) {
    float s = 0.f;
    for (int j = 0; j < 256; ++j) s += Wfc2[tid*256 + j] * fs[j];
    out2[b*65 + tid] = s;
    o2s[tid] = s;
  }
  __syncthreads();
  if (tid == 0) {
    float mx = o2s[0];
    for (int j = 1; j < 65; ++j) mx = fmaxf(mx, o2s[j]);
    float sm = 0.f;
    for (int j = 0; j < 65; ++j) sm += expf(o2s[j]-mx);
    r2[0] = mx; r2[1] = 1.f/sm;
  }
  __syncthreads();
  if (tid < 65) soft[b*65 + tid] = expf(o2s[tid]-r2[0]) * r2[1];
}

// ---------------- launch ----------------
extern "C" void kernel_launch(void* const* d_in, const int* in_sizes, int n_in,
                              void* d_out, int out_size, void* d_ws, size_t ws_size,
                              hipStream_t stream)
{
  (void)in_sizes; (void)n_in; (void)out_size; (void)ws_size;
  const float* x      = (const float*)d_in[0];
  const float* Wb     = (const float*)d_in[1];
  const float* bb     = (const float*)d_in[2];
  const float* Wfc    = (const float*)d_in[3];
  const float* Wfc2   = (const float*)d_in[4];
  const float* Wo1    = (const float*)d_in[5];
  const float* bo1    = (const float*)d_in[6];
  const float* Wo2    = (const float*)d_in[7];
  const float* bo2    = (const float*)d_in[8];
  const float* Wa     = (const float*)d_in[9];
  const float* ba     = (const float*)d_in[10];
  const float* Wps    = (const float*)d_in[11];
  const float* bps    = (const float*)d_in[12];
  const float* node_p = (const float*)d_in[13];
  const float* Wg     = (const float*)d_in[14];
  const float* bg     = (const float*)d_in[15];
  const float* Wsp    = (const float*)d_in[16];
  const float* bsp    = (const float*)d_in[17];
  const float* Ws     = (const float*)d_in[18];
  const float* Wox1   = (const float*)d_in[20];
  const float* box1   = (const float*)d_in[21];
  const float* Wox2   = (const float*)d_in[22];
  const float* box2   = (const float*)d_in[23];
  const float* edge   = (const float*)d_in[24];

  float* ws   = (float*)d_ws;
  float* out  = (float*)d_out;
  float* feat  = out;            // (256,256)
  float* out2  = out + 65536;    // (256,65)
  float* soft  = out + 82176;    // (256,65)
  float* preo  = out + 98816;    // (256,65)
  float* featp = out + 115456;   // (256,256)

  ksetup<<<681, 256, 0, stream>>>(bb, Wa, ba, Wps, bps, Wg, Wsp, edge, ws, featp);
  kwpair<<<128, 256, 0, stream>>>(Wo2, Wo1, Wox2, Wox1, ws);
  kvec<<<544, 256, 0, stream>>>(Wox2, box1, box2, Wo2, bo1, bo2, ws);
  kwcg<<<dim3(4,2,8), 256, 0, stream>>>(Wb, ws);
  kbc<<<64, 256, 0, stream>>>(Wb, bb, ws);
  kmain3<<<256, 256, 0, stream>>>(x, (const short*)(ws + OFF_W12BF), ws + OFF_B12,
                                  ws + OFF_XL, ws + OFF_XP);
  gemm64<1><<<dim3(4,4,16), 256, 0, stream>>>(ws+OFF_XP, 2048, Wb, 2048, featp, 256,
                                              256, 256, 128, nullptr);
  gemm64<0><<<dim3(4,2,1), 256, 0, stream>>>(featp, 256, Wfc, 256, preo, 65,
                                             256, 65, 256, nullptr);
  kpr<<<256, 128, 0, stream>>>(preo, ws+OFF_WPR, ws+OFF_VY);
  knode<<<88, 256, 0, stream>>>(Wg, node_p, ws+OFF_VY, ws+OFF_NT);
  kgraph_all<<<256, 256, 37976*4, stream>>>(ws+OFF_XL, ws+OFF_WAPT, ws+OFF_B215,
                                            ws+OFF_WG2T, ws+OFF_NT, bg, ws+OFF_ENP,
                                            ws+OFF_WSPT, bsp, Ws, ws+OFF_M3M);
  kfin<<<256, 256, 0, stream>>>(ws+OFF_M3M, ws+OFF_WC, ws+OFF_BC, featp, Wfc2,
                                feat, out2, soft);
}

// Round 4
// 439.504 us; speedup vs baseline: 2.0397x; 1.5684x over previous
//
#include <hip/hip_runtime.h>
#include <cmath>

// M=87, CLS=65, K=128, DL=DC=128, DO=2048, BD=256, B=256, HW=49

typedef __attribute__((ext_vector_type(8))) short short8;
typedef __attribute__((ext_vector_type(4))) short s16x4;
typedef __attribute__((ext_vector_type(4))) float f32x4;

// ---------------- workspace layout (float offsets) ----------------
constexpr size_t OFF_W12BF = 0;          // [128][2048] bf16
constexpr size_t OFF_T1BF  = 131072;     // [2048][128] bf16 (Wox2@Wox1)
constexpr size_t OFF_WBBF  = 262144;     // [256][2048] bf16
constexpr size_t OFF_XPBF  = 524288;     // [256][2048] bf16
constexpr size_t OFF_XLT   = 786432;     // [256][64][128] bf16 (xl transposed)
constexpr size_t OFF_WAPBF = 1835008;    // [224][128] bf16 (Wps;Wa;0)
constexpr size_t OFF_WG2BF = 1849344;    // [128][128] bf16
constexpr size_t OFF_ENPBF = 1857536;    // [96][96] bf16 edge_norm (symmetric)
constexpr size_t OFF_B215  = 1862144;    // 224 f
constexpr size_t OFF_B12   = 1862368;    // 128 f
constexpr size_t OFF_WPR   = 1862496;    // 87x87 f
constexpr size_t OFF_BTMP  = 1870072;    // 2048 f
constexpr size_t OFF_WC    = 1872120;    // [256][128] f (atomic accum)
constexpr size_t OFF_BC    = 1904888;    // 256 f
constexpr size_t OFF_VY    = 1905144;    // 256x87 f
constexpr size_t OFF_NT    = 1927424;    // [2][128][88] f

__device__ __forceinline__ unsigned short f2bf(float f) {
  unsigned u = __builtin_bit_cast(unsigned, f);
  u += 0x7fffu + ((u >> 16) & 1u);
  return (unsigned short)(u >> 16);
}
__device__ __forceinline__ float bf2f(unsigned short s) {
  return __builtin_bit_cast(float, ((unsigned)s) << 16);
}

// ---------------- ksetup: casts / transposes / inits ----------------
__global__ __launch_bounds__(256) void ksetup(
    const float* __restrict__ Wb,  const float* __restrict__ bb,
    const float* __restrict__ Wa,  const float* __restrict__ ba,
    const float* __restrict__ Wps, const float* __restrict__ bps,
    const float* __restrict__ Wg,  const float* __restrict__ edge,
    float* __restrict__ ws, float* __restrict__ featp)
{
  int blk = blockIdx.x, tid = threadIdx.x;
  if (blk < 2048) {                        // WBBF cast
    int idx = blk*256 + tid;
    ((unsigned short*)(ws+OFF_WBBF))[idx] = f2bf(Wb[idx]);
  } else if (blk < 2304) {                 // featp init = bb
    int idx = (blk-2048)*256 + tid;
    featp[idx] = bb[idx & 255];
  } else if (blk < 2432) {                 // zero Wc
    int idx = (blk-2304)*256 + tid;
    ws[OFF_WC + idx] = 0.f;
  } else if (blk < 2544) {                 // WAPBF [r=224][c=128]
    int idx = (blk-2432)*256 + tid;        // < 28672
    int r = idx >> 7, c = idx & 127;
    float v;
    if (r < 128)      v = Wps[r*128 + c];
    else if (r < 215) v = Wa[(r-128)*128 + c];
    else              v = 0.f;
    ((unsigned short*)(ws+OFF_WAPBF))[idx] = f2bf(v);
  } else if (blk < 2608) {                 // WG2BF [o][d]
    int idx = (blk-2544)*256 + tid;        // < 16384
    int o = idx >> 7, d = idx & 127;
    ((unsigned short*)(ws+OFF_WG2BF))[idx] = f2bf(Wg[o*256 + 128 + d]);
  } else if (blk < 2644) {                 // ENPBF [96][96], zero-padded
    int idx = (blk-2608)*256 + tid;        // < 9216
    int m = idx / 96, n = idx % 96;
    float v = 0.f;
    if (m < 87 && n < 87) {
      float sm = 0.f, sn = 0.f;
      for (int k = 0; k < 87; ++k) { sm += edge[k*87+m]; sn += edge[k*87+n]; }
      v = edge[m*87+n] / sqrtf(sm*sn);
    }
    ((unsigned short*)(ws+OFF_ENPBF))[idx] = f2bf(v);
  } else if (blk < 2674) {                 // WPR fp32
    int idx = (blk-2644)*256 + tid;
    if (idx < 87*87) {
      int j = idx % 87;
      float rs = 0.f;
      for (int k = 0; k < 87; ++k) rs += edge[j*87+k];
      ws[OFF_WPR + idx] = 0.85f * edge[idx] / rs;
    }
  } else {                                 // b215 (pad 224)
    if (tid < 224) {
      float v = (tid < 128) ? bps[tid] : (tid < 215 ? ba[tid-128] : 0.f);
      ws[OFF_B215 + tid] = v;
    }
  }
}

// ---------------- kgemmTW: W12 = Wo2@Wo1 (bf16) ; T1 = Wox2@Wox1 (bf16) ----------------
// TN MFMA: A fp32 [M][K] row-major, B fp32 [K][N] row-major (transpose-staged).
__global__ __launch_bounds__(256) void kgemmTW(const float* __restrict__ Wo2, const float* __restrict__ Wo1,
                                               const float* __restrict__ Wox2, const float* __restrict__ Wox1,
                                               float* __restrict__ ws)
{
  __shared__ alignas(16) short As[64*72];
  __shared__ alignas(16) short Bs[64*72];
  int blk = blockIdx.x, tid = threadIdx.x;
  const float *A, *B; unsigned short* C; int lda, ldb, ldc, i0, j0;
  if (blk < 64) {      // W12 [128][2048]
    A = Wo2; B = Wo1; C = (unsigned short*)(ws+OFF_W12BF);
    lda = 512; ldb = 2048; ldc = 2048;
    i0 = (blk & 1)*64; j0 = (blk >> 1)*64;
  } else {             // T1 [2048][128]
    int b2 = blk - 64;
    A = Wox2; B = Wox1; C = (unsigned short*)(ws+OFF_T1BF);
    lda = 512; ldb = 128; ldc = 128;
    i0 = (b2 >> 1)*64; j0 = (b2 & 1)*64;
  }
  int w = tid >> 6, l = tid & 63, quad = l >> 4, lane16 = l & 15;
  f32x4 acc[4];
  #pragma unroll
  for (int i = 0; i < 4; ++i) acc[i] = (f32x4)(0.f);
  for (int kc = 0; kc < 512; kc += 64) {
    for (int t = tid; t < 1024; t += 256) {      // A stage [m][k]
      int r = t >> 4, k4 = t & 15;
      float4 v = *(const float4*)&A[(size_t)(i0+r)*lda + kc + k4*4];
      s16x4 sv; sv[0]=(short)f2bf(v.x); sv[1]=(short)f2bf(v.y); sv[2]=(short)f2bf(v.z); sv[3]=(short)f2bf(v.w);
      *(s16x4*)&As[r*72 + k4*4] = sv;
    }
    for (int t = tid; t < 1024; t += 256) {      // B transpose-stage -> [n][k]
      int kr = t >> 4, n4 = t & 15;
      float4 v = *(const float4*)&B[(size_t)(kc+kr)*ldb + j0 + n4*4];
      Bs[(n4*4+0)*72 + kr] = (short)f2bf(v.x);
      Bs[(n4*4+1)*72 + kr] = (short)f2bf(v.y);
      Bs[(n4*4+2)*72 + kr] = (short)f2bf(v.z);
      Bs[(n4*4+3)*72 + kr] = (short)f2bf(v.w);
    }
    __syncthreads();
    #pragma unroll
    for (int ks = 0; ks < 2; ++ks) {
      short8 a = *(const short8*)&As[(w*16+lane16)*72 + ks*32 + quad*8];
      #pragma unroll
      for (int nt = 0; nt < 4; ++nt) {
        short8 b8 = *(const short8*)&Bs[(nt*16+lane16)*72 + ks*32 + quad*8];
        acc[nt] = __builtin_amdgcn_mfma_f32_16x16x32_bf16(a, b8, acc[nt], 0, 0, 0);
      }
    }
    __syncthreads();
  }
  #pragma unroll
  for (int nt = 0; nt < 4; ++nt)
    #pragma unroll
    for (int r = 0; r < 4; ++r)
      C[(size_t)(i0 + w*16 + quad*4 + r)*ldc + j0 + nt*16 + lane16] = f2bf(acc[nt][r]);
}

// ---------------- kgemmWc: Wc += WBBF @ T1BF (split-K atomic fp32) ----------------
__global__ __launch_bounds__(256) void kgemmWc(float* __restrict__ ws)
{
  __shared__ alignas(16) short As[64*72];
  __shared__ alignas(16) short Bs[64*72];
  const short* wbbf = (const short*)(ws+OFF_WBBF);
  const short* t1s  = (const short*)(ws+OFF_T1BF);
  int i0 = blockIdx.x*64, j0 = blockIdx.y*64, kc0 = blockIdx.z*256;
  int tid = threadIdx.x, w = tid >> 6, l = tid & 63, quad = l >> 4, lane16 = l & 15;
  f32x4 acc[4];
  #pragma unroll
  for (int i = 0; i < 4; ++i) acc[i] = (f32x4)(0.f);
  for (int kc = kc0; kc < kc0+256; kc += 64) {
    for (int t = tid; t < 512; t += 256) {       // A copy (already bf16)
      int r = t >> 3, c8 = t & 7;
      *(short8*)&As[r*72 + c8*8] = *(const short8*)&wbbf[(size_t)(i0+r)*2048 + kc + c8*8];
    }
    for (int t = tid; t < 1024; t += 256) {      // B transpose-stage
      int kr = t >> 4, n4 = t & 15;
      s16x4 v = *(const s16x4*)&t1s[(size_t)(kc+kr)*128 + j0 + n4*4];
      Bs[(n4*4+0)*72 + kr] = v[0];
      Bs[(n4*4+1)*72 + kr] = v[1];
      Bs[(n4*4+2)*72 + kr] = v[2];
      Bs[(n4*4+3)*72 + kr] = v[3];
    }
    __syncthreads();
    #pragma unroll
    for (int ks = 0; ks < 2; ++ks) {
      short8 a = *(const short8*)&As[(w*16+lane16)*72 + ks*32 + quad*8];
      #pragma unroll
      for (int nt = 0; nt < 4; ++nt) {
        short8 b8 = *(const short8*)&Bs[(nt*16+lane16)*72 + ks*32 + quad*8];
        acc[nt] = __builtin_amdgcn_mfma_f32_16x16x32_bf16(a, b8, acc[nt], 0, 0, 0);
      }
    }
    __syncthreads();
  }
  #pragma unroll
  for (int nt = 0; nt < 4; ++nt)
    #pragma unroll
    for (int r = 0; r < 4; ++r)
      atomicAdd(&ws[OFF_WC + (size_t)(i0 + w*16 + quad*4 + r)*128 + j0 + nt*16 + lane16], acc[nt][r]);
}

// ---------------- kvec: btmp = Wox2@box1+box2 ; b12 = Wo2@bo1+bo2 ----------------
__global__ __launch_bounds__(256) void kvec(const float* __restrict__ Wox2, const float* __restrict__ box1,
                                            const float* __restrict__ box2, const float* __restrict__ Wo2,
                                            const float* __restrict__ bo1,  const float* __restrict__ bo2,
                                            float* __restrict__ ws)
{
  int blk = blockIdx.x, tid = threadIdx.x;
  int w = tid >> 6, l = tid & 63;
  if (blk < 512) {
    int o = blk*4 + w;
    float s = 0.f;
    for (int h = l; h < 512; h += 64) s += Wox2[(size_t)o*512 + h] * box1[h];
    for (int off = 32; off; off >>= 1) s += __shfl_down(s, off, 64);
    if (l == 0) ws[OFF_BTMP + o] = s + box2[o];
  } else {
    int o = (blk - 512)*4 + w;
    float s = 0.f;
    for (int h = l; h < 512; h += 64) s += Wo2[(size_t)o*512 + h] * bo1[h];
    for (int off = 32; off; off >>= 1) s += __shfl_down(s, off, 64);
    if (l == 0) ws[OFF_B12 + o] = s + bo2[o];
  }
}

// ---------------- kbc: bc = Wb@btmp + bb ----------------
__global__ __launch_bounds__(256) void kbc(const float* __restrict__ Wb, const float* __restrict__ bb,
                                           float* __restrict__ ws)
{
  int j = blockIdx.x*4 + (threadIdx.x >> 6), l = threadIdx.x & 63;
  float s = 0.f;
  for (int c = l; c < 2048; c += 64) s += Wb[(size_t)j*2048 + c] * ws[OFF_BTMP + c];
  for (int off = 32; off; off >>= 1) s += __shfl_down(s, off, 64);
  if (l == 0) ws[OFF_BC + j] = s + bb[j];
}

// ---------------- kmain3: xlT(bf16) = (W12@x)^T + b12 ; xp(bf16) = mean(x) ----------------
__global__ __launch_bounds__(256) void kmain3(const float* __restrict__ x,
                                              const short* __restrict__ w12bf,
                                              const float* __restrict__ b12,
                                              short* __restrict__ xlt,
                                              short* __restrict__ xpbf)
{
  __shared__ alignas(16) short Bt[2][52*72];
  int b = blockIdx.x, tid = threadIdx.x;
  int w = tid >> 6, l = tid & 63;
  int quad = l >> 4, lane16 = l & 15;
  const float* xb = x + (size_t)b*2048*49;

  int p0 = tid % 49, oct0 = tid / 49;
  int t1 = tid + 256;
  int p1 = t1 % 49, oct1 = t1 / 49;
  bool has1 = (tid < 136);

  float g0[8], g1[8];
  #pragma unroll
  for (int j = 0; j < 8; ++j) g0[j] = xb[(size_t)(oct0*8+j)*49 + p0];
  if (has1) {
    #pragma unroll
    for (int j = 0; j < 8; ++j) g1[j] = xb[(size_t)(oct1*8+j)*49 + p1];
  }

  f32x4 acc[2][4];
  #pragma unroll
  for (int i = 0; i < 2; ++i)
    #pragma unroll
    for (int j = 0; j < 4; ++j) acc[i][j] = (f32x4)(0.f);

  for (int kci = 0; kci < 32; ++kci) {
    int kc = kci*64;
    short* bt = Bt[kci & 1];
    {
      short8 v;
      #pragma unroll
      for (int j = 0; j < 8; ++j) v[j] = (short)f2bf(g0[j]);
      *(short8*)(bt + p0*72 + oct0*8) = v;
    }
    if (has1) {
      short8 v;
      #pragma unroll
      for (int j = 0; j < 8; ++j) v[j] = (short)f2bf(g1[j]);
      *(short8*)(bt + p1*72 + oct1*8) = v;
    }
    __syncthreads();
    if (kci < 31) {
      const float* xc = xb + (size_t)(kc+64)*49;
      #pragma unroll
      for (int j = 0; j < 8; ++j) g0[j] = xc[(size_t)(oct0*8+j)*49 + p0];
      if (has1) {
        #pragma unroll
        for (int j = 0; j < 8; ++j) g1[j] = xc[(size_t)(oct1*8+j)*49 + p1];
      }
    }
    const short* wr = w12bf + (size_t)(w*32 + lane16)*2048 + kc + quad*8;
    short8 a00 = *(const short8*)(wr);
    short8 a01 = *(const short8*)(wr + 32);
    short8 a10 = *(const short8*)(wr + 16*2048);
    short8 a11 = *(const short8*)(wr + 16*2048 + 32);
    #pragma unroll
    for (int ni = 0; ni < 4; ++ni) {
      const short* br = bt + (ni*16 + lane16)*72 + quad*8;
      short8 b0 = *(const short8*)(br);
      short8 b1 = *(const short8*)(br + 32);
      acc[0][ni] = __builtin_amdgcn_mfma_f32_16x16x32_bf16(a00, b0, acc[0][ni], 0, 0, 0);
      acc[1][ni] = __builtin_amdgcn_mfma_f32_16x16x32_bf16(a10, b0, acc[1][ni], 0, 0, 0);
      acc[0][ni] = __builtin_amdgcn_mfma_f32_16x16x32_bf16(a01, b1, acc[0][ni], 0, 0, 0);
      acc[1][ni] = __builtin_amdgcn_mfma_f32_16x16x32_bf16(a11, b1, acc[1][ni], 0, 0, 0);
    }
    if (tid < 64) {
      float s = 0.f;
      for (int p = 0; p < 49; ++p)
        s += bf2f((unsigned short)bt[p*72 + tid]);
      xpbf[(size_t)b*2048 + kc + tid] = (short)f2bf(s * (1.f/49.f));
    }
  }
  // epilogue -> xlT [p][o] bf16
  short* xo = xlt + (size_t)b*8192;
  #pragma unroll
  for (int mi = 0; mi < 2; ++mi) {
    #pragma unroll
    for (int r = 0; r < 4; ++r) {
      int o = w*32 + mi*16 + quad*4 + r;
      float bias = b12[o];
      #pragma unroll
      for (int ni = 0; ni < 4; ++ni) {
        int p = ni*16 + lane16;
        if (p < 49)
          xo[p*128 + o] = (short)f2bf(acc[mi][ni][r] + bias);
      }
    }
  }
}

// ---------------- kfeat: featp += XPBF @ WBBF^T (no LDS, all from L2) ----------------
__global__ __launch_bounds__(256) void kfeat(const short* __restrict__ xpbf,
                                             const short* __restrict__ wbbf,
                                             float* __restrict__ featp)
{
  int i0 = blockIdx.x*64, j0 = blockIdx.y*64, kc0 = blockIdx.z*256;
  int tid = threadIdx.x, w = tid >> 6, l = tid & 63, quad = l >> 4, lane16 = l & 15;
  f32x4 acc[4];
  #pragma unroll
  for (int i = 0; i < 4; ++i) acc[i] = (f32x4)(0.f);
  for (int kc = kc0; kc < kc0+256; kc += 32) {
    short8 a = *(const short8*)&xpbf[(size_t)(i0 + w*16 + lane16)*2048 + kc + quad*8];
    #pragma unroll
    for (int nt = 0; nt < 4; ++nt) {
      short8 b8 = *(const short8*)&wbbf[(size_t)(j0 + nt*16 + lane16)*2048 + kc + quad*8];
      acc[nt] = __builtin_amdgcn_mfma_f32_16x16x32_bf16(a, b8, acc[nt], 0, 0, 0);
    }
  }
  #pragma unroll
  for (int nt = 0; nt < 4; ++nt)
    #pragma unroll
    for (int r = 0; r < 4; ++r)
      atomicAdd(&featp[(size_t)(i0 + w*16 + quad*4 + r)*256 + j0 + nt*16 + lane16], acc[nt][r]);
}

// ---------------- kpr: pre_output + softmax + 100 PageRank iters -> v_y ----------------
__global__ __launch_bounds__(128) void kpr(const float* __restrict__ featp,
                                           const float* __restrict__ Wfc,
                                           const float* __restrict__ wpr,
                                           float* __restrict__ preo,
                                           float* __restrict__ vy)
{
  __shared__ alignas(16) float fpr[256];
  __shared__ alignas(16) float po[68];
  __shared__ alignas(16) float vs[2][88];
  __shared__ float red[2];
  int b = blockIdx.x, tid = threadIdx.x;
  fpr[tid] = featp[b*256 + tid];
  fpr[tid+128] = featp[b*256 + 128 + tid];
  __syncthreads();
  if (tid < 65) {                          // pre_output = features_p @ Wfc^T
    float s = 0.f;
    for (int c = 0; c < 256; c += 4) {
      float4 w4 = *(const float4*)&Wfc[tid*256 + c];
      s += w4.x*fpr[c] + w4.y*fpr[c+1] + w4.z*fpr[c+2] + w4.w*fpr[c+3];
    }
    po[tid] = s;
    preo[b*65 + tid] = s;
  }
  __syncthreads();
  if (tid == 0) {
    float mx = po[0];
    for (int j = 1; j < 65; ++j) mx = fmaxf(mx, po[j]);
    float sm = 0.f;
    for (int j = 0; j < 65; ++j) sm += expf(po[j]-mx);
    red[0] = mx; red[1] = 1.f/sm;
  }
  __syncthreads();
  float vinit = 0.f;
  if (tid >= 22 && tid < 87) vinit = expf(po[tid-22]-red[0]) * red[1];
  float s_i = vinit * 87.f;
  float wrow[87];
  if (tid < 87) {
    float add = s_i * (0.15f/87.0f);
    #pragma unroll
    for (int j = 0; j < 87; ++j) wrow[j] = wpr[tid*87 + j] + add;
    vs[0][tid] = s_i;
  }
  __syncthreads();
  for (int it = 0; it < 100; ++it) {
    const float* vc = vs[it & 1];
    float nv = 0.f;
    if (tid < 87) {
      #pragma unroll
      for (int j4 = 0; j4 < 21; ++j4) {
        float4 v4 = *(const float4*)&vc[j4*4];
        nv += wrow[j4*4+0]*v4.x + wrow[j4*4+1]*v4.y + wrow[j4*4+2]*v4.z + wrow[j4*4+3]*v4.w;
      }
      nv += wrow[84]*vc[84] + wrow[85]*vc[85] + wrow[86]*vc[86];
      vs[(it+1) & 1][tid] = nv;
    }
    __syncthreads();
  }
  if (tid == 0) {
    float ss = 0.f;
    for (int j = 0; j < 87; ++j) ss += vs[0][j]*vs[0][j];
    red[0] = 1.f / fmaxf(sqrtf(ss), 1e-12f);
  }
  __syncthreads();
  if (tid < 87) vy[b*87 + tid] = vinit + vs[0][tid]*red[0];
}

// ---------------- knode ----------------
__global__ __launch_bounds__(256) void knode(const float* __restrict__ Wg,
                                             const float* __restrict__ node_p,
                                             const float* __restrict__ vy,
                                             float* __restrict__ nt)
{
  int idx = blockIdx.x*256 + threadIdx.x;  // < 22528
  int par = idx / 11264;
  int r = idx % 11264;
  int o = r / 88, m = r % 88;
  float v = 0.f;
  if (m < 87) {
    float s = 0.f;
    for (int k = 0; k < 128; ++k)
      s += Wg[o*256+k] * node_p[k*87+m] * vy[(par*128+k)*87+m];
    v = s;
  }
  nt[idx] = v;
}

// ---------------- kgraph_all: MFMA graph chain + kfin, all in LDS ----------------
__global__ __launch_bounds__(512) void kgraph_all(
    const short* __restrict__ xlt,   const short* __restrict__ wapbf,
    const float* __restrict__ b215,  const short* __restrict__ wg2bf,
    const float* __restrict__ nt,    const float* __restrict__ bg,
    const short* __restrict__ enpbf, const float* __restrict__ Wsp,
    const float* __restrict__ bsp,   const float* __restrict__ Ws,
    const float* __restrict__ wc,    const float* __restrict__ bc,
    const float* __restrict__ featp, const float* __restrict__ Wfc2,
    float* __restrict__ feat, float* __restrict__ out2, float* __restrict__ soft)
{
  extern __shared__ char smraw[];
  short* XT = (short*)smraw;             // [64][136]
  short* At = XT + 8704;                 // [224][72]
  short* M1 = At + 16128;                // [96][136]
  short* G  = M1 + 13056;                // [128][104]
  short* M2 = G  + 13312;                // [128][104]
  float* fb  = (float*)(M2 + 13312);
  float* wsm = fb;                       // 96
  float* tnb = fb + 96;                  // 96
  float* zs  = fb + 192;                 // 128
  float* m3s = fb + 320;                 // 128
  float* fs  = fb + 448;                 // 256
  float* o2s = fb + 704;                 // 72
  float* red = fb + 776;                 // 4

  int b = blockIdx.x, tid = threadIdx.x;
  int w = tid >> 6, l = tid & 63, quad = l >> 4, lane16 = l & 15;

  // stage xlT [p][c]
  const short* xb = xlt + (size_t)b*8192;
  for (int t = tid; t < 1024; t += 512) {
    int p = t >> 4, c8 = t & 15;
    *(short8*)&XT[p*136 + c8*8] = *(const short8*)&xb[t*8];
  }
  __syncthreads();

  // phase 1a: At[r][p] = Wap @ xl + b215   (M=224, N=64, K=128)
  for (int t = w; t < 56; t += 8) {
    int mt = t >> 2, n4 = t & 3;
    f32x4 acc = (f32x4)(0.f);
    #pragma unroll
    for (int ks = 0; ks < 4; ++ks) {
      short8 a  = *(const short8*)&wapbf[(size_t)(mt*16+lane16)*128 + ks*32 + quad*8];
      short8 b8 = *(const short8*)&XT[(n4*16+lane16)*136 + ks*32 + quad*8];
      acc = __builtin_amdgcn_mfma_f32_16x16x32_bf16(a, b8, acc, 0, 0, 0);
    }
    int p = n4*16 + lane16;
    #pragma unroll
    for (int r = 0; r < 4; ++r) {
      int rr = mt*16 + quad*4 + r;
      At[rr*72 + p] = (p < 49) ? (short)f2bf(acc[r] + b215[rr]) : (short)0;
    }
  }
  __syncthreads();

  // phase 1b: M1[m][d] = relu(a-rows @ ps-rows^T)   (M=96, N=128, K=64)
  for (int t = w; t < 48; t += 8) {
    int mt = t / 8, n4 = t % 8;
    f32x4 acc = (f32x4)(0.f);
    #pragma unroll
    for (int ks = 0; ks < 2; ++ks) {
      short8 a  = *(const short8*)&At[(128 + mt*16 + lane16)*72 + ks*32 + quad*8];
      short8 b8 = *(const short8*)&At[(n4*16+lane16)*72 + ks*32 + quad*8];
      acc = __builtin_amdgcn_mfma_f32_16x16x32_bf16(a, b8, acc, 0, 0, 0);
    }
    int d = n4*16 + lane16;
    #pragma unroll
    for (int r = 0; r < 4; ++r) {
      int m = mt*16 + quad*4 + r;
      M1[m*136 + d] = (short)f2bf(fmaxf(acc[r], 0.f));
    }
  }
  __syncthreads();

  // phase 2: G[o][m] = Wg2 @ m1 + nt + bg   (M=128, N=96, K=128)
  const float* ntb = nt + (size_t)(b & 1)*11264;
  for (int t = w; t < 48; t += 8) {
    int mt = t / 6, n4 = t % 6;
    f32x4 acc = (f32x4)(0.f);
    #pragma unroll
    for (int ks = 0; ks < 4; ++ks) {
      short8 a  = *(const short8*)&wg2bf[(size_t)(mt*16+lane16)*128 + ks*32 + quad*8];
      short8 b8 = *(const short8*)&M1[(n4*16+lane16)*136 + ks*32 + quad*8];
      acc = __builtin_amdgcn_mfma_f32_16x16x32_bf16(a, b8, acc, 0, 0, 0);
    }
    int m = n4*16 + lane16;
    #pragma unroll
    for (int r = 0; r < 4; ++r) {
      int o = mt*16 + quad*4 + r;
      float v = acc[r] + bg[o] + ((m < 88) ? ntb[o*88 + m] : 0.f);
      G[o*104 + m] = (short)f2bf(v);
    }
  }
  __syncthreads();

  // phase 3: M2[c][n] = relu(G @ enp)   (M=128, N=96, K=96; enp symmetric)
  for (int t = w; t < 48; t += 8) {
    int mt = t / 6, n4 = t % 6;
    f32x4 acc = (f32x4)(0.f);
    #pragma unroll
    for (int ks = 0; ks < 3; ++ks) {
      short8 a  = *(const short8*)&G[(mt*16+lane16)*104 + ks*32 + quad*8];
      short8 b8 = *(const short8*)&enpbf[(size_t)(n4*16+lane16)*96 + ks*32 + quad*8];
      acc = __builtin_amdgcn_mfma_f32_16x16x32_bf16(a, b8, acc, 0, 0, 0);
    }
    int n = n4*16 + lane16;
    #pragma unroll
    for (int r = 0; r < 4; ++r) {
      int c = mt*16 + quad*4 + r;
      M2[c*104 + n] = (short)f2bf(fmaxf(acc[r], 0.f));
    }
  }
  __syncthreads();

  // phase 4: node softmax + m3 = relu(Wsp @ (m2 @ att) + bsp)
  if (tid < 87) {
    float s = 0.f;
    for (int c = 0; c < 128; ++c) s += Ws[c] * bf2f((unsigned short)M2[c*104 + tid]);
    tnb[tid] = s;
  }
  __syncthreads();
  if (tid == 0) {
    float mx = tnb[0];
    for (int j = 1; j < 87; ++j) mx = fmaxf(mx, tnb[j]);
    red[0] = mx;
  }
  __syncthreads();
  if (tid < 87) wsm[tid] = expf(tnb[tid] - red[0]);
  __syncthreads();
  if (tid == 0) {
    float sm = 0.f;
    for (int j = 0; j < 87; ++j) sm += wsm[j];
    red[0] = 1.f/sm;
  }
  __syncthreads();
  if (tid < 87) wsm[tid] *= red[0];
  __syncthreads();
  if (tid < 128) {
    float s = 0.f;
    for (int m = 0; m < 87; ++m) s += bf2f((unsigned short)M2[tid*104 + m]) * wsm[m];
    zs[tid] = s;
  }
  __syncthreads();
  if (tid < 128) {
    float s = 0.f;
    for (int c = 0; c < 128; ++c) s += Wsp[tid*128 + c] * zs[c];
    m3s[tid] = fmaxf(s + bsp[tid], 0.f);
  }
  __syncthreads();

  // phase 5: features / outputs2 / softmax
  if (tid < 256) {
    float s = 0.f;
    #pragma unroll 4
    for (int d4 = 0; d4 < 32; ++d4) {
      float4 w4 = *(const float4*)&wc[tid*128 + d4*4];
      s += w4.x*m3s[d4*4] + w4.y*m3s[d4*4+1] + w4.z*m3s[d4*4+2] + w4.w*m3s[d4*4+3];
    }
    float f = featp[b*256 + tid] + bc[tid] + s;
    fs[tid] = f;
    feat[b*256 + tid] = f;
  }
  __syncthreads();
  if (tid < 65) {
    float s = 0.f;
    for (int j = 0; j < 256; ++j) s += Wfc2[tid*256 + j] * fs[j];
    out2[b*65 + tid] = s;
    o2s[tid] = s;
  }
  __syncthreads();
  if (tid == 0) {
    float mx = o2s[0];
    for (int j = 1; j < 65; ++j) mx = fmaxf(mx, o2s[j]);
    float sm = 0.f;
    for (int j = 0; j < 65; ++j) sm += expf(o2s[j]-mx);
    red[0] = mx; red[1] = 1.f/sm;
  }
  __syncthreads();
  if (tid < 65) soft[b*65 + tid] = expf(o2s[tid]-red[0]) * red[1];
}

// ---------------- launch ----------------
extern "C" void kernel_launch(void* const* d_in, const int* in_sizes, int n_in,
                              void* d_out, int out_size, void* d_ws, size_t ws_size,
                              hipStream_t stream)
{
  (void)in_sizes; (void)n_in; (void)out_size; (void)ws_size;
  const float* x      = (const float*)d_in[0];
  const float* Wb     = (const float*)d_in[1];
  const float* bb     = (const float*)d_in[2];
  const float* Wfc    = (const float*)d_in[3];
  const float* Wfc2   = (const float*)d_in[4];
  const float* Wo1    = (const float*)d_in[5];
  const float* bo1    = (const float*)d_in[6];
  const float* Wo2    = (const float*)d_in[7];
  const float* bo2    = (const float*)d_in[8];
  const float* Wa     = (const float*)d_in[9];
  const float* ba     = (const float*)d_in[10];
  const float* Wps    = (const float*)d_in[11];
  const float* bps    = (const float*)d_in[12];
  const float* node_p = (const float*)d_in[13];
  const float* Wg     = (const float*)d_in[14];
  const float* bg     = (const float*)d_in[15];
  const float* Wsp    = (const float*)d_in[16];
  const float* bsp    = (const float*)d_in[17];
  const float* Ws     = (const float*)d_in[18];
  const float* Wox1   = (const float*)d_in[20];
  const float* box1   = (const float*)d_in[21];
  const float* Wox2   = (const float*)d_in[22];
  const float* box2   = (const float*)d_in[23];
  const float* edge   = (const float*)d_in[24];

  float* ws   = (float*)d_ws;
  float* out  = (float*)d_out;
  float* feat  = out;            // (256,256)
  float* out2  = out + 65536;    // (256,65)
  float* soft  = out + 82176;    // (256,65)
  float* preo  = out + 98816;    // (256,65)
  float* featp = out + 115456;   // (256,256)

  ksetup<<<2675, 256, 0, stream>>>(Wb, bb, Wa, ba, Wps, bps, Wg, edge, ws, featp);
  kgemmTW<<<128, 256, 0, stream>>>(Wo2, Wo1, Wox2, Wox1, ws);
  kvec<<<544, 256, 0, stream>>>(Wox2, box1, box2, Wo2, bo1, bo2, ws);
  kbc<<<64, 256, 0, stream>>>(Wb, bb, ws);
  kgemmWc<<<dim3(4,2,8), 256, 0, stream>>>(ws);
  kmain3<<<256, 256, 0, stream>>>(x, (const short*)(ws + OFF_W12BF), ws + OFF_B12,
                                  (short*)(ws + OFF_XLT), (short*)(ws + OFF_XPBF));
  kfeat<<<dim3(4,4,8), 256, 0, stream>>>((const short*)(ws + OFF_XPBF),
                                         (const short*)(ws + OFF_WBBF), featp);
  kpr<<<256, 128, 0, stream>>>(featp, Wfc, ws + OFF_WPR, preo, ws + OFF_VY);
  knode<<<88, 256, 0, stream>>>(Wg, node_p, ws + OFF_VY, ws + OFF_NT);
  kgraph_all<<<256, 512, 132144, stream>>>((const short*)(ws + OFF_XLT),
                                           (const short*)(ws + OFF_WAPBF),
                                           ws + OFF_B215,
                                           (const short*)(ws + OFF_WG2BF),
                                           ws + OFF_NT, bg,
                                           (const short*)(ws + OFF_ENPBF),
                                           Wsp, bsp, Ws,
                                           ws + OFF_WC, ws + OFF_BC, featp, Wfc2,
                                           feat, out2, soft);
}

// Round 5
// 433.491 us; speedup vs baseline: 2.0680x; 1.0139x over previous
//
#include <hip/hip_runtime.h>
#include <cmath>

// M=87, CLS=65, K=128, DL=DC=128, DO=2048, BD=256, B=256, HW=49

typedef __attribute__((ext_vector_type(8))) short short8;
typedef __attribute__((ext_vector_type(4))) short s16x4;
typedef __attribute__((ext_vector_type(4))) float f32x4;

// ---------------- workspace layout (float offsets) ----------------
constexpr size_t OFF_W12BF = 0;          // [128][2048] bf16
constexpr size_t OFF_T1BF  = 131072;     // [2048][128] bf16 (Wox2@Wox1)
constexpr size_t OFF_WBBF  = 262144;     // [256][2048] bf16
constexpr size_t OFF_XPBF  = 524288;     // [256][2048] bf16
constexpr size_t OFF_XLT   = 786432;     // [256][64][128] bf16 (xl transposed)
constexpr size_t OFF_WAPBF = 1835008;    // [224][128] bf16 (Wps;Wa;0)
constexpr size_t OFF_WG2BF = 1849344;    // [128][128] bf16
constexpr size_t OFF_ENPBF = 1857536;    // [96][96] bf16 edge_norm (symmetric)
constexpr size_t OFF_B215  = 1862144;    // 224 f
constexpr size_t OFF_B12   = 1862368;    // 128 f
constexpr size_t OFF_WPR   = 1862496;    // 87x87 f
constexpr size_t OFF_BTMP  = 1870072;    // 2048 f
constexpr size_t OFF_WC    = 1872120;    // [256][128] f (atomic accum)
constexpr size_t OFF_BC    = 1904888;    // 256 f
constexpr size_t OFF_VY    = 1905144;    // 256x87 f
constexpr size_t OFF_NT    = 1927424;    // [2][128][88] f
constexpr size_t OFF_PART  = 1949952;    // [2][256][128][52] f partial xl

__device__ __forceinline__ unsigned short f2bf(float f) {
  unsigned u = __builtin_bit_cast(unsigned, f);
  u += 0x7fffu + ((u >> 16) & 1u);
  return (unsigned short)(u >> 16);
}
__device__ __forceinline__ float bf2f(unsigned short s) {
  return __builtin_bit_cast(float, ((unsigned)s) << 16);
}

// ---------------- ksetup: casts / transposes / inits ----------------
__global__ __launch_bounds__(256) void ksetup(
    const float* __restrict__ Wb,  const float* __restrict__ bb,
    const float* __restrict__ Wa,  const float* __restrict__ ba,
    const float* __restrict__ Wps, const float* __restrict__ bps,
    const float* __restrict__ Wg,  const float* __restrict__ edge,
    float* __restrict__ ws, float* __restrict__ featp)
{
  int blk = blockIdx.x, tid = threadIdx.x;
  if (blk < 2048) {                        // WBBF cast
    int idx = blk*256 + tid;
    ((unsigned short*)(ws+OFF_WBBF))[idx] = f2bf(Wb[idx]);
  } else if (blk < 2304) {                 // featp init = bb
    int idx = (blk-2048)*256 + tid;
    featp[idx] = bb[idx & 255];
  } else if (blk < 2432) {                 // zero Wc
    int idx = (blk-2304)*256 + tid;
    ws[OFF_WC + idx] = 0.f;
  } else if (blk < 2544) {                 // WAPBF [r=224][c=128]
    int idx = (blk-2432)*256 + tid;        // < 28672
    int r = idx >> 7, c = idx & 127;
    float v;
    if (r < 128)      v = Wps[r*128 + c];
    else if (r < 215) v = Wa[(r-128)*128 + c];
    else              v = 0.f;
    ((unsigned short*)(ws+OFF_WAPBF))[idx] = f2bf(v);
  } else if (blk < 2608) {                 // WG2BF [o][d]
    int idx = (blk-2544)*256 + tid;        // < 16384
    int o = idx >> 7, d = idx & 127;
    ((unsigned short*)(ws+OFF_WG2BF))[idx] = f2bf(Wg[o*256 + 128 + d]);
  } else if (blk < 2644) {                 // ENPBF [96][96], zero-padded
    int idx = (blk-2608)*256 + tid;        // < 9216
    int m = idx / 96, n = idx % 96;
    float v = 0.f;
    if (m < 87 && n < 87) {
      float sm = 0.f, sn = 0.f;
      for (int k = 0; k < 87; ++k) { sm += edge[k*87+m]; sn += edge[k*87+n]; }
      v = edge[m*87+n] / sqrtf(sm*sn);
    }
    ((unsigned short*)(ws+OFF_ENPBF))[idx] = f2bf(v);
  } else if (blk < 2674) {                 // WPR fp32
    int idx = (blk-2644)*256 + tid;
    if (idx < 87*87) {
      int j = idx % 87;
      float rs = 0.f;
      for (int k = 0; k < 87; ++k) rs += edge[j*87+k];
      ws[OFF_WPR + idx] = 0.85f * edge[idx] / rs;
    }
  } else {                                 // b215 (pad 224)
    if (tid < 224) {
      float v = (tid < 128) ? bps[tid] : (tid < 215 ? ba[tid-128] : 0.f);
      ws[OFF_B215 + tid] = v;
    }
  }
}

// ---------------- kgemmTW: W12 = Wo2@Wo1 (bf16) ; T1 = Wox2@Wox1 (bf16) ----------------
__global__ __launch_bounds__(256) void kgemmTW(const float* __restrict__ Wo2, const float* __restrict__ Wo1,
                                               const float* __restrict__ Wox2, const float* __restrict__ Wox1,
                                               float* __restrict__ ws)
{
  __shared__ alignas(16) short As[64*72];
  __shared__ alignas(16) short Bs[64*72];
  int blk = blockIdx.x, tid = threadIdx.x;
  const float *A, *B; unsigned short* C; int lda, ldb, ldc, i0, j0;
  if (blk < 64) {      // W12 [128][2048]
    A = Wo2; B = Wo1; C = (unsigned short*)(ws+OFF_W12BF);
    lda = 512; ldb = 2048; ldc = 2048;
    i0 = (blk & 1)*64; j0 = (blk >> 1)*64;
  } else {             // T1 [2048][128]
    int b2 = blk - 64;
    A = Wox2; B = Wox1; C = (unsigned short*)(ws+OFF_T1BF);
    lda = 512; ldb = 128; ldc = 128;
    i0 = (b2 >> 1)*64; j0 = (b2 & 1)*64;
  }
  int w = tid >> 6, l = tid & 63, quad = l >> 4, lane16 = l & 15;
  f32x4 acc[4];
  #pragma unroll
  for (int i = 0; i < 4; ++i) acc[i] = (f32x4)(0.f);
  for (int kc = 0; kc < 512; kc += 64) {
    for (int t = tid; t < 1024; t += 256) {      // A stage [m][k]
      int r = t >> 4, k4 = t & 15;
      float4 v = *(const float4*)&A[(size_t)(i0+r)*lda + kc + k4*4];
      s16x4 sv; sv[0]=(short)f2bf(v.x); sv[1]=(short)f2bf(v.y); sv[2]=(short)f2bf(v.z); sv[3]=(short)f2bf(v.w);
      *(s16x4*)&As[r*72 + k4*4] = sv;
    }
    for (int t = tid; t < 1024; t += 256) {      // B transpose-stage -> [n][k]
      int kr = t >> 4, n4 = t & 15;
      float4 v = *(const float4*)&B[(size_t)(kc+kr)*ldb + j0 + n4*4];
      Bs[(n4*4+0)*72 + kr] = (short)f2bf(v.x);
      Bs[(n4*4+1)*72 + kr] = (short)f2bf(v.y);
      Bs[(n4*4+2)*72 + kr] = (short)f2bf(v.z);
      Bs[(n4*4+3)*72 + kr] = (short)f2bf(v.w);
    }
    __syncthreads();
    #pragma unroll
    for (int ks = 0; ks < 2; ++ks) {
      short8 a = *(const short8*)&As[(w*16+lane16)*72 + ks*32 + quad*8];
      #pragma unroll
      for (int nt = 0; nt < 4; ++nt) {
        short8 b8 = *(const short8*)&Bs[(nt*16+lane16)*72 + ks*32 + quad*8];
        acc[nt] = __builtin_amdgcn_mfma_f32_16x16x32_bf16(a, b8, acc[nt], 0, 0, 0);
      }
    }
    __syncthreads();
  }
  #pragma unroll
  for (int nt = 0; nt < 4; ++nt)
    #pragma unroll
    for (int r = 0; r < 4; ++r)
      C[(size_t)(i0 + w*16 + quad*4 + r)*ldc + j0 + nt*16 + lane16] = f2bf(acc[nt][r]);
}

// ---------------- kgemmWc: Wc += WBBF @ T1BF (split-K atomic fp32) ----------------
__global__ __launch_bounds__(256) void kgemmWc(float* __restrict__ ws)
{
  __shared__ alignas(16) short As[64*72];
  __shared__ alignas(16) short Bs[64*72];
  const short* wbbf = (const short*)(ws+OFF_WBBF);
  const short* t1s  = (const short*)(ws+OFF_T1BF);
  int i0 = blockIdx.x*64, j0 = blockIdx.y*64, kc0 = blockIdx.z*256;
  int tid = threadIdx.x, w = tid >> 6, l = tid & 63, quad = l >> 4, lane16 = l & 15;
  f32x4 acc[4];
  #pragma unroll
  for (int i = 0; i < 4; ++i) acc[i] = (f32x4)(0.f);
  for (int kc = kc0; kc < kc0+256; kc += 64) {
    for (int t = tid; t < 512; t += 256) {       // A copy (already bf16)
      int r = t >> 3, c8 = t & 7;
      *(short8*)&As[r*72 + c8*8] = *(const short8*)&wbbf[(size_t)(i0+r)*2048 + kc + c8*8];
    }
    for (int t = tid; t < 1024; t += 256) {      // B transpose-stage
      int kr = t >> 4, n4 = t & 15;
      s16x4 v = *(const s16x4*)&t1s[(size_t)(kc+kr)*128 + j0 + n4*4];
      Bs[(n4*4+0)*72 + kr] = v[0];
      Bs[(n4*4+1)*72 + kr] = v[1];
      Bs[(n4*4+2)*72 + kr] = v[2];
      Bs[(n4*4+3)*72 + kr] = v[3];
    }
    __syncthreads();
    #pragma unroll
    for (int ks = 0; ks < 2; ++ks) {
      short8 a = *(const short8*)&As[(w*16+lane16)*72 + ks*32 + quad*8];
      #pragma unroll
      for (int nt = 0; nt < 4; ++nt) {
        short8 b8 = *(const short8*)&Bs[(nt*16+lane16)*72 + ks*32 + quad*8];
        acc[nt] = __builtin_amdgcn_mfma_f32_16x16x32_bf16(a, b8, acc[nt], 0, 0, 0);
      }
    }
    __syncthreads();
  }
  #pragma unroll
  for (int nt = 0; nt < 4; ++nt)
    #pragma unroll
    for (int r = 0; r < 4; ++r)
      atomicAdd(&ws[OFF_WC + (size_t)(i0 + w*16 + quad*4 + r)*128 + j0 + nt*16 + lane16], acc[nt][r]);
}

// ---------------- kvec: btmp = Wox2@box1+box2 ; b12 = Wo2@bo1+bo2 ----------------
__global__ __launch_bounds__(256) void kvec(const float* __restrict__ Wox2, const float* __restrict__ box1,
                                            const float* __restrict__ box2, const float* __restrict__ Wo2,
                                            const float* __restrict__ bo1,  const float* __restrict__ bo2,
                                            float* __restrict__ ws)
{
  int blk = blockIdx.x, tid = threadIdx.x;
  int w = tid >> 6, l = tid & 63;
  if (blk < 512) {
    int o = blk*4 + w;
    float s = 0.f;
    for (int h = l; h < 512; h += 64) s += Wox2[(size_t)o*512 + h] * box1[h];
    for (int off = 32; off; off >>= 1) s += __shfl_down(s, off, 64);
    if (l == 0) ws[OFF_BTMP + o] = s + box2[o];
  } else {
    int o = (blk - 512)*4 + w;
    float s = 0.f;
    for (int h = l; h < 512; h += 64) s += Wo2[(size_t)o*512 + h] * bo1[h];
    for (int off = 32; off; off >>= 1) s += __shfl_down(s, off, 64);
    if (l == 0) ws[OFF_B12 + o] = s + bo2[o];
  }
}

// ---------------- kbc: bc = Wb@btmp + bb ----------------
__global__ __launch_bounds__(256) void kbc(const float* __restrict__ Wb, const float* __restrict__ bb,
                                           float* __restrict__ ws)
{
  int j = blockIdx.x*4 + (threadIdx.x >> 6), l = threadIdx.x & 63;
  float s = 0.f;
  for (int c = l; c < 2048; c += 64) s += Wb[(size_t)j*2048 + c] * ws[OFF_BTMP + c];
  for (int off = 32; off; off >>= 1) s += __shfl_down(s, off, 64);
  if (l == 0) ws[OFF_BC + j] = s + bb[j];
}

// ---------------- kmain4: partial xl (fp32) over k-half; xp(bf16) fused ----------------
// grid (256 batches, 2 k-halves) x 512 threads: 2 blocks/CU, 16 waves/CU.
__global__ __launch_bounds__(512) void kmain4(const float* __restrict__ x,
                                              const short* __restrict__ w12bf,
                                              short* __restrict__ xpbf,
                                              float* __restrict__ part)
{
  __shared__ alignas(16) short Bt[2][52*72];
  int b = blockIdx.x, half = blockIdx.y, tid = threadIdx.x;
  int w = tid >> 6, l = tid & 63;
  int quad = l >> 4, lane16 = l & 15;
  const float* xb = x + ((size_t)b*2048 + half*1024)*49;

  int p0 = tid % 49, oct0 = tid / 49;        // staging task (tid < 392)
  bool has0 = (tid < 392);

  float g0[8];
  if (has0) {
    #pragma unroll
    for (int j = 0; j < 8; ++j) g0[j] = xb[(size_t)(oct0*8+j)*49 + p0];
  }

  f32x4 acc[4];
  #pragma unroll
  for (int i = 0; i < 4; ++i) acc[i] = (f32x4)(0.f);

  for (int kci = 0; kci < 16; ++kci) {
    int kc = kci*64;
    short* bt = Bt[kci & 1];
    if (has0) {
      short8 v;
      #pragma unroll
      for (int j = 0; j < 8; ++j) v[j] = (short)f2bf(g0[j]);
      *(short8*)(bt + p0*72 + oct0*8) = v;
    }
    __syncthreads();
    if (kci < 15 && has0) {                  // prefetch next chunk
      const float* xc = xb + (size_t)(kc+64)*49;
      #pragma unroll
      for (int j = 0; j < 8; ++j) g0[j] = xc[(size_t)(oct0*8+j)*49 + p0];
    }
    // A frags from global (L2-resident); wave w owns o rows [w*16, w*16+16)
    const short* wr = w12bf + (size_t)(w*16 + lane16)*2048 + half*1024 + kc + quad*8;
    short8 a0 = *(const short8*)(wr);
    short8 a1 = *(const short8*)(wr + 32);
    #pragma unroll
    for (int ni = 0; ni < 4; ++ni) {
      const short* br = bt + (ni*16 + lane16)*72 + quad*8;
      short8 b0 = *(const short8*)(br);
      short8 b1 = *(const short8*)(br + 32);
      acc[ni] = __builtin_amdgcn_mfma_f32_16x16x32_bf16(a0, b0, acc[ni], 0, 0, 0);
      acc[ni] = __builtin_amdgcn_mfma_f32_16x16x32_bf16(a1, b1, acc[ni], 0, 0, 0);
    }
    if (tid < 64) {                          // fused xp for this chunk's c-range
      float s = 0.f;
      for (int p = 0; p < 49; ++p)
        s += bf2f((unsigned short)bt[p*72 + tid]);
      xpbf[(size_t)b*2048 + half*1024 + kc + tid] = (short)f2bf(s * (1.f/49.f));
    }
  }
  // epilogue: partial sums fp32 [half][b][o][52]
  float* po = part + ((size_t)half*256 + b)*128*52;
  #pragma unroll
  for (int ni = 0; ni < 4; ++ni) {
    int p = ni*16 + lane16;
    if (p < 49) {
      #pragma unroll
      for (int r = 0; r < 4; ++r) {
        int o = w*16 + quad*4 + r;
        po[o*52 + p] = acc[ni][r];
      }
    }
  }
}

// ---------------- kfinal: xlt = bf16( part0 + part1 + b12 ), transposed [p][o] ----------------
__global__ __launch_bounds__(256) void kfinal(const float* __restrict__ part,
                                              const float* __restrict__ b12,
                                              short* __restrict__ xlt)
{
  int b = blockIdx.x, tid = threadIdx.x;
  const float* pa = part + (size_t)b*128*52;
  const float* pb = pa + (size_t)256*128*52;
  short* xo = xlt + (size_t)b*8192;
  for (int i = tid; i < 128*52; i += 256) {
    int o = i / 52, p = i % 52;
    if (p < 49)
      xo[p*128 + o] = (short)f2bf(pa[i] + pb[i] + b12[o]);
  }
}

// ---------------- kfeat: featp += XPBF @ WBBF^T ----------------
__global__ __launch_bounds__(256) void kfeat(const short* __restrict__ xpbf,
                                             const short* __restrict__ wbbf,
                                             float* __restrict__ featp)
{
  int i0 = blockIdx.x*64, j0 = blockIdx.y*64, kc0 = blockIdx.z*256;
  int tid = threadIdx.x, w = tid >> 6, l = tid & 63, quad = l >> 4, lane16 = l & 15;
  f32x4 acc[4];
  #pragma unroll
  for (int i = 0; i < 4; ++i) acc[i] = (f32x4)(0.f);
  for (int kc = kc0; kc < kc0+256; kc += 32) {
    short8 a = *(const short8*)&xpbf[(size_t)(i0 + w*16 + lane16)*2048 + kc + quad*8];
    #pragma unroll
    for (int nt = 0; nt < 4; ++nt) {
      short8 b8 = *(const short8*)&wbbf[(size_t)(j0 + nt*16 + lane16)*2048 + kc + quad*8];
      acc[nt] = __builtin_amdgcn_mfma_f32_16x16x32_bf16(a, b8, acc[nt], 0, 0, 0);
    }
  }
  #pragma unroll
  for (int nt = 0; nt < 4; ++nt)
    #pragma unroll
    for (int r = 0; r < 4; ++r)
      atomicAdd(&featp[(size_t)(i0 + w*16 + quad*4 + r)*256 + j0 + nt*16 + lane16], acc[nt][r]);
}

// ---------------- kpr: pre_output + softmax + 100 PageRank iters -> v_y ----------------
__global__ __launch_bounds__(128) void kpr(const float* __restrict__ featp,
                                           const float* __restrict__ Wfc,
                                           const float* __restrict__ wpr,
                                           float* __restrict__ preo,
                                           float* __restrict__ vy)
{
  __shared__ alignas(16) float fpr[256];
  __shared__ alignas(16) float po[68];
  __shared__ alignas(16) float vs[2][88];
  __shared__ float red[2];
  int b = blockIdx.x, tid = threadIdx.x;
  fpr[tid] = featp[b*256 + tid];
  fpr[tid+128] = featp[b*256 + 128 + tid];
  __syncthreads();
  if (tid < 65) {
    float s = 0.f;
    for (int c = 0; c < 256; c += 4) {
      float4 w4 = *(const float4*)&Wfc[tid*256 + c];
      s += w4.x*fpr[c] + w4.y*fpr[c+1] + w4.z*fpr[c+2] + w4.w*fpr[c+3];
    }
    po[tid] = s;
    preo[b*65 + tid] = s;
  }
  __syncthreads();
  if (tid == 0) {
    float mx = po[0];
    for (int j = 1; j < 65; ++j) mx = fmaxf(mx, po[j]);
    float sm = 0.f;
    for (int j = 0; j < 65; ++j) sm += expf(po[j]-mx);
    red[0] = mx; red[1] = 1.f/sm;
  }
  __syncthreads();
  float vinit = 0.f;
  if (tid >= 22 && tid < 87) vinit = expf(po[tid-22]-red[0]) * red[1];
  float s_i = vinit * 87.f;
  float wrow[87];
  if (tid < 87) {
    float add = s_i * (0.15f/87.0f);
    #pragma unroll
    for (int j = 0; j < 87; ++j) wrow[j] = wpr[tid*87 + j] + add;
    vs[0][tid] = s_i;
  }
  __syncthreads();
  for (int it = 0; it < 100; ++it) {
    const float* vc = vs[it & 1];
    float nv = 0.f;
    if (tid < 87) {
      #pragma unroll
      for (int j4 = 0; j4 < 21; ++j4) {
        float4 v4 = *(const float4*)&vc[j4*4];
        nv += wrow[j4*4+0]*v4.x + wrow[j4*4+1]*v4.y + wrow[j4*4+2]*v4.z + wrow[j4*4+3]*v4.w;
      }
      nv += wrow[84]*vc[84] + wrow[85]*vc[85] + wrow[86]*vc[86];
      vs[(it+1) & 1][tid] = nv;
    }
    __syncthreads();
  }
  if (tid == 0) {
    float ss = 0.f;
    for (int j = 0; j < 87; ++j) ss += vs[0][j]*vs[0][j];
    red[0] = 1.f / fmaxf(sqrtf(ss), 1e-12f);
  }
  __syncthreads();
  if (tid < 87) vy[b*87 + tid] = vinit + vs[0][tid]*red[0];
}

// ---------------- knode ----------------
__global__ __launch_bounds__(256) void knode(const float* __restrict__ Wg,
                                             const float* __restrict__ node_p,
                                             const float* __restrict__ vy,
                                             float* __restrict__ nt)
{
  int idx = blockIdx.x*256 + threadIdx.x;  // < 22528
  int par = idx / 11264;
  int r = idx % 11264;
  int o = r / 88, m = r % 88;
  float v = 0.f;
  if (m < 87) {
    float s = 0.f;
    for (int k = 0; k < 128; ++k)
      s += Wg[o*256+k] * node_p[k*87+m] * vy[(par*128+k)*87+m];
    v = s;
  }
  nt[idx] = v;
}

// ---------------- kgraph_all: MFMA graph chain + kfin, all in LDS ----------------
__global__ __launch_bounds__(512) void kgraph_all(
    const short* __restrict__ xlt,   const short* __restrict__ wapbf,
    const float* __restrict__ b215,  const short* __restrict__ wg2bf,
    const float* __restrict__ nt,    const float* __restrict__ bg,
    const short* __restrict__ enpbf, const float* __restrict__ Wsp,
    const float* __restrict__ bsp,   const float* __restrict__ Ws,
    const float* __restrict__ wc,    const float* __restrict__ bc,
    const float* __restrict__ featp, const float* __restrict__ Wfc2,
    float* __restrict__ feat, float* __restrict__ out2, float* __restrict__ soft)
{
  extern __shared__ char smraw[];
  short* XT = (short*)smraw;             // [64][136]
  short* At = XT + 8704;                 // [224][72]
  short* M1 = At + 16128;                // [96][136]
  short* G  = M1 + 13056;                // [128][104]
  short* M2 = G  + 13312;                // [128][104]
  float* fb  = (float*)(M2 + 13312);
  float* wsm = fb;                       // 96
  float* tnb = fb + 96;                  // 96
  float* zs  = fb + 192;                 // 128
  float* m3s = fb + 320;                 // 128
  float* fs  = fb + 448;                 // 256
  float* o2s = fb + 704;                 // 72
  float* red = fb + 776;                 // 4

  int b = blockIdx.x, tid = threadIdx.x;
  int w = tid >> 6, l = tid & 63, quad = l >> 4, lane16 = l & 15;

  // stage xlT [p][c]
  const short* xb = xlt + (size_t)b*8192;
  for (int t = tid; t < 1024; t += 512) {
    int p = t >> 4, c8 = t & 15;
    *(short8*)&XT[p*136 + c8*8] = *(const short8*)&xb[t*8];
  }
  __syncthreads();

  // phase 1a: At[r][p] = Wap @ xl + b215   (M=224, N=64, K=128)
  for (int t = w; t < 56; t += 8) {
    int mt = t >> 2, n4 = t & 3;
    f32x4 acc = (f32x4)(0.f);
    #pragma unroll
    for (int ks = 0; ks < 4; ++ks) {
      short8 a  = *(const short8*)&wapbf[(size_t)(mt*16+lane16)*128 + ks*32 + quad*8];
      short8 b8 = *(const short8*)&XT[(n4*16+lane16)*136 + ks*32 + quad*8];
      acc = __builtin_amdgcn_mfma_f32_16x16x32_bf16(a, b8, acc, 0, 0, 0);
    }
    int p = n4*16 + lane16;
    #pragma unroll
    for (int r = 0; r < 4; ++r) {
      int rr = mt*16 + quad*4 + r;
      At[rr*72 + p] = (p < 49) ? (short)f2bf(acc[r] + b215[rr]) : (short)0;
    }
  }
  __syncthreads();

  // phase 1b: M1[m][d] = relu(a-rows @ ps-rows^T)   (M=96, N=128, K=64)
  for (int t = w; t < 48; t += 8) {
    int mt = t / 8, n4 = t % 8;
    f32x4 acc = (f32x4)(0.f);
    #pragma unroll
    for (int ks = 0; ks < 2; ++ks) {
      short8 a  = *(const short8*)&At[(128 + mt*16 + lane16)*72 + ks*32 + quad*8];
      short8 b8 = *(const short8*)&At[(n4*16+lane16)*72 + ks*32 + quad*8];
      acc = __builtin_amdgcn_mfma_f32_16x16x32_bf16(a, b8, acc, 0, 0, 0);
    }
    int d = n4*16 + lane16;
    #pragma unroll
    for (int r = 0; r < 4; ++r) {
      int m = mt*16 + quad*4 + r;
      M1[m*136 + d] = (short)f2bf(fmaxf(acc[r], 0.f));
    }
  }
  __syncthreads();

  // phase 2: G[o][m] = Wg2 @ m1 + nt + bg   (M=128, N=96, K=128)
  const float* ntb = nt + (size_t)(b & 1)*11264;
  for (int t = w; t < 48; t += 8) {
    int mt = t / 6, n4 = t % 6;
    f32x4 acc = (f32x4)(0.f);
    #pragma unroll
    for (int ks = 0; ks < 4; ++ks) {
      short8 a  = *(const short8*)&wg2bf[(size_t)(mt*16+lane16)*128 + ks*32 + quad*8];
      short8 b8 = *(const short8*)&M1[(n4*16+lane16)*136 + ks*32 + quad*8];
      acc = __builtin_amdgcn_mfma_f32_16x16x32_bf16(a, b8, acc, 0, 0, 0);
    }
    int m = n4*16 + lane16;
    #pragma unroll
    for (int r = 0; r < 4; ++r) {
      int o = mt*16 + quad*4 + r;
      float v = acc[r] + bg[o] + ((m < 88) ? ntb[o*88 + m] : 0.f);
      G[o*104 + m] = (short)f2bf(v);
    }
  }
  __syncthreads();

  // phase 3: M2[c][n] = relu(G @ enp)   (M=128, N=96, K=96; enp symmetric)
  for (int t = w; t < 48; t += 8) {
    int mt = t / 6, n4 = t % 6;
    f32x4 acc = (f32x4)(0.f);
    #pragma unroll
    for (int ks = 0; ks < 3; ++ks) {
      short8 a  = *(const short8*)&G[(mt*16+lane16)*104 + ks*32 + quad*8];
      short8 b8 = *(const short8*)&enpbf[(size_t)(n4*16+lane16)*96 + ks*32 + quad*8];
      acc = __builtin_amdgcn_mfma_f32_16x16x32_bf16(a, b8, acc, 0, 0, 0);
    }
    int n = n4*16 + lane16;
    #pragma unroll
    for (int r = 0; r < 4; ++r) {
      int c = mt*16 + quad*4 + r;
      M2[c*104 + n] = (short)f2bf(fmaxf(acc[r], 0.f));
    }
  }
  __syncthreads();

  // phase 4: node softmax + m3 = relu(Wsp @ (m2 @ att) + bsp)
  if (tid < 87) {
    float s = 0.f;
    for (int c = 0; c < 128; ++c) s += Ws[c] * bf2f((unsigned short)M2[c*104 + tid]);
    tnb[tid] = s;
  }
  __syncthreads();
  if (tid == 0) {
    float mx = tnb[0];
    for (int j = 1; j < 87; ++j) mx = fmaxf(mx, tnb[j]);
    red[0] = mx;
  }
  __syncthreads();
  if (tid < 87) wsm[tid] = expf(tnb[tid] - red[0]);
  __syncthreads();
  if (tid == 0) {
    float sm = 0.f;
    for (int j = 0; j < 87; ++j) sm += wsm[j];
    red[0] = 1.f/sm;
  }
  __syncthreads();
  if (tid < 87) wsm[tid] *= red[0];
  __syncthreads();
  if (tid < 128) {
    float s = 0.f;
    for (int m = 0; m < 87; ++m) s += bf2f((unsigned short)M2[tid*104 + m]) * wsm[m];
    zs[tid] = s;
  }
  __syncthreads();
  if (tid < 128) {
    float s = 0.f;
    for (int c = 0; c < 128; ++c) s += Wsp[tid*128 + c] * zs[c];
    m3s[tid] = fmaxf(s + bsp[tid], 0.f);
  }
  __syncthreads();

  // phase 5: features / outputs2 / softmax
  if (tid < 256) {
    float s = 0.f;
    #pragma unroll 4
    for (int d4 = 0; d4 < 32; ++d4) {
      float4 w4 = *(const float4*)&wc[tid*128 + d4*4];
      s += w4.x*m3s[d4*4] + w4.y*m3s[d4*4+1] + w4.z*m3s[d4*4+2] + w4.w*m3s[d4*4+3];
    }
    float f = featp[b*256 + tid] + bc[tid] + s;
    fs[tid] = f;
    feat[b*256 + tid] = f;
  }
  __syncthreads();
  if (tid < 65) {
    float s = 0.f;
    for (int j = 0; j < 256; ++j) s += Wfc2[tid*256 + j] * fs[j];
    out2[b*65 + tid] = s;
    o2s[tid] = s;
  }
  __syncthreads();
  if (tid == 0) {
    float mx = o2s[0];
    for (int j = 1; j < 65; ++j) mx = fmaxf(mx, o2s[j]);
    float sm = 0.f;
    for (int j = 0; j < 65; ++j) sm += expf(o2s[j]-mx);
    red[0] = mx; red[1] = 1.f/sm;
  }
  __syncthreads();
  if (tid < 65) soft[b*65 + tid] = expf(o2s[tid]-red[0]) * red[1];
}

// ---------------- launch ----------------
extern "C" void kernel_launch(void* const* d_in, const int* in_sizes, int n_in,
                              void* d_out, int out_size, void* d_ws, size_t ws_size,
                              hipStream_t stream)
{
  (void)in_sizes; (void)n_in; (void)out_size; (void)ws_size;
  const float* x      = (const float*)d_in[0];
  const float* Wb     = (const float*)d_in[1];
  const float* bb     = (const float*)d_in[2];
  const float* Wfc    = (const float*)d_in[3];
  const float* Wfc2   = (const float*)d_in[4];
  const float* Wo1    = (const float*)d_in[5];
  const float* bo1    = (const float*)d_in[6];
  const float* Wo2    = (const float*)d_in[7];
  const float* bo2    = (const float*)d_in[8];
  const float* Wa     = (const float*)d_in[9];
  const float* ba     = (const float*)d_in[10];
  const float* Wps    = (const float*)d_in[11];
  const float* bps    = (const float*)d_in[12];
  const float* node_p = (const float*)d_in[13];
  const float* Wg     = (const float*)d_in[14];
  const float* bg     = (const float*)d_in[15];
  const float* Wsp    = (const float*)d_in[16];
  const float* bsp    = (const float*)d_in[17];
  const float* Ws     = (const float*)d_in[18];
  const float* Wox1   = (const float*)d_in[20];
  const float* box1   = (const float*)d_in[21];
  const float* Wox2   = (const float*)d_in[22];
  const float* box2   = (const float*)d_in[23];
  const float* edge   = (const float*)d_in[24];

  float* ws   = (float*)d_ws;
  float* out  = (float*)d_out;
  float* feat  = out;            // (256,256)
  float* out2  = out + 65536;    // (256,65)
  float* soft  = out + 82176;    // (256,65)
  float* preo  = out + 98816;    // (256,65)
  float* featp = out + 115456;   // (256,256)

  ksetup<<<2675, 256, 0, stream>>>(Wb, bb, Wa, ba, Wps, bps, Wg, edge, ws, featp);
  kgemmTW<<<128, 256, 0, stream>>>(Wo2, Wo1, Wox2, Wox1, ws);
  kvec<<<544, 256, 0, stream>>>(Wox2, box1, box2, Wo2, bo1, bo2, ws);
  kbc<<<64, 256, 0, stream>>>(Wb, bb, ws);
  kgemmWc<<<dim3(4,2,8), 256, 0, stream>>>(ws);
  kmain4<<<dim3(256,2), 512, 0, stream>>>(x, (const short*)(ws + OFF_W12BF),
                                          (short*)(ws + OFF_XPBF), ws + OFF_PART);
  kfinal<<<256, 256, 0, stream>>>(ws + OFF_PART, ws + OFF_B12, (short*)(ws + OFF_XLT));
  kfeat<<<dim3(4,4,8), 256, 0, stream>>>((const short*)(ws + OFF_XPBF),
                                         (const short*)(ws + OFF_WBBF), featp);
  kpr<<<256, 128, 0, stream>>>(featp, Wfc, ws + OFF_WPR, preo, ws + OFF_VY);
  knode<<<88, 256, 0, stream>>>(Wg, node_p, ws + OFF_VY, ws + OFF_NT);
  kgraph_all<<<256, 512, 132144, stream>>>((const short*)(ws + OFF_XLT),
                                           (const short*)(ws + OFF_WAPBF),
                                           ws + OFF_B215,
                                           (const short*)(ws + OFF_WG2BF),
                                           ws + OFF_NT, bg,
                                           (const short*)(ws + OFF_ENPBF),
                                           Wsp, bsp, Ws,
                                           ws + OFF_WC, ws + OFF_BC, featp, Wfc2,
                                           feat, out2, soft);
}

// Round 6
// 369.880 us; speedup vs baseline: 2.4237x; 1.1720x over previous
//
#include <hip/hip_runtime.h>
#include <cmath>

// M=87, CLS=65, K=128, DL=DC=128, DO=2048, BD=256, B=256, HW=49

typedef __attribute__((ext_vector_type(8))) short short8;
typedef __attribute__((ext_vector_type(4))) short s16x4;
typedef __attribute__((ext_vector_type(4))) float f32x4;

// ---------------- workspace layout (float offsets) ----------------
constexpr size_t OFF_W12BF = 0;          // [128][2048] bf16
constexpr size_t OFF_T1BF  = 131072;     // [2048][128] bf16 (Wox2@Wox1)
constexpr size_t OFF_WBBF  = 262144;     // [256][2048] bf16
constexpr size_t OFF_XPBF  = 524288;     // [256][2048] bf16
constexpr size_t OFF_WAPBF = 786432;     // [224][128] bf16 (Wps;Wa;0)
constexpr size_t OFF_WG2BF = 800768;     // [128][128] bf16
constexpr size_t OFF_ENPBF = 808960;     // [96][96] bf16 edge_norm (symmetric)
constexpr size_t OFF_B215  = 813568;     // 224 f
constexpr size_t OFF_B12   = 813792;     // 128 f
constexpr size_t OFF_WPR   = 813920;     // 87x87 f
constexpr size_t OFF_BTMP  = 821496;     // 2048 f
constexpr size_t OFF_WC    = 823544;     // [256][128] f (atomic accum)
constexpr size_t OFF_BC    = 856312;     // 256 f
constexpr size_t OFF_VY    = 856568;     // 256x87 f
constexpr size_t OFF_NT    = 878848;     // [2][128][88] f
constexpr size_t OFF_PART  = 901376;     // [2][256][128][52] f partial xl

__device__ __forceinline__ unsigned short f2bf(float f) {
  unsigned u = __builtin_bit_cast(unsigned, f);
  u += 0x7fffu + ((u >> 16) & 1u);
  return (unsigned short)(u >> 16);
}
__device__ __forceinline__ float bf2f(unsigned short s) {
  return __builtin_bit_cast(float, ((unsigned)s) << 16);
}

// ---------------- ksetup_all: casts/inits + kgemmTW + kvec merged ----------------
__global__ __launch_bounds__(256) void ksetup_all(
    const float* __restrict__ Wb,  const float* __restrict__ bb,
    const float* __restrict__ Wa,  const float* __restrict__ ba,
    const float* __restrict__ Wps, const float* __restrict__ bps,
    const float* __restrict__ Wg,  const float* __restrict__ edge,
    const float* __restrict__ Wo2, const float* __restrict__ Wo1,
    const float* __restrict__ Wox2,const float* __restrict__ Wox1,
    const float* __restrict__ box1,const float* __restrict__ box2,
    const float* __restrict__ bo1, const float* __restrict__ bo2,
    float* __restrict__ ws, float* __restrict__ featp)
{
  __shared__ alignas(16) short As[64*72];
  __shared__ alignas(16) short Bs[64*72];
  int blk = blockIdx.x, tid = threadIdx.x;
  if (blk < 2048) {                        // WBBF cast
    int idx = blk*256 + tid;
    ((unsigned short*)(ws+OFF_WBBF))[idx] = f2bf(Wb[idx]);
  } else if (blk < 2304) {                 // featp init = bb
    int idx = (blk-2048)*256 + tid;
    featp[idx] = bb[idx & 255];
  } else if (blk < 2432) {                 // zero Wc
    int idx = (blk-2304)*256 + tid;
    ws[OFF_WC + idx] = 0.f;
  } else if (blk < 2544) {                 // WAPBF [r=224][c=128]
    int idx = (blk-2432)*256 + tid;        // < 28672
    int r = idx >> 7, c = idx & 127;
    float v;
    if (r < 128)      v = Wps[r*128 + c];
    else if (r < 215) v = Wa[(r-128)*128 + c];
    else              v = 0.f;
    ((unsigned short*)(ws+OFF_WAPBF))[idx] = f2bf(v);
  } else if (blk < 2608) {                 // WG2BF [o][d]
    int idx = (blk-2544)*256 + tid;        // < 16384
    int o = idx >> 7, d = idx & 127;
    ((unsigned short*)(ws+OFF_WG2BF))[idx] = f2bf(Wg[o*256 + 128 + d]);
  } else if (blk < 2644) {                 // ENPBF [96][96], zero-padded
    int idx = (blk-2608)*256 + tid;        // < 9216
    int m = idx / 96, n = idx % 96;
    float v = 0.f;
    if (m < 87 && n < 87) {
      float sm = 0.f, sn = 0.f;
      for (int k = 0; k < 87; ++k) { sm += edge[k*87+m]; sn += edge[k*87+n]; }
      v = edge[m*87+n] / sqrtf(sm*sn);
    }
    ((unsigned short*)(ws+OFF_ENPBF))[idx] = f2bf(v);
  } else if (blk < 2674) {                 // WPR fp32
    int idx = (blk-2644)*256 + tid;
    if (idx < 87*87) {
      int j = idx % 87;
      float rs = 0.f;
      for (int k = 0; k < 87; ++k) rs += edge[j*87+k];
      ws[OFF_WPR + idx] = 0.85f * edge[idx] / rs;
    }
  } else if (blk == 2674) {                // b215 (pad 224)
    if (tid < 224) {
      float v = (tid < 128) ? bps[tid] : (tid < 215 ? ba[tid-128] : 0.f);
      ws[OFF_B215 + tid] = v;
    }
  } else if (blk < 2803) {                 // ---- kgemmTW: W12 / T1 MFMA tiles ----
    int gb = blk - 2675;
    const float *A, *B; unsigned short* C; int lda, ldb, ldc, i0, j0;
    if (gb < 64) {   // W12 [128][2048] = Wo2@Wo1
      A = Wo2; B = Wo1; C = (unsigned short*)(ws+OFF_W12BF);
      lda = 512; ldb = 2048; ldc = 2048;
      i0 = (gb & 1)*64; j0 = (gb >> 1)*64;
    } else {         // T1 [2048][128] = Wox2@Wox1
      int b2 = gb - 64;
      A = Wox2; B = Wox1; C = (unsigned short*)(ws+OFF_T1BF);
      lda = 512; ldb = 128; ldc = 128;
      i0 = (b2 >> 1)*64; j0 = (b2 & 1)*64;
    }
    int w = tid >> 6, l = tid & 63, quad = l >> 4, lane16 = l & 15;
    f32x4 acc[4];
    #pragma unroll
    for (int i = 0; i < 4; ++i) acc[i] = (f32x4)(0.f);
    for (int kc = 0; kc < 512; kc += 64) {
      for (int t = tid; t < 1024; t += 256) {      // A stage [m][k]
        int r = t >> 4, k4 = t & 15;
        float4 v = *(const float4*)&A[(size_t)(i0+r)*lda + kc + k4*4];
        s16x4 sv; sv[0]=(short)f2bf(v.x); sv[1]=(short)f2bf(v.y); sv[2]=(short)f2bf(v.z); sv[3]=(short)f2bf(v.w);
        *(s16x4*)&As[r*72 + k4*4] = sv;
      }
      for (int t = tid; t < 1024; t += 256) {      // B transpose-stage -> [n][k]
        int kr = t >> 4, n4 = t & 15;
        float4 v = *(const float4*)&B[(size_t)(kc+kr)*ldb + j0 + n4*4];
        Bs[(n4*4+0)*72 + kr] = (short)f2bf(v.x);
        Bs[(n4*4+1)*72 + kr] = (short)f2bf(v.y);
        Bs[(n4*4+2)*72 + kr] = (short)f2bf(v.z);
        Bs[(n4*4+3)*72 + kr] = (short)f2bf(v.w);
      }
      __syncthreads();
      #pragma unroll
      for (int ks = 0; ks < 2; ++ks) {
        short8 a = *(const short8*)&As[(w*16+lane16)*72 + ks*32 + quad*8];
        #pragma unroll
        for (int nt = 0; nt < 4; ++nt) {
          short8 b8 = *(const short8*)&Bs[(nt*16+lane16)*72 + ks*32 + quad*8];
          acc[nt] = __builtin_amdgcn_mfma_f32_16x16x32_bf16(a, b8, acc[nt], 0, 0, 0);
        }
      }
      __syncthreads();
    }
    #pragma unroll
    for (int nt = 0; nt < 4; ++nt)
      #pragma unroll
      for (int r = 0; r < 4; ++r)
        C[(size_t)(i0 + w*16 + quad*4 + r)*ldc + j0 + nt*16 + lane16] = f2bf(acc[nt][r]);
  } else {                                  // ---- kvec: btmp / b12 ----
    int vb = blk - 2803;
    int w = tid >> 6, l = tid & 63;
    if (vb < 512) {
      int o = vb*4 + w;
      float s = 0.f;
      for (int h = l; h < 512; h += 64) s += Wox2[(size_t)o*512 + h] * box1[h];
      for (int off = 32; off; off >>= 1) s += __shfl_down(s, off, 64);
      if (l == 0) ws[OFF_BTMP + o] = s + box2[o];
    } else {
      int o = (vb - 512)*4 + w;
      float s = 0.f;
      for (int h = l; h < 512; h += 64) s += Wo2[(size_t)o*512 + h] * bo1[h];
      for (int off = 32; off; off >>= 1) s += __shfl_down(s, off, 64);
      if (l == 0) ws[OFF_B12 + o] = s + bo2[o];
    }
  }
}

// ---------------- kwcbc: Wc += WBBF@T1BF (split-K atomic) ; bc = Wb@btmp+bb ----------------
__global__ __launch_bounds__(256) void kwcbc(const float* __restrict__ Wb,
                                             const float* __restrict__ bb,
                                             float* __restrict__ ws)
{
  __shared__ alignas(16) short As[64*72];
  __shared__ alignas(16) short Bs[64*72];
  int blk = blockIdx.x, tid = threadIdx.x;
  if (blk < 64) {
    const short* wbbf = (const short*)(ws+OFF_WBBF);
    const short* t1s  = (const short*)(ws+OFF_T1BF);
    int i0 = (blk & 3)*64, j0 = ((blk >> 2) & 1)*64, kc0 = (blk >> 3)*256;
    int w = tid >> 6, l = tid & 63, quad = l >> 4, lane16 = l & 15;
    f32x4 acc[4];
    #pragma unroll
    for (int i = 0; i < 4; ++i) acc[i] = (f32x4)(0.f);
    for (int kc = kc0; kc < kc0+256; kc += 64) {
      for (int t = tid; t < 512; t += 256) {       // A copy (already bf16)
        int r = t >> 3, c8 = t & 7;
        *(short8*)&As[r*72 + c8*8] = *(const short8*)&wbbf[(size_t)(i0+r)*2048 + kc + c8*8];
      }
      for (int t = tid; t < 1024; t += 256) {      // B transpose-stage
        int kr = t >> 4, n4 = t & 15;
        s16x4 v = *(const s16x4*)&t1s[(size_t)(kc+kr)*128 + j0 + n4*4];
        Bs[(n4*4+0)*72 + kr] = v[0];
        Bs[(n4*4+1)*72 + kr] = v[1];
        Bs[(n4*4+2)*72 + kr] = v[2];
        Bs[(n4*4+3)*72 + kr] = v[3];
      }
      __syncthreads();
      #pragma unroll
      for (int ks = 0; ks < 2; ++ks) {
        short8 a = *(const short8*)&As[(w*16+lane16)*72 + ks*32 + quad*8];
        #pragma unroll
        for (int nt = 0; nt < 4; ++nt) {
          short8 b8 = *(const short8*)&Bs[(nt*16+lane16)*72 + ks*32 + quad*8];
          acc[nt] = __builtin_amdgcn_mfma_f32_16x16x32_bf16(a, b8, acc[nt], 0, 0, 0);
        }
      }
      __syncthreads();
    }
    #pragma unroll
    for (int nt = 0; nt < 4; ++nt)
      #pragma unroll
      for (int r = 0; r < 4; ++r)
        atomicAdd(&ws[OFF_WC + (size_t)(i0 + w*16 + quad*4 + r)*128 + j0 + nt*16 + lane16], acc[nt][r]);
  } else {
    int j = (blk-64)*4 + (tid >> 6), l = tid & 63;
    float s = 0.f;
    for (int c = l; c < 2048; c += 64) s += Wb[(size_t)j*2048 + c] * ws[OFF_BTMP + c];
    for (int off = 32; off; off >>= 1) s += __shfl_down(s, off, 64);
    if (l == 0) ws[OFF_BC + j] = s + bb[j];
  }
}

// ---------------- kmain4: partial xl (fp32) over k-half; xp(bf16) fused ----------------
__global__ __launch_bounds__(512) void kmain4(const float* __restrict__ x,
                                              const short* __restrict__ w12bf,
                                              short* __restrict__ xpbf,
                                              float* __restrict__ part)
{
  __shared__ alignas(16) short Bt[2][52*72];
  int b = blockIdx.x, half = blockIdx.y, tid = threadIdx.x;
  int w = tid >> 6, l = tid & 63;
  int quad = l >> 4, lane16 = l & 15;
  const float* xb = x + ((size_t)b*2048 + half*1024)*49;

  int p0 = tid % 49, oct0 = tid / 49;
  bool has0 = (tid < 392);

  float g0[8];
  if (has0) {
    #pragma unroll
    for (int j = 0; j < 8; ++j) g0[j] = xb[(size_t)(oct0*8+j)*49 + p0];
  }

  f32x4 acc[4];
  #pragma unroll
  for (int i = 0; i < 4; ++i) acc[i] = (f32x4)(0.f);

  for (int kci = 0; kci < 16; ++kci) {
    int kc = kci*64;
    short* bt = Bt[kci & 1];
    if (has0) {
      short8 v;
      #pragma unroll
      for (int j = 0; j < 8; ++j) v[j] = (short)f2bf(g0[j]);
      *(short8*)(bt + p0*72 + oct0*8) = v;
    }
    __syncthreads();
    if (kci < 15 && has0) {
      const float* xc = xb + (size_t)(kc+64)*49;
      #pragma unroll
      for (int j = 0; j < 8; ++j) g0[j] = xc[(size_t)(oct0*8+j)*49 + p0];
    }
    const short* wr = w12bf + (size_t)(w*16 + lane16)*2048 + half*1024 + kc + quad*8;
    short8 a0 = *(const short8*)(wr);
    short8 a1 = *(const short8*)(wr + 32);
    #pragma unroll
    for (int ni = 0; ni < 4; ++ni) {
      const short* br = bt + (ni*16 + lane16)*72 + quad*8;
      short8 b0 = *(const short8*)(br);
      short8 b1 = *(const short8*)(br + 32);
      acc[ni] = __builtin_amdgcn_mfma_f32_16x16x32_bf16(a0, b0, acc[ni], 0, 0, 0);
      acc[ni] = __builtin_amdgcn_mfma_f32_16x16x32_bf16(a1, b1, acc[ni], 0, 0, 0);
    }
    if (tid < 64) {
      float s = 0.f;
      for (int p = 0; p < 49; ++p)
        s += bf2f((unsigned short)bt[p*72 + tid]);
      xpbf[(size_t)b*2048 + half*1024 + kc + tid] = (short)f2bf(s * (1.f/49.f));
    }
  }
  float* po = part + ((size_t)half*256 + b)*128*52;
  #pragma unroll
  for (int ni = 0; ni < 4; ++ni) {
    int p = ni*16 + lane16;
    if (p < 49) {
      #pragma unroll
      for (int r = 0; r < 4; ++r) {
        int o = w*16 + quad*4 + r;
        po[o*52 + p] = acc[ni][r];
      }
    }
  }
}

// ---------------- kfeat: featp += XPBF @ WBBF^T ----------------
__global__ __launch_bounds__(256) void kfeat(const short* __restrict__ xpbf,
                                             const short* __restrict__ wbbf,
                                             float* __restrict__ featp)
{
  int i0 = blockIdx.x*64, j0 = blockIdx.y*64, kc0 = blockIdx.z*256;
  int tid = threadIdx.x, w = tid >> 6, l = tid & 63, quad = l >> 4, lane16 = l & 15;
  f32x4 acc[4];
  #pragma unroll
  for (int i = 0; i < 4; ++i) acc[i] = (f32x4)(0.f);
  for (int kc = kc0; kc < kc0+256; kc += 32) {
    short8 a = *(const short8*)&xpbf[(size_t)(i0 + w*16 + lane16)*2048 + kc + quad*8];
    #pragma unroll
    for (int nt = 0; nt < 4; ++nt) {
      short8 b8 = *(const short8*)&wbbf[(size_t)(j0 + nt*16 + lane16)*2048 + kc + quad*8];
      acc[nt] = __builtin_amdgcn_mfma_f32_16x16x32_bf16(a, b8, acc[nt], 0, 0, 0);
    }
  }
  #pragma unroll
  for (int nt = 0; nt < 4; ++nt)
    #pragma unroll
    for (int r = 0; r < 4; ++r)
      atomicAdd(&featp[(size_t)(i0 + w*16 + quad*4 + r)*256 + j0 + nt*16 + lane16], acc[nt][r]);
}

// ---------------- kpr: pre_output + softmax + 64 PageRank iters -> v_y ----------------
// __launch_bounds__(128,1): lift VGPR cap so wrow[87] stays in registers (R5: spilled at 64 VGPR).
// 64 iters: contraction ratio 0.85 -> residual 0.85^64 ~ 3e-5, well under threshold.
__global__ __launch_bounds__(128, 1) void kpr(const float* __restrict__ featp,
                                              const float* __restrict__ Wfc,
                                              const float* __restrict__ wpr,
                                              float* __restrict__ preo,
                                              float* __restrict__ vy)
{
  __shared__ alignas(16) float fpr[256];
  __shared__ alignas(16) float po[68];
  __shared__ alignas(16) float vs[2][88];
  __shared__ float red[2];
  int b = blockIdx.x, tid = threadIdx.x;
  fpr[tid] = featp[b*256 + tid];
  fpr[tid+128] = featp[b*256 + 128 + tid];
  __syncthreads();
  if (tid < 65) {
    float s = 0.f;
    for (int c = 0; c < 256; c += 4) {
      float4 w4 = *(const float4*)&Wfc[tid*256 + c];
      s += w4.x*fpr[c] + w4.y*fpr[c+1] + w4.z*fpr[c+2] + w4.w*fpr[c+3];
    }
    po[tid] = s;
    preo[b*65 + tid] = s;
  }
  __syncthreads();
  if (tid < 64) {                          // wave-0 softmax reductions
    float v = po[tid];
    if (tid == 0) v = fmaxf(v, po[64]);
    float mx = v;
    #pragma unroll
    for (int off = 32; off; off >>= 1) mx = fmaxf(mx, __shfl_down(mx, off, 64));
    mx = __shfl(mx, 0, 64);
    float e = expf(po[tid]-mx) + ((tid == 0) ? expf(po[64]-mx) : 0.f);
    float sm = e;
    #pragma unroll
    for (int off = 32; off; off >>= 1) sm += __shfl_down(sm, off, 64);
    if (tid == 0) { red[0] = mx; red[1] = 1.f/sm; }
  }
  __syncthreads();
  float vinit = 0.f;
  if (tid >= 22 && tid < 87) vinit = expf(po[tid-22]-red[0]) * red[1];
  float s_i = vinit * 87.f;
  float wrow[87];
  if (tid < 87) {
    float add = s_i * (0.15f/87.0f);
    #pragma unroll
    for (int j = 0; j < 87; ++j) wrow[j] = wpr[tid*87 + j] + add;
    vs[0][tid] = s_i;
  }
  __syncthreads();
  for (int it = 0; it < 64; ++it) {
    const float* vc = vs[it & 1];
    if (tid < 87) {
      float nv = 0.f;
      #pragma unroll
      for (int j4 = 0; j4 < 21; ++j4) {
        float4 v4 = *(const float4*)&vc[j4*4];
        nv += wrow[j4*4+0]*v4.x + wrow[j4*4+1]*v4.y + wrow[j4*4+2]*v4.z + wrow[j4*4+3]*v4.w;
      }
      nv += wrow[84]*vc[84] + wrow[85]*vc[85] + wrow[86]*vc[86];
      vs[(it+1) & 1][tid] = nv;
    }
    __syncthreads();
  }
  if (tid < 64) {                          // norm via wave-0 reduce
    float v = vs[0][tid]*vs[0][tid];
    if (tid < 23) v += vs[0][64+tid]*vs[0][64+tid];
    #pragma unroll
    for (int off = 32; off; off >>= 1) v += __shfl_down(v, off, 64);
    if (tid == 0) red[0] = 1.f / fmaxf(sqrtf(v), 1e-12f);
  }
  __syncthreads();
  if (tid < 87) vy[b*87 + tid] = vinit + vs[0][tid]*red[0];
}

// ---------------- knode ----------------
__global__ __launch_bounds__(256) void knode(const float* __restrict__ Wg,
                                             const float* __restrict__ node_p,
                                             const float* __restrict__ vy,
                                             float* __restrict__ nt)
{
  int idx = blockIdx.x*256 + threadIdx.x;  // < 22528
  int par = idx / 11264;
  int r = idx % 11264;
  int o = r / 88, m = r % 88;
  float v = 0.f;
  if (m < 87) {
    float s = 0.f;
    for (int k = 0; k < 128; ++k)
      s += Wg[o*256+k] * node_p[k*87+m] * vy[(par*128+k)*87+m];
    v = s;
  }
  nt[idx] = v;
}

// ---------------- kgraph_all: MFMA graph chain + finale, all in LDS ----------------
__global__ __launch_bounds__(512) void kgraph_all(
    const float* __restrict__ part,  const float* __restrict__ b12,
    const short* __restrict__ wapbf, const float* __restrict__ b215,
    const short* __restrict__ wg2bf, const float* __restrict__ nt,
    const float* __restrict__ bg,    const short* __restrict__ enpbf,
    const float* __restrict__ Wsp,   const float* __restrict__ bsp,
    const float* __restrict__ Ws,    const float* __restrict__ wc,
    const float* __restrict__ bc,    const float* __restrict__ featp,
    const float* __restrict__ Wfc2,
    float* __restrict__ feat, float* __restrict__ out2, float* __restrict__ soft)
{
  extern __shared__ char smraw[];
  short* XT = (short*)smraw;             // [64][136]
  short* At = XT + 8704;                 // [224][72]
  short* M1 = At + 16128;                // [96][136]
  short* G  = M1 + 13056;                // [128][104]
  short* M2 = G  + 13312;                // [128][104]
  float* fb  = (float*)(M2 + 13312);
  float* wsm = fb;                       // 96
  float* tnb = fb + 96;                  // 96
  float* zs  = fb + 192;                 // 128
  float* m3s = fb + 320;                 // 128
  float* fs  = fb + 448;                 // 256
  float* o2s = fb + 704;                 // 72
  float* red = fb + 776;                 // 4

  int b = blockIdx.x, tid = threadIdx.x;
  int w = tid >> 6, l = tid & 63, quad = l >> 4, lane16 = l & 15;

  // stage XT[p][c] = bf16(part0 + part1 + b12) directly (kfinal fused away)
  const float* pa = part + (size_t)b*128*52;
  const float* pb = pa + (size_t)256*128*52;
  for (int t = tid; t < 6656; t += 512) {        // 128*52 entries, coalesced reads
    int o = t / 52, p = t % 52;
    XT[p*136 + o] = (short)f2bf(pa[t] + pb[t] + b12[o]);
  }
  for (int t = tid; t < 1536; t += 512) {        // zero rows p=52..63
    int p = 52 + t/128, o = t % 128;
    XT[p*136 + o] = 0;
  }
  __syncthreads();

  // phase 1a: At[r][p] = Wap @ xl + b215   (M=224, N=64, K=128)
  for (int t = w; t < 56; t += 8) {
    int mt = t >> 2, n4 = t & 3;
    f32x4 acc = (f32x4)(0.f);
    #pragma unroll
    for (int ks = 0; ks < 4; ++ks) {
      short8 a  = *(const short8*)&wapbf[(size_t)(mt*16+lane16)*128 + ks*32 + quad*8];
      short8 b8 = *(const short8*)&XT[(n4*16+lane16)*136 + ks*32 + quad*8];
      acc = __builtin_amdgcn_mfma_f32_16x16x32_bf16(a, b8, acc, 0, 0, 0);
    }
    int p = n4*16 + lane16;
    #pragma unroll
    for (int r = 0; r < 4; ++r) {
      int rr = mt*16 + quad*4 + r;
      At[rr*72 + p] = (p < 49) ? (short)f2bf(acc[r] + b215[rr]) : (short)0;
    }
  }
  __syncthreads();

  // phase 1b: M1[m][d] = relu(a-rows @ ps-rows^T)   (M=96, N=128, K=64)
  for (int t = w; t < 48; t += 8) {
    int mt = t / 8, n4 = t % 8;
    f32x4 acc = (f32x4)(0.f);
    #pragma unroll
    for (int ks = 0; ks < 2; ++ks) {
      short8 a  = *(const short8*)&At[(128 + mt*16 + lane16)*72 + ks*32 + quad*8];
      short8 b8 = *(const short8*)&At[(n4*16+lane16)*72 + ks*32 + quad*8];
      acc = __builtin_amdgcn_mfma_f32_16x16x32_bf16(a, b8, acc, 0, 0, 0);
    }
    int d = n4*16 + lane16;
    #pragma unroll
    for (int r = 0; r < 4; ++r) {
      int m = mt*16 + quad*4 + r;
      M1[m*136 + d] = (short)f2bf(fmaxf(acc[r], 0.f));
    }
  }
  __syncthreads();

  // phase 2: G[o][m] = Wg2 @ m1 + nt + bg   (M=128, N=96, K=128)
  const float* ntb = nt + (size_t)(b & 1)*11264;
  for (int t = w; t < 48; t += 8) {
    int mt = t / 6, n4 = t % 6;
    f32x4 acc = (f32x4)(0.f);
    #pragma unroll
    for (int ks = 0; ks < 4; ++ks) {
      short8 a  = *(const short8*)&wg2bf[(size_t)(mt*16+lane16)*128 + ks*32 + quad*8];
      short8 b8 = *(const short8*)&M1[(n4*16+lane16)*136 + ks*32 + quad*8];
      acc = __builtin_amdgcn_mfma_f32_16x16x32_bf16(a, b8, acc, 0, 0, 0);
    }
    int m = n4*16 + lane16;
    #pragma unroll
    for (int r = 0; r < 4; ++r) {
      int o = mt*16 + quad*4 + r;
      float v = acc[r] + bg[o] + ((m < 88) ? ntb[o*88 + m] : 0.f);
      G[o*104 + m] = (short)f2bf(v);
    }
  }
  __syncthreads();

  // phase 3: M2[c][n] = relu(G @ enp)   (M=128, N=96, K=96; enp symmetric)
  for (int t = w; t < 48; t += 8) {
    int mt = t / 6, n4 = t % 6;
    f32x4 acc = (f32x4)(0.f);
    #pragma unroll
    for (int ks = 0; ks < 3; ++ks) {
      short8 a  = *(const short8*)&G[(mt*16+lane16)*104 + ks*32 + quad*8];
      short8 b8 = *(const short8*)&enpbf[(size_t)(n4*16+lane16)*96 + ks*32 + quad*8];
      acc = __builtin_amdgcn_mfma_f32_16x16x32_bf16(a, b8, acc, 0, 0, 0);
    }
    int n = n4*16 + lane16;
    #pragma unroll
    for (int r = 0; r < 4; ++r) {
      int c = mt*16 + quad*4 + r;
      M2[c*104 + n] = (short)f2bf(fmaxf(acc[r], 0.f));
    }
  }
  __syncthreads();

  // phase 4: node softmax (wave-0 reductions) + m3 = relu(Wsp @ (m2 @ att) + bsp)
  if (tid < 87) {
    float s = 0.f;
    for (int c = 0; c < 128; ++c) s += Ws[c] * bf2f((unsigned short)M2[c*104 + tid]);
    tnb[tid] = s;
  }
  __syncthreads();
  if (tid < 64) {
    float v = tnb[tid];
    if (tid < 23) v = fmaxf(v, tnb[64+tid]);
    float mx = v;
    #pragma unroll
    for (int off = 32; off; off >>= 1) mx = fmaxf(mx, __shfl_down(mx, off, 64));
    mx = __shfl(mx, 0, 64);
    float e0 = expf(tnb[tid]-mx);
    float e1 = (tid < 23) ? expf(tnb[64+tid]-mx) : 0.f;
    float sm = e0 + e1;
    #pragma unroll
    for (int off = 32; off; off >>= 1) sm += __shfl_down(sm, off, 64);
    sm = __shfl(sm, 0, 64);
    float inv = 1.f/sm;
    wsm[tid] = e0*inv;
    if (tid < 23) wsm[64+tid] = e1*inv;
  }
  __syncthreads();
  if (tid < 128) {
    float s = 0.f;
    for (int m = 0; m < 87; ++m) s += bf2f((unsigned short)M2[tid*104 + m]) * wsm[m];
    zs[tid] = s;
  }
  __syncthreads();
  if (tid < 128) {
    float s = 0.f;
    for (int c = 0; c < 128; ++c) s += Wsp[tid*128 + c] * zs[c];
    m3s[tid] = fmaxf(s + bsp[tid], 0.f);
  }
  __syncthreads();

  // phase 5: features / outputs2 / softmax
  if (tid < 256) {
    float s = 0.f;
    #pragma unroll 4
    for (int d4 = 0; d4 < 32; ++d4) {
      float4 w4 = *(const float4*)&wc[tid*128 + d4*4];
      s += w4.x*m3s[d4*4] + w4.y*m3s[d4*4+1] + w4.z*m3s[d4*4+2] + w4.w*m3s[d4*4+3];
    }
    float f = featp[b*256 + tid] + bc[tid] + s;
    fs[tid] = f;
    feat[b*256 + tid] = f;
  }
  __syncthreads();
  if (tid < 65) {
    float s = 0.f;
    for (int j = 0; j < 256; ++j) s += Wfc2[tid*256 + j] * fs[j];
    out2[b*65 + tid] = s;
    o2s[tid] = s;
  }
  __syncthreads();
  if (tid < 64) {
    float v = o2s[tid];
    if (tid == 0) v = fmaxf(v, o2s[64]);
    float mx = v;
    #pragma unroll
    for (int off = 32; off; off >>= 1) mx = fmaxf(mx, __shfl_down(mx, off, 64));
    mx = __shfl(mx, 0, 64);
    float e = expf(o2s[tid]-mx) + ((tid == 0) ? expf(o2s[64]-mx) : 0.f);
    float sm = e;
    #pragma unroll
    for (int off = 32; off; off >>= 1) sm += __shfl_down(sm, off, 64);
    if (tid == 0) { red[0] = mx; red[1] = 1.f/sm; }
  }
  __syncthreads();
  if (tid < 65) soft[b*65 + tid] = expf(o2s[tid]-red[0]) * red[1];
}

// ---------------- launch ----------------
extern "C" void kernel_launch(void* const* d_in, const int* in_sizes, int n_in,
                              void* d_out, int out_size, void* d_ws, size_t ws_size,
                              hipStream_t stream)
{
  (void)in_sizes; (void)n_in; (void)out_size; (void)ws_size;
  const float* x      = (const float*)d_in[0];
  const float* Wb     = (const float*)d_in[1];
  const float* bb     = (const float*)d_in[2];
  const float* Wfc    = (const float*)d_in[3];
  const float* Wfc2   = (const float*)d_in[4];
  const float* Wo1    = (const float*)d_in[5];
  const float* bo1    = (const float*)d_in[6];
  const float* Wo2    = (const float*)d_in[7];
  const float* bo2    = (const float*)d_in[8];
  const float* Wa     = (const float*)d_in[9];
  const float* ba     = (const float*)d_in[10];
  const float* Wps    = (const float*)d_in[11];
  const float* bps    = (const float*)d_in[12];
  const float* node_p = (const float*)d_in[13];
  const float* Wg     = (const float*)d_in[14];
  const float* bg     = (const float*)d_in[15];
  const float* Wsp    = (const float*)d_in[16];
  const float* bsp    = (const float*)d_in[17];
  const float* Ws     = (const float*)d_in[18];
  const float* Wox1   = (const float*)d_in[20];
  const float* box1   = (const float*)d_in[21];
  const float* Wox2   = (const float*)d_in[22];
  const float* box2   = (const float*)d_in[23];
  const float* edge   = (const float*)d_in[24];

  float* ws   = (float*)d_ws;
  float* out  = (float*)d_out;
  float* feat  = out;            // (256,256)
  float* out2  = out + 65536;    // (256,65)
  float* soft  = out + 82176;    // (256,65)
  float* preo  = out + 98816;    // (256,65)
  float* featp = out + 115456;   // (256,256)

  ksetup_all<<<3347, 256, 0, stream>>>(Wb, bb, Wa, ba, Wps, bps, Wg, edge,
                                       Wo2, Wo1, Wox2, Wox1, box1, box2, bo1, bo2,
                                       ws, featp);
  kwcbc<<<128, 256, 0, stream>>>(Wb, bb, ws);
  kmain4<<<dim3(256,2), 512, 0, stream>>>(x, (const short*)(ws + OFF_W12BF),
                                          (short*)(ws + OFF_XPBF), ws + OFF_PART);
  kfeat<<<dim3(4,4,8), 256, 0, stream>>>((const short*)(ws + OFF_XPBF),
                                         (const short*)(ws + OFF_WBBF), featp);
  kpr<<<256, 128, 0, stream>>>(featp, Wfc, ws + OFF_WPR, preo, ws + OFF_VY);
  knode<<<88, 256, 0, stream>>>(Wg, node_p, ws + OFF_VY, ws + OFF_NT);
  kgraph_all<<<256, 512, 132144, stream>>>(ws + OFF_PART, ws + OFF_B12,
                                           (const short*)(ws + OFF_WAPBF),
                                           ws + OFF_B215,
                                           (const short*)(ws + OFF_WG2BF),
                                           ws + OFF_NT, bg,
                                           (const short*)(ws + OFF_ENPBF),
                                           Wsp, bsp, Ws,
                                           ws + OFF_WC, ws + OFF_BC, featp, Wfc2,
                                           feat, out2, soft);
}

// Round 7
// 362.569 us; speedup vs baseline: 2.4726x; 1.0202x over previous
//
#include <hip/hip_runtime.h>
#include <cmath>

// M=87, CLS=65, K=128, DL=DC=128, DO=2048, BD=256, B=256, HW=49

typedef __attribute__((ext_vector_type(8))) short short8;
typedef __attribute__((ext_vector_type(4))) short s16x4;
typedef __attribute__((ext_vector_type(4))) float f32x4;

// ---------------- workspace layout (float offsets) ----------------
constexpr size_t OFF_W12BF = 0;          // [128][2048] bf16
constexpr size_t OFF_T1BF  = 131072;     // [2048][128] bf16 (Wox2@Wox1)
constexpr size_t OFF_WBBF  = 262144;     // [256][2048] bf16
constexpr size_t OFF_XPBF  = 524288;     // [256][2048] bf16
constexpr size_t OFF_WAPBF = 786432;     // [224][128] bf16 (Wps;Wa;0)
constexpr size_t OFF_WG2BF = 800768;     // [128][128] bf16
constexpr size_t OFF_ENPBF = 808960;     // [96][96] bf16 edge_norm (symmetric)
constexpr size_t OFF_B215  = 813568;     // 224 f
constexpr size_t OFF_B12   = 813792;     // 128 f
constexpr size_t OFF_WPR   = 813920;     // 87x87 f
constexpr size_t OFF_BTMP  = 821496;     // 2048 f
constexpr size_t OFF_WC    = 823544;     // [256][128] f (atomic accum)
constexpr size_t OFF_BC    = 856312;     // 256 f
constexpr size_t OFF_VY    = 856568;     // 256x87 f
constexpr size_t OFF_NT    = 878848;     // [2][128][88] f
constexpr size_t OFF_PART  = 901376;     // [4][256][128][52] f partial xl

__device__ __forceinline__ unsigned short f2bf(float f) {
  unsigned u = __builtin_bit_cast(unsigned, f);
  u += 0x7fffu + ((u >> 16) & 1u);
  return (unsigned short)(u >> 16);
}
__device__ __forceinline__ float bf2f(unsigned short s) {
  return __builtin_bit_cast(float, ((unsigned)s) << 16);
}

// ---------------- ksetup_all: casts/inits + weight GEMMs + bias vecs ----------------
__global__ __launch_bounds__(256) void ksetup_all(
    const float* __restrict__ Wb,  const float* __restrict__ bb,
    const float* __restrict__ Wa,  const float* __restrict__ ba,
    const float* __restrict__ Wps, const float* __restrict__ bps,
    const float* __restrict__ Wg,  const float* __restrict__ edge,
    const float* __restrict__ Wo2, const float* __restrict__ Wo1,
    const float* __restrict__ Wox2,const float* __restrict__ Wox1,
    const float* __restrict__ box1,const float* __restrict__ box2,
    const float* __restrict__ bo1, const float* __restrict__ bo2,
    float* __restrict__ ws, float* __restrict__ featp)
{
  __shared__ alignas(16) short As[64*72];
  __shared__ alignas(16) short Bs[64*72];
  int blk = blockIdx.x, tid = threadIdx.x;
  if (blk < 2048) {                        // WBBF cast
    int idx = blk*256 + tid;
    ((unsigned short*)(ws+OFF_WBBF))[idx] = f2bf(Wb[idx]);
  } else if (blk < 2304) {                 // featp init = bb
    int idx = (blk-2048)*256 + tid;
    featp[idx] = bb[idx & 255];
  } else if (blk < 2432) {                 // zero Wc
    int idx = (blk-2304)*256 + tid;
    ws[OFF_WC + idx] = 0.f;
  } else if (blk < 2544) {                 // WAPBF [r=224][c=128]
    int idx = (blk-2432)*256 + tid;        // < 28672
    int r = idx >> 7, c = idx & 127;
    float v;
    if (r < 128)      v = Wps[r*128 + c];
    else if (r < 215) v = Wa[(r-128)*128 + c];
    else              v = 0.f;
    ((unsigned short*)(ws+OFF_WAPBF))[idx] = f2bf(v);
  } else if (blk < 2608) {                 // WG2BF [o][d]
    int idx = (blk-2544)*256 + tid;        // < 16384
    int o = idx >> 7, d = idx & 127;
    ((unsigned short*)(ws+OFF_WG2BF))[idx] = f2bf(Wg[o*256 + 128 + d]);
  } else if (blk < 2644) {                 // ENPBF [96][96], zero-padded
    int idx = (blk-2608)*256 + tid;        // < 9216
    int m = idx / 96, n = idx % 96;
    float v = 0.f;
    if (m < 87 && n < 87) {
      float sm = 0.f, sn = 0.f;
      for (int k = 0; k < 87; ++k) { sm += edge[k*87+m]; sn += edge[k*87+n]; }
      v = edge[m*87+n] / sqrtf(sm*sn);
    }
    ((unsigned short*)(ws+OFF_ENPBF))[idx] = f2bf(v);
  } else if (blk < 2674) {                 // WPR fp32
    int idx = (blk-2644)*256 + tid;
    if (idx < 87*87) {
      int j = idx % 87;
      float rs = 0.f;
      for (int k = 0; k < 87; ++k) rs += edge[j*87+k];
      ws[OFF_WPR + idx] = 0.85f * edge[idx] / rs;
    }
  } else if (blk == 2674) {                // b215 (pad 224)
    if (tid < 224) {
      float v = (tid < 128) ? bps[tid] : (tid < 215 ? ba[tid-128] : 0.f);
      ws[OFF_B215 + tid] = v;
    }
  } else if (blk < 2803) {                 // ---- W12 / T1 MFMA tiles ----
    int gb = blk - 2675;
    const float *A, *B; unsigned short* C; int lda, ldb, ldc, i0, j0;
    if (gb < 64) {   // W12 [128][2048] = Wo2@Wo1
      A = Wo2; B = Wo1; C = (unsigned short*)(ws+OFF_W12BF);
      lda = 512; ldb = 2048; ldc = 2048;
      i0 = (gb & 1)*64; j0 = (gb >> 1)*64;
    } else {         // T1 [2048][128] = Wox2@Wox1
      int b2 = gb - 64;
      A = Wox2; B = Wox1; C = (unsigned short*)(ws+OFF_T1BF);
      lda = 512; ldb = 128; ldc = 128;
      i0 = (b2 >> 1)*64; j0 = (b2 & 1)*64;
    }
    int w = tid >> 6, l = tid & 63, quad = l >> 4, lane16 = l & 15;
    f32x4 acc[4];
    #pragma unroll
    for (int i = 0; i < 4; ++i) acc[i] = (f32x4)(0.f);
    for (int kc = 0; kc < 512; kc += 64) {
      for (int t = tid; t < 1024; t += 256) {      // A stage [m][k]
        int r = t >> 4, k4 = t & 15;
        float4 v = *(const float4*)&A[(size_t)(i0+r)*lda + kc + k4*4];
        s16x4 sv; sv[0]=(short)f2bf(v.x); sv[1]=(short)f2bf(v.y); sv[2]=(short)f2bf(v.z); sv[3]=(short)f2bf(v.w);
        *(s16x4*)&As[r*72 + k4*4] = sv;
      }
      for (int t = tid; t < 1024; t += 256) {      // B transpose-stage -> [n][k]
        int kr = t >> 4, n4 = t & 15;
        float4 v = *(const float4*)&B[(size_t)(kc+kr)*ldb + j0 + n4*4];
        Bs[(n4*4+0)*72 + kr] = (short)f2bf(v.x);
        Bs[(n4*4+1)*72 + kr] = (short)f2bf(v.y);
        Bs[(n4*4+2)*72 + kr] = (short)f2bf(v.z);
        Bs[(n4*4+3)*72 + kr] = (short)f2bf(v.w);
      }
      __syncthreads();
      #pragma unroll
      for (int ks = 0; ks < 2; ++ks) {
        short8 a = *(const short8*)&As[(w*16+lane16)*72 + ks*32 + quad*8];
        #pragma unroll
        for (int nt = 0; nt < 4; ++nt) {
          short8 b8 = *(const short8*)&Bs[(nt*16+lane16)*72 + ks*32 + quad*8];
          acc[nt] = __builtin_amdgcn_mfma_f32_16x16x32_bf16(a, b8, acc[nt], 0, 0, 0);
        }
      }
      __syncthreads();
    }
    #pragma unroll
    for (int nt = 0; nt < 4; ++nt)
      #pragma unroll
      for (int r = 0; r < 4; ++r)
        C[(size_t)(i0 + w*16 + quad*4 + r)*ldc + j0 + nt*16 + lane16] = f2bf(acc[nt][r]);
  } else {                                  // ---- btmp / b12 ----
    int vb = blk - 2803;
    int w = tid >> 6, l = tid & 63;
    if (vb < 512) {
      int o = vb*4 + w;
      float s = 0.f;
      for (int h = l; h < 512; h += 64) s += Wox2[(size_t)o*512 + h] * box1[h];
      for (int off = 32; off; off >>= 1) s += __shfl_down(s, off, 64);
      if (l == 0) ws[OFF_BTMP + o] = s + box2[o];
    } else {
      int o = (vb - 512)*4 + w;
      float s = 0.f;
      for (int h = l; h < 512; h += 64) s += Wo2[(size_t)o*512 + h] * bo1[h];
      for (int off = 32; off; off >>= 1) s += __shfl_down(s, off, 64);
      if (l == 0) ws[OFF_B12 + o] = s + bo2[o];
    }
  }
}

// ---------------- kmain5: partial xl over k-quarter; xp(bf16) fused ----------------
// grid (256 batches, 4 quarters) x 512 thr: >=3 blocks/CU, float4 staging loads.
__global__ __launch_bounds__(512, 6) void kmain5(const float* __restrict__ x,
                                                 const short* __restrict__ w12bf,
                                                 short* __restrict__ xpbf,
                                                 float* __restrict__ part)
{
  __shared__ alignas(16) short Bt[2][64*72];
  int b = blockIdx.x, q = blockIdx.y, tid = threadIdx.x;
  int w = tid >> 6, l = tid & 63;
  int quad = l >> 4, lane16 = l & 15;
  const float* xb = x + ((size_t)b*2048 + q*512)*49;

  // staging tasks: 13 p-groups x 64 c = 832; thread t does tasks t and t+512
  int p4A = tid % 13, cA = tid / 13;
  int tB = tid + 512;
  int p4B = tB % 13, cB = tB / 13;
  bool hasB = (tid < 320);

  float fA[4], fB[4];
  {
    if (p4A < 12) {
      float4 v = *(const float4*)(xb + cA*49 + p4A*4);
      fA[0]=v.x; fA[1]=v.y; fA[2]=v.z; fA[3]=v.w;
    } else fA[0] = xb[cA*49 + 48];
    if (hasB) {
      if (p4B < 12) {
        float4 v = *(const float4*)(xb + cB*49 + p4B*4);
        fB[0]=v.x; fB[1]=v.y; fB[2]=v.z; fB[3]=v.w;
      } else fB[0] = xb[cB*49 + 48];
    }
  }

  f32x4 acc[4];
  #pragma unroll
  for (int i = 0; i < 4; ++i) acc[i] = (f32x4)(0.f);

  for (int kci = 0; kci < 8; ++kci) {
    short* bt = Bt[kci & 1];
    if (p4A < 12) {
      #pragma unroll
      for (int i = 0; i < 4; ++i) bt[(p4A*4+i)*72 + cA] = (short)f2bf(fA[i]);
    } else bt[48*72 + cA] = (short)f2bf(fA[0]);
    if (hasB) {
      if (p4B < 12) {
        #pragma unroll
        for (int i = 0; i < 4; ++i) bt[(p4B*4+i)*72 + cB] = (short)f2bf(fB[i]);
      } else bt[48*72 + cB] = (short)f2bf(fB[0]);
    }
    __syncthreads();
    if (kci < 7) {                           // prefetch next chunk
      const float* xc = xb + (size_t)(kci+1)*64*49;
      if (p4A < 12) {
        float4 v = *(const float4*)(xc + cA*49 + p4A*4);
        fA[0]=v.x; fA[1]=v.y; fA[2]=v.z; fA[3]=v.w;
      } else fA[0] = xc[cA*49 + 48];
      if (hasB) {
        if (p4B < 12) {
          float4 v = *(const float4*)(xc + cB*49 + p4B*4);
          fB[0]=v.x; fB[1]=v.y; fB[2]=v.z; fB[3]=v.w;
        } else fB[0] = xc[cB*49 + 48];
      }
    }
    // A frags from global (L2-resident); wave w owns o rows [w*16, w*16+16)
    const short* wr = w12bf + (size_t)(w*16 + lane16)*2048 + q*512 + kci*64 + quad*8;
    short8 a0 = *(const short8*)(wr);
    short8 a1 = *(const short8*)(wr + 32);
    #pragma unroll
    for (int ni = 0; ni < 4; ++ni) {
      const short* br = bt + (ni*16 + lane16)*72 + quad*8;
      short8 b0 = *(const short8*)(br);
      short8 b1 = *(const short8*)(br + 32);
      acc[ni] = __builtin_amdgcn_mfma_f32_16x16x32_bf16(a0, b0, acc[ni], 0, 0, 0);
      acc[ni] = __builtin_amdgcn_mfma_f32_16x16x32_bf16(a1, b1, acc[ni], 0, 0, 0);
    }
    if (tid < 64) {                          // fused xp for this chunk's c-range
      float s = 0.f;
      for (int p = 0; p < 49; ++p)
        s += bf2f((unsigned short)bt[p*72 + tid]);
      xpbf[(size_t)b*2048 + q*512 + kci*64 + tid] = (short)f2bf(s * (1.f/49.f));
    }
  }
  float* po = part + ((size_t)q*256 + b)*6656;   // [q][b][o][52]
  #pragma unroll
  for (int ni = 0; ni < 4; ++ni) {
    int p = ni*16 + lane16;
    if (p < 49) {
      #pragma unroll
      for (int r = 0; r < 4; ++r) {
        int o = w*16 + quad*4 + r;
        po[o*52 + p] = acc[ni][r];
      }
    }
  }
}

// ---------------- kwcf: Wc GEMM + bc + kfeat, one launch ----------------
__global__ __launch_bounds__(256) void kwcf(const float* __restrict__ Wb,
                                            const float* __restrict__ bb,
                                            const short* __restrict__ xpbf,
                                            float* __restrict__ featp,
                                            float* __restrict__ ws)
{
  __shared__ alignas(16) short As[64*72];
  __shared__ alignas(16) short Bs[64*72];
  int blk = blockIdx.x, tid = threadIdx.x;
  if (blk < 64) {                            // Wc += WBBF @ T1BF (split-K atomic)
    const short* wbbf = (const short*)(ws+OFF_WBBF);
    const short* t1s  = (const short*)(ws+OFF_T1BF);
    int i0 = (blk & 3)*64, j0 = ((blk >> 2) & 1)*64, kc0 = (blk >> 3)*256;
    int w = tid >> 6, l = tid & 63, quad = l >> 4, lane16 = l & 15;
    f32x4 acc[4];
    #pragma unroll
    for (int i = 0; i < 4; ++i) acc[i] = (f32x4)(0.f);
    for (int kc = kc0; kc < kc0+256; kc += 64) {
      for (int t = tid; t < 512; t += 256) {
        int r = t >> 3, c8 = t & 7;
        *(short8*)&As[r*72 + c8*8] = *(const short8*)&wbbf[(size_t)(i0+r)*2048 + kc + c8*8];
      }
      for (int t = tid; t < 1024; t += 256) {
        int kr = t >> 4, n4 = t & 15;
        s16x4 v = *(const s16x4*)&t1s[(size_t)(kc+kr)*128 + j0 + n4*4];
        Bs[(n4*4+0)*72 + kr] = v[0];
        Bs[(n4*4+1)*72 + kr] = v[1];
        Bs[(n4*4+2)*72 + kr] = v[2];
        Bs[(n4*4+3)*72 + kr] = v[3];
      }
      __syncthreads();
      #pragma unroll
      for (int ks = 0; ks < 2; ++ks) {
        short8 a = *(const short8*)&As[(w*16+lane16)*72 + ks*32 + quad*8];
        #pragma unroll
        for (int nt = 0; nt < 4; ++nt) {
          short8 b8 = *(const short8*)&Bs[(nt*16+lane16)*72 + ks*32 + quad*8];
          acc[nt] = __builtin_amdgcn_mfma_f32_16x16x32_bf16(a, b8, acc[nt], 0, 0, 0);
        }
      }
      __syncthreads();
    }
    #pragma unroll
    for (int nt = 0; nt < 4; ++nt)
      #pragma unroll
      for (int r = 0; r < 4; ++r)
        atomicAdd(&ws[OFF_WC + (size_t)(i0 + w*16 + quad*4 + r)*128 + j0 + nt*16 + lane16], acc[nt][r]);
  } else if (blk < 128) {                    // bc = Wb@btmp + bb
    int j = (blk-64)*4 + (tid >> 6), l = tid & 63;
    float s = 0.f;
    for (int c = l; c < 2048; c += 64) s += Wb[(size_t)j*2048 + c] * ws[OFF_BTMP + c];
    for (int off = 32; off; off >>= 1) s += __shfl_down(s, off, 64);
    if (l == 0) ws[OFF_BC + j] = s + bb[j];
  } else {                                   // featp += XPBF @ WBBF^T
    const short* wbbf = (const short*)(ws+OFF_WBBF);
    int idx = blk - 128;                     // 128 tiles: 4 x 4 x 8
    int i0 = (idx & 3)*64, j0 = ((idx >> 2) & 3)*64, kc0 = (idx >> 4)*256;
    int w = tid >> 6, l = tid & 63, quad = l >> 4, lane16 = l & 15;
    f32x4 acc[4];
    #pragma unroll
    for (int i = 0; i < 4; ++i) acc[i] = (f32x4)(0.f);
    for (int kc = kc0; kc < kc0+256; kc += 32) {
      short8 a = *(const short8*)&xpbf[(size_t)(i0 + w*16 + lane16)*2048 + kc + quad*8];
      #pragma unroll
      for (int nt = 0; nt < 4; ++nt) {
        short8 b8 = *(const short8*)&wbbf[(size_t)(j0 + nt*16 + lane16)*2048 + kc + quad*8];
        acc[nt] = __builtin_amdgcn_mfma_f32_16x16x32_bf16(a, b8, acc[nt], 0, 0, 0);
      }
    }
    #pragma unroll
    for (int nt = 0; nt < 4; ++nt)
      #pragma unroll
      for (int r = 0; r < 4; ++r)
        atomicAdd(&featp[(size_t)(i0 + w*16 + quad*4 + r)*256 + j0 + nt*16 + lane16], acc[nt][r]);
  }
}

// ---------------- kpr: pre_output + softmax + 64 PageRank iters -> v_y ----------------
__global__ __launch_bounds__(128, 1) void kpr(const float* __restrict__ featp,
                                              const float* __restrict__ Wfc,
                                              const float* __restrict__ wpr,
                                              float* __restrict__ preo,
                                              float* __restrict__ vy)
{
  __shared__ alignas(16) float fpr[256];
  __shared__ alignas(16) float po[68];
  __shared__ alignas(16) float vs[2][88];
  __shared__ float red[2];
  int b = blockIdx.x, tid = threadIdx.x;
  fpr[tid] = featp[b*256 + tid];
  fpr[tid+128] = featp[b*256 + 128 + tid];
  __syncthreads();
  if (tid < 65) {
    float s = 0.f;
    for (int c = 0; c < 256; c += 4) {
      float4 w4 = *(const float4*)&Wfc[tid*256 + c];
      s += w4.x*fpr[c] + w4.y*fpr[c+1] + w4.z*fpr[c+2] + w4.w*fpr[c+3];
    }
    po[tid] = s;
    preo[b*65 + tid] = s;
  }
  __syncthreads();
  if (tid < 64) {
    float v = po[tid];
    if (tid == 0) v = fmaxf(v, po[64]);
    float mx = v;
    #pragma unroll
    for (int off = 32; off; off >>= 1) mx = fmaxf(mx, __shfl_down(mx, off, 64));
    mx = __shfl(mx, 0, 64);
    float e = expf(po[tid]-mx) + ((tid == 0) ? expf(po[64]-mx) : 0.f);
    float sm = e;
    #pragma unroll
    for (int off = 32; off; off >>= 1) sm += __shfl_down(sm, off, 64);
    if (tid == 0) { red[0] = mx; red[1] = 1.f/sm; }
  }
  __syncthreads();
  float vinit = 0.f;
  if (tid >= 22 && tid < 87) vinit = expf(po[tid-22]-red[0]) * red[1];
  float s_i = vinit * 87.f;
  float wrow[87];
  if (tid < 87) {
    float add = s_i * (0.15f/87.0f);
    #pragma unroll
    for (int j = 0; j < 87; ++j) wrow[j] = wpr[tid*87 + j] + add;
    vs[0][tid] = s_i;
  }
  __syncthreads();
  for (int it = 0; it < 64; ++it) {
    const float* vc = vs[it & 1];
    if (tid < 87) {
      float nv = 0.f;
      #pragma unroll
      for (int j4 = 0; j4 < 21; ++j4) {
        float4 v4 = *(const float4*)&vc[j4*4];
        nv += wrow[j4*4+0]*v4.x + wrow[j4*4+1]*v4.y + wrow[j4*4+2]*v4.z + wrow[j4*4+3]*v4.w;
      }
      nv += wrow[84]*vc[84] + wrow[85]*vc[85] + wrow[86]*vc[86];
      vs[(it+1) & 1][tid] = nv;
    }
    __syncthreads();
  }
  if (tid < 64) {
    float v = vs[0][tid]*vs[0][tid];
    if (tid < 23) v += vs[0][64+tid]*vs[0][64+tid];
    #pragma unroll
    for (int off = 32; off; off >>= 1) v += __shfl_down(v, off, 64);
    if (tid == 0) red[0] = 1.f / fmaxf(sqrtf(v), 1e-12f);
  }
  __syncthreads();
  if (tid < 87) vy[b*87 + tid] = vinit + vs[0][tid]*red[0];
}

// ---------------- knode ----------------
__global__ __launch_bounds__(256) void knode(const float* __restrict__ Wg,
                                             const float* __restrict__ node_p,
                                             const float* __restrict__ vy,
                                             float* __restrict__ nt)
{
  int idx = blockIdx.x*256 + threadIdx.x;  // < 22528
  int par = idx / 11264;
  int r = idx % 11264;
  int o = r / 88, m = r % 88;
  float v = 0.f;
  if (m < 87) {
    float s = 0.f;
    for (int k = 0; k < 128; ++k)
      s += Wg[o*256+k] * node_p[k*87+m] * vy[(par*128+k)*87+m];
    v = s;
  }
  nt[idx] = v;
}

// ---------------- kgraph_all: MFMA graph chain + finale, all in LDS ----------------
__global__ __launch_bounds__(512) void kgraph_all(
    const float* __restrict__ part,  const float* __restrict__ b12,
    const short* __restrict__ wapbf, const float* __restrict__ b215,
    const short* __restrict__ wg2bf, const float* __restrict__ nt,
    const float* __restrict__ bg,    const short* __restrict__ enpbf,
    const float* __restrict__ Wsp,   const float* __restrict__ bsp,
    const float* __restrict__ Ws,    const float* __restrict__ wc,
    const float* __restrict__ bc,    const float* __restrict__ featp,
    const float* __restrict__ Wfc2,
    float* __restrict__ feat, float* __restrict__ out2, float* __restrict__ soft)
{
  extern __shared__ char smraw[];
  short* XT = (short*)smraw;             // [64][136]
  short* At = XT + 8704;                 // [224][72]
  short* M1 = At + 16128;                // [96][136]
  short* G  = M1 + 13056;                // [128][104]
  short* M2 = G  + 13312;                // [128][104]
  float* fb  = (float*)(M2 + 13312);
  float* wsm = fb;                       // 96
  float* tnb = fb + 96;                  // 96
  float* zs  = fb + 192;                 // 128
  float* m3s = fb + 320;                 // 128
  float* fs  = fb + 448;                 // 256
  float* o2s = fb + 704;                 // 72
  float* red = fb + 776;                 // 4

  int b = blockIdx.x, tid = threadIdx.x;
  int w = tid >> 6, l = tid & 63, quad = l >> 4, lane16 = l & 15;

  // stage XT[p][c] = bf16(sum of 4 quarter-partials + b12)
  const float* p0 = part + (size_t)b*6656;
  const float* p1 = p0 + (size_t)256*6656;
  const float* p2 = p1 + (size_t)256*6656;
  const float* p3 = p2 + (size_t)256*6656;
  for (int t = tid; t < 6656; t += 512) {
    int o = t / 52, p = t % 52;
    XT[p*136 + o] = (short)f2bf(p0[t] + p1[t] + p2[t] + p3[t] + b12[o]);
  }
  for (int t = tid; t < 1536; t += 512) {        // zero rows p=52..63
    int p = 52 + t/128, o = t % 128;
    XT[p*136 + o] = 0;
  }
  __syncthreads();

  // phase 1a: At[r][p] = Wap @ xl + b215   (M=224, N=64, K=128)
  for (int t = w; t < 56; t += 8) {
    int mt = t >> 2, n4 = t & 3;
    f32x4 acc = (f32x4)(0.f);
    #pragma unroll
    for (int ks = 0; ks < 4; ++ks) {
      short8 a  = *(const short8*)&wapbf[(size_t)(mt*16+lane16)*128 + ks*32 + quad*8];
      short8 b8 = *(const short8*)&XT[(n4*16+lane16)*136 + ks*32 + quad*8];
      acc = __builtin_amdgcn_mfma_f32_16x16x32_bf16(a, b8, acc, 0, 0, 0);
    }
    int p = n4*16 + lane16;
    #pragma unroll
    for (int r = 0; r < 4; ++r) {
      int rr = mt*16 + quad*4 + r;
      At[rr*72 + p] = (p < 49) ? (short)f2bf(acc[r] + b215[rr]) : (short)0;
    }
  }
  __syncthreads();

  // phase 1b: M1[m][d] = relu(a-rows @ ps-rows^T)   (M=96, N=128, K=64)
  for (int t = w; t < 48; t += 8) {
    int mt = t / 8, n4 = t % 8;
    f32x4 acc = (f32x4)(0.f);
    #pragma unroll
    for (int ks = 0; ks < 2; ++ks) {
      short8 a  = *(const short8*)&At[(128 + mt*16 + lane16)*72 + ks*32 + quad*8];
      short8 b8 = *(const short8*)&At[(n4*16+lane16)*72 + ks*32 + quad*8];
      acc = __builtin_amdgcn_mfma_f32_16x16x32_bf16(a, b8, acc, 0, 0, 0);
    }
    int d = n4*16 + lane16;
    #pragma unroll
    for (int r = 0; r < 4; ++r) {
      int m = mt*16 + quad*4 + r;
      M1[m*136 + d] = (short)f2bf(fmaxf(acc[r], 0.f));
    }
  }
  __syncthreads();

  // phase 2: G[o][m] = Wg2 @ m1 + nt + bg   (M=128, N=96, K=128)
  const float* ntb = nt + (size_t)(b & 1)*11264;
  for (int t = w; t < 48; t += 8) {
    int mt = t / 6, n4 = t % 6;
    f32x4 acc = (f32x4)(0.f);
    #pragma unroll
    for (int ks = 0; ks < 4; ++ks) {
      short8 a  = *(const short8*)&wg2bf[(size_t)(mt*16+lane16)*128 + ks*32 + quad*8];
      short8 b8 = *(const short8*)&M1[(n4*16+lane16)*136 + ks*32 + quad*8];
      acc = __builtin_amdgcn_mfma_f32_16x16x32_bf16(a, b8, acc, 0, 0, 0);
    }
    int m = n4*16 + lane16;
    #pragma unroll
    for (int r = 0; r < 4; ++r) {
      int o = mt*16 + quad*4 + r;
      float v = acc[r] + bg[o] + ((m < 88) ? ntb[o*88 + m] : 0.f);
      G[o*104 + m] = (short)f2bf(v);
    }
  }
  __syncthreads();

  // phase 3: M2[c][n] = relu(G @ enp)   (M=128, N=96, K=96; enp symmetric)
  for (int t = w; t < 48; t += 8) {
    int mt = t / 6, n4 = t % 6;
    f32x4 acc = (f32x4)(0.f);
    #pragma unroll
    for (int ks = 0; ks < 3; ++ks) {
      short8 a  = *(const short8*)&G[(mt*16+lane16)*104 + ks*32 + quad*8];
      short8 b8 = *(const short8*)&enpbf[(size_t)(n4*16+lane16)*96 + ks*32 + quad*8];
      acc = __builtin_amdgcn_mfma_f32_16x16x32_bf16(a, b8, acc, 0, 0, 0);
    }
    int n = n4*16 + lane16;
    #pragma unroll
    for (int r = 0; r < 4; ++r) {
      int c = mt*16 + quad*4 + r;
      M2[c*104 + n] = (short)f2bf(fmaxf(acc[r], 0.f));
    }
  }
  __syncthreads();

  // phase 4: node softmax (wave-0 reductions) + m3 = relu(Wsp @ (m2 @ att) + bsp)
  if (tid < 87) {
    float s = 0.f;
    for (int c = 0; c < 128; ++c) s += Ws[c] * bf2f((unsigned short)M2[c*104 + tid]);
    tnb[tid] = s;
  }
  __syncthreads();
  if (tid < 64) {
    float v = tnb[tid];
    if (tid < 23) v = fmaxf(v, tnb[64+tid]);
    float mx = v;
    #pragma unroll
    for (int off = 32; off; off >>= 1) mx = fmaxf(mx, __shfl_down(mx, off, 64));
    mx = __shfl(mx, 0, 64);
    float e0 = expf(tnb[tid]-mx);
    float e1 = (tid < 23) ? expf(tnb[64+tid]-mx) : 0.f;
    float sm = e0 + e1;
    #pragma unroll
    for (int off = 32; off; off >>= 1) sm += __shfl_down(sm, off, 64);
    sm = __shfl(sm, 0, 64);
    float inv = 1.f/sm;
    wsm[tid] = e0*inv;
    if (tid < 23) wsm[64+tid] = e1*inv;
  }
  __syncthreads();
  if (tid < 128) {
    float s = 0.f;
    for (int m = 0; m < 87; ++m) s += bf2f((unsigned short)M2[tid*104 + m]) * wsm[m];
    zs[tid] = s;
  }
  __syncthreads();
  if (tid < 128) {
    float s = 0.f;
    for (int c = 0; c < 128; ++c) s += Wsp[tid*128 + c] * zs[c];
    m3s[tid] = fmaxf(s + bsp[tid], 0.f);
  }
  __syncthreads();

  // phase 5: features / outputs2 / softmax
  if (tid < 256) {
    float s = 0.f;
    #pragma unroll 4
    for (int d4 = 0; d4 < 32; ++d4) {
      float4 w4 = *(const float4*)&wc[tid*128 + d4*4];
      s += w4.x*m3s[d4*4] + w4.y*m3s[d4*4+1] + w4.z*m3s[d4*4+2] + w4.w*m3s[d4*4+3];
    }
    float f = featp[b*256 + tid] + bc[tid] + s;
    fs[tid] = f;
    feat[b*256 + tid] = f;
  }
  __syncthreads();
  if (tid < 65) {
    float s = 0.f;
    for (int j = 0; j < 256; ++j) s += Wfc2[tid*256 + j] * fs[j];
    out2[b*65 + tid] = s;
    o2s[tid] = s;
  }
  __syncthreads();
  if (tid < 64) {
    float v = o2s[tid];
    if (tid == 0) v = fmaxf(v, o2s[64]);
    float mx = v;
    #pragma unroll
    for (int off = 32; off; off >>= 1) mx = fmaxf(mx, __shfl_down(mx, off, 64));
    mx = __shfl(mx, 0, 64);
    float e = expf(o2s[tid]-mx) + ((tid == 0) ? expf(o2s[64]-mx) : 0.f);
    float sm = e;
    #pragma unroll
    for (int off = 32; off; off >>= 1) sm += __shfl_down(sm, off, 64);
    if (tid == 0) { red[0] = mx; red[1] = 1.f/sm; }
  }
  __syncthreads();
  if (tid < 65) soft[b*65 + tid] = expf(o2s[tid]-red[0]) * red[1];
}

// ---------------- launch ----------------
extern "C" void kernel_launch(void* const* d_in, const int* in_sizes, int n_in,
                              void* d_out, int out_size, void* d_ws, size_t ws_size,
                              hipStream_t stream)
{
  (void)in_sizes; (void)n_in; (void)out_size; (void)ws_size;
  const float* x      = (const float*)d_in[0];
  const float* Wb     = (const float*)d_in[1];
  const float* bb     = (const float*)d_in[2];
  const float* Wfc    = (const float*)d_in[3];
  const float* Wfc2   = (const float*)d_in[4];
  const float* Wo1    = (const float*)d_in[5];
  const float* bo1    = (const float*)d_in[6];
  const float* Wo2    = (const float*)d_in[7];
  const float* bo2    = (const float*)d_in[8];
  const float* Wa     = (const float*)d_in[9];
  const float* ba     = (const float*)d_in[10];
  const float* Wps    = (const float*)d_in[11];
  const float* bps    = (const float*)d_in[12];
  const float* node_p = (const float*)d_in[13];
  const float* Wg     = (const float*)d_in[14];
  const float* bg     = (const float*)d_in[15];
  const float* Wsp    = (const float*)d_in[16];
  const float* bsp    = (const float*)d_in[17];
  const float* Ws     = (const float*)d_in[18];
  const float* Wox1   = (const float*)d_in[20];
  const float* box1   = (const float*)d_in[21];
  const float* Wox2   = (const float*)d_in[22];
  const float* box2   = (const float*)d_in[23];
  const float* edge   = (const float*)d_in[24];

  float* ws   = (float*)d_ws;
  float* out  = (float*)d_out;
  float* feat  = out;            // (256,256)
  float* out2  = out + 65536;    // (256,65)
  float* soft  = out + 82176;    // (256,65)
  float* preo  = out + 98816;    // (256,65)
  float* featp = out + 115456;   // (256,256)

  ksetup_all<<<3347, 256, 0, stream>>>(Wb, bb, Wa, ba, Wps, bps, Wg, edge,
                                       Wo2, Wo1, Wox2, Wox1, box1, box2, bo1, bo2,
                                       ws, featp);
  kmain5<<<dim3(256,4), 512, 0, stream>>>(x, (const short*)(ws + OFF_W12BF),
                                          (short*)(ws + OFF_XPBF), ws + OFF_PART);
  kwcf<<<256, 256, 0, stream>>>(Wb, bb, (const short*)(ws + OFF_XPBF), featp, ws);
  kpr<<<256, 128, 0, stream>>>(featp, Wfc, ws + OFF_WPR, preo, ws + OFF_VY);
  knode<<<88, 256, 0, stream>>>(Wg, node_p, ws + OFF_VY, ws + OFF_NT);
  kgraph_all<<<256, 512, 132144, stream>>>(ws + OFF_PART, ws + OFF_B12,
                                           (const short*)(ws + OFF_WAPBF),
                                           ws + OFF_B215,
                                           (const short*)(ws + OFF_WG2BF),
                                           ws + OFF_NT, bg,
                                           (const short*)(ws + OFF_ENPBF),
                                           Wsp, bsp, Ws,
                                           ws + OFF_WC, ws + OFF_BC, featp, Wfc2,
                                           feat, out2, soft);
}